// Round 1
// baseline (323.219 us; speedup 1.0000x reference)
//
#include <hip/hip_runtime.h>
#include <cstdint>

#define HS 62
#define HX 248
#define HXW (HX * HX)  // 61504
#define HSW (HS * HS)  // 3844

typedef __attribute__((ext_vector_type(8))) short bf16x8;
typedef __attribute__((ext_vector_type(4))) float f32x4;
typedef __attribute__((ext_vector_type(2))) float f32x2;

static __device__ __forceinline__ unsigned short f2bf(float f) {
  uint32_t u = __builtin_bit_cast(uint32_t, f);
  u += 0x7fff + ((u >> 16) & 1);  // RNE
  return (unsigned short)(u >> 16);
}
static __device__ __forceinline__ float bf2f(unsigned short u) {
  uint32_t x = (uint32_t)u << 16;
  return __builtin_bit_cast(float, x);
}
static __device__ __forceinline__ float bflo(uint32_t u) {
  return __builtin_bit_cast(float, u << 16);
}
static __device__ __forceinline__ float bfhi(uint32_t u) {
  return __builtin_bit_cast(float, u & 0xffff0000u);
}

// packed fp32 FMA: acc = a*b + acc (2 lanes of fp32, CDNA v_pk_fma_f32)
static __device__ __forceinline__ void pkfma(f32x2& acc, f32x2 a, f32x2 b) {
  asm("v_pk_fma_f32 %0, %1, %2, %0" : "+v"(acc) : "v"(a), "v"(b));
}
// packed f32->bf16 RNE convert: returns (bf16(lo) | bf16(hi)<<16)
static __device__ __forceinline__ uint32_t cvtpk(float lo, float hi) {
  uint32_t r;
  asm("v_cvt_pk_bf16_f32 %0, %1, %2" : "=v"(r) : "v"(lo), "v"(hi));
  return r;
}
// unpack u32 holding 2 bf16 -> packed f32 pair
static __device__ __forceinline__ f32x2 unp(uint32_t u) {
  f32x2 r;
  r.x = __builtin_bit_cast(float, u << 16);
  r.y = __builtin_bit_cast(float, u & 0xffff0000u);
  return r;
}

// ---------------------------------------------------------------------------
// Depthwise 3x3 scalar (62x62 tensors), fp32 out, bias+residual.
// ---------------------------------------------------------------------------
__global__ void dwconv3_kernel(const float* __restrict__ x, const float* __restrict__ w,
                               const float* __restrict__ bias, float* __restrict__ y,
                               int C, int H, int W, int total, int residual) {
  int i = blockIdx.x * 256 + threadIdx.x;
  if (i >= total) return;
  int wx = i % W;
  int t = i / W;
  int hy = t % H;
  int bc = t / H;
  int c = bc % C;
  const float* xb = x + (size_t)bc * H * W;
  const float* wc = w + c * 9;
  float s = bias ? bias[c] : 0.0f;
  for (int di = -1; di <= 1; di++) {
    int h2 = hy + di;
    if (h2 < 0 || h2 >= H) continue;
    for (int dj = -1; dj <= 1; dj++) {
      int w2 = wx + dj;
      if (w2 < 0 || w2 >= W) continue;
      s += xb[(size_t)h2 * W + w2] * wc[(di + 1) * 3 + (dj + 1)];
    }
  }
  if (residual) s += xb[(size_t)hy * W + wx];
  y[i] = s;
}

// ---------------------------------------------------------------------------
// Depthwise 3x3 x-path: fp32 NCHW in -> bf16 NCHW out, residual. 4 px/thread.
// ---------------------------------------------------------------------------
__global__ void dwconv4_bf16_kernel(const float* __restrict__ x, const float* __restrict__ w,
                                    const float* __restrict__ bias,
                                    unsigned short* __restrict__ y, int total4) {
  int i = blockIdx.x * 256 + threadIdx.x;
  if (i >= total4) return;
  int W4 = HX >> 2;
  int wq = (i % W4) * 4;
  int t = i / W4;
  int hy = t % HX;
  int bc = t / HX;
  int c = bc & 127;
  const float* xb = x + (size_t)bc * HXW;
  const float* wc = w + c * 9;
  float bv = bias[c];
  float s0 = bv, s1 = bv, s2 = bv, s3 = bv;
  for (int di = -1; di <= 1; di++) {
    int h2 = hy + di;
    if (h2 < 0 || h2 >= HX) continue;
    const float* row = xb + (size_t)h2 * HX + wq;
    float4 cv = *(const float4*)row;
    float lf = (wq > 0) ? row[-1] : 0.0f;
    float rt = (wq + 4 < HX) ? row[4] : 0.0f;
    float w0 = wc[(di + 1) * 3 + 0];
    float w1 = wc[(di + 1) * 3 + 1];
    float w2 = wc[(di + 1) * 3 + 2];
    s0 += w0 * lf   + w1 * cv.x + w2 * cv.y;
    s1 += w0 * cv.x + w1 * cv.y + w2 * cv.z;
    s2 += w0 * cv.y + w1 * cv.z + w2 * cv.w;
    s3 += w0 * cv.z + w1 * cv.w + w2 * rt;
  }
  {
    float4 cc = *(const float4*)(xb + (size_t)hy * HX + wq);
    s0 += cc.x; s1 += cc.y; s2 += cc.z; s3 += cc.w;
  }
  uint2 d;
  d.x = (uint32_t)f2bf(s0) | ((uint32_t)f2bf(s1) << 16);
  d.y = (uint32_t)f2bf(s2) | ((uint32_t)f2bf(s3) << 16);
  *(uint2*)(y + (size_t)bc * HXW + (size_t)hy * HX + wq) = d;
}

// ---------------------------------------------------------------------------
// fp32 -> bf16 flat convert (for w_kv).
// ---------------------------------------------------------------------------
__global__ void cvt_bf16_kernel(const float* __restrict__ src, unsigned short* __restrict__ dst,
                                int n) {
  int i = blockIdx.x * 256 + threadIdx.x;
  if (i < n) dst[i] = f2bf(src[i]);
}

// ---------------------------------------------------------------------------
// Depthwise 3x3 q path: fp32 NCHW in -> bf16 NHWC out, pre-scaled by 32^-0.5.
// ---------------------------------------------------------------------------
__global__ void dwconv_q_kernel(const float* __restrict__ x, const float* __restrict__ w,
                                unsigned short* __restrict__ qn, int total) {
  int i = blockIdx.x * 256 + threadIdx.x;
  if (i >= total) return;
  int wx = i % HS;
  int t = i / HS;
  int hy = t % HS;
  int bc = t / HS;
  int c = bc & 127;
  int b = bc >> 7;
  const float* xb = x + (size_t)bc * HSW;
  const float* wc = w + c * 9;
  float s = 0.0f;
  for (int di = -1; di <= 1; di++) {
    int h2 = hy + di;
    if (h2 < 0 || h2 >= HS) continue;
    for (int dj = -1; dj <= 1; dj++) {
      int w2 = wx + dj;
      if (w2 < 0 || w2 >= HS) continue;
      s += xb[(size_t)h2 * HS + w2] * wc[(di + 1) * 3 + (dj + 1)];
    }
  }
  qn[((size_t)(b * HSW + hy * HS + wx)) * 128 + c] = f2bf(s * 0.17677669529663688f);
}

// ---------------------------------------------------------------------------
// MFMA 1x1 conv kv path, v3: weights staged in LDS per 64-o quarter.
// Block = 64 px x 256 o, 4 waves. Grid (961, 2).
// ---------------------------------------------------------------------------
__global__ __launch_bounds__(256) void conv1_kv_mfma_kernel(
    const unsigned short* __restrict__ xpb,  // (2,128,61504) bf16 NCHW
    const unsigned short* __restrict__ wkb,  // (256,128) bf16
    unsigned short* __restrict__ y) {        // (2,61504,256) bf16 NHWC
  int b = blockIdx.y;
  int p0 = blockIdx.x * 64;
  int tid = threadIdx.x;
  int wave = tid >> 6, lane = tid & 63, quad = lane >> 4, l15 = lane & 15;
  __shared__ __align__(16) unsigned short bufA[64 * 136];  // 17,408 B
  __shared__ __align__(16) unsigned short bufW[64 * 136];  // 17,408 B

  // phase 1: stage X-tile as bufA[px][c], stride 136
  {
    int c = tid >> 1, half = tid & 1;
    const unsigned short* src = xpb + ((size_t)(b * 128 + c)) * HXW + p0 + half * 32;
#pragma unroll
    for (int j = 0; j < 8; j++) {
      uint2 v = *(const uint2*)(src + j * 4);
      int px = half * 32 + j * 4;
      bufA[(px + 0) * 136 + c] = (unsigned short)(v.x & 0xffff);
      bufA[(px + 1) * 136 + c] = (unsigned short)(v.x >> 16);
      bufA[(px + 2) * 136 + c] = (unsigned short)(v.y & 0xffff);
      bufA[(px + 3) * 136 + c] = (unsigned short)(v.y >> 16);
    }
  }
  __syncthreads();
  bf16x8 A[4];
#pragma unroll
  for (int kb = 0; kb < 4; kb++)
    A[kb] = __builtin_bit_cast(bf16x8,
        *(const uint4*)&bufA[(wave * 16 + l15) * 136 + kb * 32 + quad * 8]);
  // bufA becomes the output stage after the next barrier.

  const f32x4 zf = {0.f, 0.f, 0.f, 0.f};
#pragma unroll 1
  for (int h = 0; h < 2; h++) {
#pragma unroll 1
    for (int oq = 0; oq < 2; oq++) {
      __syncthreads();  // bufW reusable; (h>0: bufA flush complete)
      {  // cooperative coalesced load of one 64-o weight quarter -> bufW
        int orow = tid >> 2;          // 0..63
        int cseg = (tid & 3) * 32;    // 0,32,64,96
        const unsigned short* src = wkb + (size_t)(h * 128 + oq * 64 + orow) * 128 + cseg;
        unsigned short* dst = &bufW[orow * 136 + cseg];
        *(uint4*)(dst)      = *(const uint4*)(src);
        *(uint4*)(dst + 8)  = *(const uint4*)(src + 8);
        *(uint4*)(dst + 16) = *(const uint4*)(src + 16);
        *(uint4*)(dst + 24) = *(const uint4*)(src + 24);
      }
      __syncthreads();
#pragma unroll
      for (int ot = 0; ot < 4; ot++) {
        const unsigned short* wrow = &bufW[(ot * 16 + l15) * 136 + quad * 8];
        f32x4 D = zf;
        D = __builtin_amdgcn_mfma_f32_16x16x32_bf16(A[0], __builtin_bit_cast(bf16x8, *(const uint4*)(wrow)),      D, 0, 0, 0);
        D = __builtin_amdgcn_mfma_f32_16x16x32_bf16(A[1], __builtin_bit_cast(bf16x8, *(const uint4*)(wrow + 32)), D, 0, 0, 0);
        D = __builtin_amdgcn_mfma_f32_16x16x32_bf16(A[2], __builtin_bit_cast(bf16x8, *(const uint4*)(wrow + 64)), D, 0, 0, 0);
        D = __builtin_amdgcn_mfma_f32_16x16x32_bf16(A[3], __builtin_bit_cast(bf16x8, *(const uint4*)(wrow + 96)), D, 0, 0, 0);
#pragma unroll
        for (int r = 0; r < 4; r++)
          bufA[(wave * 16 + quad * 4 + r) * 136 + (oq * 4 + ot) * 16 + l15] = f2bf(D[r]);
      }
    }
    __syncthreads();
    {  // flush this o-half: 64 px x 128 o, coalesced
      int px = tid >> 2, og = (tid & 3) * 32;
      const uint4* srcp = (const uint4*)&bufA[px * 136 + og];
      uint4* dstp = (uint4*)(y + ((size_t)b * HXW + p0 + px) * 256 + h * 128 + og);
#pragma unroll
      for (int j = 0; j < 4; j++) dstp[j] = srcp[j];
    }
  }
}

// ---------------------------------------------------------------------------
// Fused depthwise 3x3 K/V from bf16 NHWC tkv — v2: column-streaming.
// Each wave owns 8 CONSECUTIVE px; a column (3 vertical uint2 taps) is loaded
// once and feeds 3 px x 3 rows from registers (loads/px 9 -> 3.75).
// Packed v_pk_fma_f32 does 2 channels/instr (VALU ~2x down vs scalar).
// Edge rows via template instantiation (uniform branch, no per-column masks).
// Grid (8, 124, 2), block 256.
// ---------------------------------------------------------------------------
template <bool VT, bool VB>
static __device__ __forceinline__ void dwkv_row(
    const unsigned short* __restrict__ r0, const unsigned short* __restrict__ r1,
    const unsigned short* __restrict__ r2, const f32x2 (&wp)[9][2],
    int px0, f32x2 (&acc)[8][2]) {
  const f32x2 z2 = {0.f, 0.f};
#pragma unroll
  for (int p = 0; p < 8; p++) { acc[p][0] = z2; acc[p][1] = z2; }
#pragma unroll
  for (int j = 0; j < 10; j++) {
    int xcol = px0 - 1 + j;
    int xc = xcol;
    if (j == 0) xc = (xcol < 0) ? 0 : xcol;
    if (j == 9) xc = (xcol > HX - 1) ? HX - 1 : xcol;
    size_t off = (size_t)xc * 256;
    uint2 u1 = *(const uint2*)(r1 + off);
    uint2 u0, u2;
    if constexpr (VT) u0 = *(const uint2*)(r0 + off);
    if constexpr (VB) u2 = *(const uint2*)(r2 + off);
    if (j == 0 || j == 9) {  // only edge columns can be out of range
      bool oob = (j == 0) ? (xcol < 0) : (xcol > HX - 1);
      if (oob) {
        u1.x = 0u; u1.y = 0u;
        if constexpr (VT) { u0.x = 0u; u0.y = 0u; }
        if constexpr (VB) { u2.x = 0u; u2.y = 0u; }
      }
    }
    f32x2 d1a = unp(u1.x), d1b = unp(u1.y);
    f32x2 d0a, d0b, d2a, d2b;
    if constexpr (VT) { d0a = unp(u0.x); d0b = unp(u0.y); }
    if constexpr (VB) { d2a = unp(u2.x); d2b = unp(u2.y); }
    // this column is: LEFT tap (w col 0) of px j, CENTER (w col 1) of px j-1,
    // RIGHT (w col 2) of px j-2.  w rows: top=t, mid=3+t, bot=6+t.
    if (j <= 7) {
      if constexpr (VT) { pkfma(acc[j][0], wp[0][0], d0a); pkfma(acc[j][1], wp[0][1], d0b); }
      pkfma(acc[j][0], wp[3][0], d1a); pkfma(acc[j][1], wp[3][1], d1b);
      if constexpr (VB) { pkfma(acc[j][0], wp[6][0], d2a); pkfma(acc[j][1], wp[6][1], d2b); }
    }
    if (j >= 1 && j <= 8) {
      if constexpr (VT) { pkfma(acc[j - 1][0], wp[1][0], d0a); pkfma(acc[j - 1][1], wp[1][1], d0b); }
      pkfma(acc[j - 1][0], wp[4][0], d1a); pkfma(acc[j - 1][1], wp[4][1], d1b);
      if constexpr (VB) { pkfma(acc[j - 1][0], wp[7][0], d2a); pkfma(acc[j - 1][1], wp[7][1], d2b); }
    }
    if (j >= 2) {
      if constexpr (VT) { pkfma(acc[j - 2][0], wp[2][0], d0a); pkfma(acc[j - 2][1], wp[2][1], d0b); }
      pkfma(acc[j - 2][0], wp[5][0], d1a); pkfma(acc[j - 2][1], wp[5][1], d1b);
      if constexpr (VB) { pkfma(acc[j - 2][0], wp[8][0], d2a); pkfma(acc[j - 2][1], wp[8][1], d2b); }
    }
  }
}

__global__ __launch_bounds__(256, 4) void dwconv_kv_kernel(const unsigned short* __restrict__ tkv,
                                                           const float* __restrict__ w,
                                                           unsigned short* __restrict__ kT,
                                                           unsigned short* __restrict__ vv) {
  int strip = blockIdx.x;                      // 0..7
  int x0 = (strip == 7) ? 216 : strip * 32;
  int g = blockIdx.y;                          // 0..123
  int b = blockIdx.z;
  int tid = threadIdx.x;
  int cq = tid & 63;                           // channel quad (lane)
  int pg = tid >> 6;                           // wave id -> 8-px group
  int ch0 = cq * 4;
  int px0 = x0 + pg * 8;

  f32x2 wp[9][2];
#pragma unroll
  for (int t = 0; t < 9; t++) {
    wp[t][0].x = w[(ch0 + 0) * 9 + t];
    wp[t][0].y = w[(ch0 + 1) * 9 + t];
    wp[t][1].x = w[(ch0 + 2) * 9 + t];
    wp[t][1].y = w[(ch0 + 3) * 9 + t];
  }

  __shared__ unsigned short vt[128 * 35];      // [ch][px] stride 35 (9 KB)
  const unsigned short* base = tkv + (size_t)b * HXW * 256 + ch0;

#pragma unroll 1
  for (int r = 0; r < 2; r++) {
    int hy = g * 2 + r;
    const unsigned short* r1 = base + (size_t)hy * (HX * 256);
    const unsigned short* r0 = (hy > 0) ? (r1 - HX * 256) : r1;
    const unsigned short* r2 = (hy < HX - 1) ? (r1 + HX * 256) : r1;
    f32x2 acc[8][2];
    if (hy == 0)            dwkv_row<false, true >(r0, r1, r2, wp, px0, acc);
    else if (hy == HX - 1)  dwkv_row<true,  false>(r0, r1, r2, wp, px0, acc);
    else                    dwkv_row<true,  true >(r0, r1, r2, wp, px0, acc);

    if (cq < 32) {  // K half: direct NHWC store, packed bf16 convert
      unsigned short* kb = kT + ((size_t)b * HXW + (size_t)hy * HX + px0) * 128 + ch0;
#pragma unroll
      for (int p = 0; p < 8; p++) {
        uint2 d;
        d.x = cvtpk(acc[p][0].x, acc[p][0].y);
        d.y = cvtpk(acc[p][1].x, acc[p][1].y);
        *(uint2*)(kb + (size_t)p * 128) = d;
      }
    } else {        // V half: stage transposed into LDS
      int c0 = ch0 - 128;
      int pxr = pg * 8;
#pragma unroll
      for (int p = 0; p < 8; p++) {
        vt[(c0 + 0) * 35 + pxr + p] = f2bf(acc[p][0].x);
        vt[(c0 + 1) * 35 + pxr + p] = f2bf(acc[p][0].y);
        vt[(c0 + 2) * 35 + pxr + p] = f2bf(acc[p][1].x);
        vt[(c0 + 3) * 35 + pxr + p] = f2bf(acc[p][1].y);
      }
    }
    __syncthreads();
    {  // cooperative NCHW store of the V row
      int cv = tid & 127;
      int phx = (tid >> 7) * 16;
      unsigned short* dst = vv + ((size_t)(b * 128 + cv)) * HXW + (size_t)hy * HX + x0 + phx;
      const unsigned short* srcv = vt + cv * 35 + phx;
#pragma unroll
      for (int jj = 0; jj < 4; jj++) {
        uint2 d;
        d.x = (uint32_t)srcv[jj * 4 + 0] | ((uint32_t)srcv[jj * 4 + 1] << 16);
        d.y = (uint32_t)srcv[jj * 4 + 2] | ((uint32_t)srcv[jj * 4 + 3] << 16);
        *(uint2*)(dst + jj * 4) = d;
      }
    }
    __syncthreads();
  }
}

// ---------------------------------------------------------------------------
// 1x1 conv tiled SGEMM (fp32) — small tensors (q path, output projection).
// ---------------------------------------------------------------------------
template <int O>
__global__ __launch_bounds__(256) void conv1_kernel(const float* __restrict__ x,
                                                    const float* __restrict__ w,
                                                    float* __restrict__ y, int HW) {
  constexpr int K = 128;
  constexpr int BK = 32;
  __shared__ __align__(16) float ws_s[BK][64];
  __shared__ __align__(16) float xs_s[BK][64];
  int b = blockIdx.z;
  int o0 = blockIdx.y * 64;
  int p0 = blockIdx.x * 64;
  const float* xb = x + (size_t)b * K * HW;
  int tx = threadIdx.x & 15;
  int ty = threadIdx.x >> 4;
  float acc[4][4] = {};
  int lo = threadIdx.x >> 2;
  int lk = (threadIdx.x & 3) * 8;
  int lc = threadIdx.x >> 3;
  int lp = (threadIdx.x & 7) * 8;

  for (int k0 = 0; k0 < K; k0 += BK) {
    __syncthreads();
    {
      const float* wp = w + (size_t)(o0 + lo) * K + k0 + lk;
      float4 a = *(const float4*)wp;
      float4 bq = *(const float4*)(wp + 4);
      ws_s[lk + 0][lo] = a.x;  ws_s[lk + 1][lo] = a.y;
      ws_s[lk + 2][lo] = a.z;  ws_s[lk + 3][lo] = a.w;
      ws_s[lk + 4][lo] = bq.x; ws_s[lk + 5][lo] = bq.y;
      ws_s[lk + 6][lo] = bq.z; ws_s[lk + 7][lo] = bq.w;
    }
    {
      int p = p0 + lp;
      const float* xp = xb + (size_t)(k0 + lc) * HW;
      float4 a, bq;
      if (p + 7 < HW) {
        a = *(const float4*)(xp + p);
        bq = *(const float4*)(xp + p + 4);
      } else {
        float tv[8];
#pragma unroll
        for (int j = 0; j < 8; j++) tv[j] = (p + j < HW) ? xp[p + j] : 0.0f;
        a = make_float4(tv[0], tv[1], tv[2], tv[3]);
        bq = make_float4(tv[4], tv[5], tv[6], tv[7]);
      }
      *(float4*)&xs_s[lc][lp] = a;
      *(float4*)&xs_s[lc][lp + 4] = bq;
    }
    __syncthreads();
#pragma unroll
    for (int k = 0; k < BK; k++) {
      float4 wv = *(const float4*)&ws_s[k][ty * 4];
      float4 xv = *(const float4*)&xs_s[k][tx * 4];
      acc[0][0] += wv.x * xv.x; acc[0][1] += wv.x * xv.y; acc[0][2] += wv.x * xv.z; acc[0][3] += wv.x * xv.w;
      acc[1][0] += wv.y * xv.x; acc[1][1] += wv.y * xv.y; acc[1][2] += wv.y * xv.z; acc[1][3] += wv.y * xv.w;
      acc[2][0] += wv.z * xv.x; acc[2][1] += wv.z * xv.y; acc[2][2] += wv.z * xv.z; acc[2][3] += wv.z * xv.w;
      acc[3][0] += wv.w * xv.x; acc[3][1] += wv.w * xv.y; acc[3][2] += wv.w * xv.z; acc[3][3] += wv.w * xv.w;
    }
  }
  int p = p0 + tx * 4;
  float* yb = y + (size_t)b * O * HW + (size_t)(o0 + ty * 4) * HW;
#pragma unroll
  for (int j = 0; j < 4; j++) {
    float* yr = yb + (size_t)j * HW + p;
    if (p + 3 < HW) {
      *(float4*)yr = make_float4(acc[j][0], acc[j][1], acc[j][2], acc[j][3]);
    } else {
#pragma unroll
      for (int e = 0; e < 4; e++) if (p + e < HW) yr[e] = acc[j][e];
    }
  }
}

// ---------------------------------------------------------------------------
// MFMA windowed attention, head-pair blocks. 512 thr = 8 waves.
// ---------------------------------------------------------------------------
__global__ __launch_bounds__(512) void attn_mfma_kernel(
    const unsigned short* __restrict__ qn,   // (2,62,62,128) bf16, pre-scaled
    const unsigned short* __restrict__ kT,   // (2,248,248,128) bf16 NHWC
    const unsigned short* __restrict__ vp,   // (2,128,248,248) bf16 NCHW
    float* __restrict__ o) {
  int n = blockIdx.x, hp = blockIdx.y, b = blockIdx.z;
  int wi = n / 10, wj = n % 10;
  int wave = threadIdx.x >> 6;
  int hd = wave & 1, oct = wave >> 1;
  int h = hp * 2 + hd;
  int lane = threadIdx.x & 63;
  int quad = lane >> 4;
  int l15 = lane & 15;
  int y0 = 24 * wi, x0 = 24 * wj;

  __shared__ __align__(16) unsigned short lds[20480];  // 40,960 B
  unsigned short* Pw = lds + wave * 2560;              // [q][40keys] 5KB/wave

  bf16x8 QB[4];
#pragma unroll
  for (int nt = 0; nt < 4; nt++) {
    int qq = nt * 16 + l15;
    int qy = 6 * wi + (qq >> 3), qx = 6 * wj + (qq & 7);
    QB[nt] = __builtin_bit_cast(bf16x8,
        *(const uint4*)(qn + ((size_t)(b * HSW + qy * HS + qx)) * 128 + h * 32 + quad * 8));
  }

  f32x4 Oacc[2][4];
#pragma unroll
  for (int a = 0; a < 2; a++)
#pragma unroll
    for (int c = 0; c < 4; c++) Oacc[a][c] = f32x4{0.f, 0.f, 0.f, 0.f};
  float lsum[4] = {0.f, 0.f, 0.f, 0.f};

  const unsigned short* kb = kT + (size_t)b * HXW * 128 + h * 32;
  const unsigned short* vb = vp + ((size_t)(b * 128 + h * 32)) * HXW;
  const f32x4 zf = {0.f, 0.f, 0.f, 0.f};

#define LOADROW(r, K0, K1, V0, V1)                                              \
  {                                                                             \
    int y = y0 + (r);                                                           \
    const unsigned short* krow = kb + ((size_t)(y * HX + x0)) * 128;            \
    K0 = *(const uint4*)(krow + (size_t)l15 * 128 + quad * 8);                  \
    K1 = *(const uint4*)(krow + (size_t)(16 + l15) * 128 + quad * 8);           \
    const unsigned short* vrow = vb + (size_t)y * HX + x0 + quad * 8;           \
    V0 = *(const uint4*)(vrow + (size_t)l15 * HXW);                             \
    V1 = *(const uint4*)(vrow + (size_t)(16 + l15) * HXW);                      \
  }

  auto compute = [&](uint4 k0, uint4 k1, uint4 v0, uint4 v1) {
    bf16x8 KA0 = __builtin_bit_cast(bf16x8, k0);
    bf16x8 KA1 = __builtin_bit_cast(bf16x8, k1);
    bf16x8 VA0 = __builtin_bit_cast(bf16x8, v0);
    bf16x8 VA1 = __builtin_bit_cast(bf16x8, v1);
    f32x4 S[2][4];
#pragma unroll
    for (int nt = 0; nt < 4; nt++) {
      S[0][nt] = __builtin_amdgcn_mfma_f32_16x16x32_bf16(KA0, QB[nt], zf, 0, 0, 0);
      S[1][nt] = __builtin_amdgcn_mfma_f32_16x16x32_bf16(KA1, QB[nt], zf, 0, 0, 0);
    }
#pragma unroll
    for (int nt = 0; nt < 4; nt++) {
      float pv[2][4];
      float cs = 0.f;
#pragma unroll
      for (int mt = 0; mt < 2; mt++)
#pragma unroll
        for (int r = 0; r < 4; r++) {
          pv[mt][r] = __expf(S[mt][nt][r]);
          cs += pv[mt][r];
        }
      lsum[nt] += cs;
#pragma unroll
      for (int mt = 0; mt < 2; mt++) {
        uint2 d;
        d.x = (uint32_t)f2bf(pv[mt][0]) | ((uint32_t)f2bf(pv[mt][1]) << 16);
        d.y = (uint32_t)f2bf(pv[mt][2]) | ((uint32_t)f2bf(pv[mt][3]) << 16);
        *(uint2*)(Pw + (16 * nt + l15) * 40 + 16 * mt + quad * 4) = d;
      }
    }
#pragma unroll
    for (int nt = 0; nt < 4; nt++) {
      bf16x8 PB = __builtin_bit_cast(bf16x8, *(const uint4*)(Pw + (16 * nt + l15) * 40 + quad * 8));
      Oacc[0][nt] = __builtin_amdgcn_mfma_f32_16x16x32_bf16(VA0, PB, Oacc[0][nt], 0, 0, 0);
      Oacc[1][nt] = __builtin_amdgcn_mfma_f32_16x16x32_bf16(VA1, PB, Oacc[1][nt], 0, 0, 0);
    }
  };

  int rbase = oct * 8;
  uint4 kA0, kA1, vA0, vA1, kB0, kB1, vB0, vB1;
  LOADROW(rbase + 0, kA0, kA1, vA0, vA1);
  LOADROW(rbase + 1, kB0, kB1, vB0, vB1);
#pragma unroll 1
  for (int r = 0; r < 8; r += 2) {
    compute(kA0, kA1, vA0, vA1);
    {
      int rn = (r + 2 < 8) ? (r + 2) : 6;  // clamped, branch-free
      LOADROW(rbase + rn, kA0, kA1, vA0, vA1);
    }
    compute(kB0, kB1, vB0, vB1);
    {
      int rn = (r + 3 < 8) ? (r + 3) : 7;  // clamped, branch-free
      LOADROW(rbase + rn, kB0, kB1, vB0, vB1);
    }
  }
#undef LOADROW

#pragma unroll
  for (int nt = 0; nt < 4; nt++) {
    lsum[nt] += __shfl_xor(lsum[nt], 16, 64);
    lsum[nt] += __shfl_xor(lsum[nt], 32, 64);
  }

  float* mO = (float*)lds;                 // [oct][32ch][64q]  32 KB
  float* mL = (float*)(lds + 16384);       // [oct][64q]
#pragma unroll 1
  for (int p = 0; p < 2; p++) {
    __syncthreads();
    if (hd == p) {
#pragma unroll
      for (int mt = 0; mt < 2; mt++)
#pragma unroll
        for (int nt = 0; nt < 4; nt++)
#pragma unroll
          for (int r = 0; r < 4; r++)
            mO[oct * 2048 + (16 * mt + quad * 4 + r) * 64 + 16 * nt + l15] = Oacc[mt][nt][r];
      if (quad == 0) {
#pragma unroll
        for (int nt = 0; nt < 4; nt++) mL[oct * 64 + nt * 16 + l15] = lsum[nt];
      }
    }
    __syncthreads();
    {
      int q = threadIdx.x & 63;
      int cg = threadIdx.x >> 6;  // 0..7 -> 4 ch each
      float inv = 1.0f / (mL[q] + mL[64 + q] + mL[128 + q] + mL[192 + q]);
      float* ob = o + (((size_t)(b * 100 + n)) * 128 + (hp * 2 + p) * 32 + cg * 4) * 64 + q;
#pragma unroll
      for (int e = 0; e < 4; e++) {
        int ch = cg * 4 + e;
        float s = mO[ch * 64 + q] + mO[2048 + ch * 64 + q] +
                  mO[4096 + ch * 64 + q] + mO[6144 + ch * 64 + q];
        ob[(size_t)e * 64] = s * inv;
      }
    }
  }
}

// ---------------------------------------------------------------------------
// Reverse: scatter-average overlapping 8x8 windows (step 6) into (2,128,62,62)
// ---------------------------------------------------------------------------
__global__ void reverse_kernel(const float* __restrict__ win, float* __restrict__ out) {
  int i = blockIdx.x * 256 + threadIdx.x;
  const int total = 2 * 128 * HSW;
  if (i >= total) return;
  int x = i % HS;
  int t = i / HS;
  int y = t % HS;
  t /= HS;
  int c = t % 128;
  int b = t / 128;
  int wi0 = (y >= 7) ? (y - 2) / 6 : 0;
  int wi1 = min(9, y / 6);
  int wj0 = (x >= 7) ? (x - 2) / 6 : 0;
  int wj1 = min(9, x / 6);
  float s = 0.0f;
  for (int wi = wi0; wi <= wi1; wi++)
    for (int wj = wj0; wj <= wj1; wj++) {
      int di = y - 6 * wi, dj = x - 6 * wj;
      s += win[(((size_t)(b * 100 + wi * 10 + wj)) * 128 + c) * 64 + di * 8 + dj];
    }
  float cnt = (float)((wi1 - wi0 + 1) * (wj1 - wj0 + 1));
  out[i] = s / cnt;
}

// ---------------------------------------------------------------------------
extern "C" void kernel_launch(void* const* d_in, const int* in_sizes, int n_in,
                              void* d_out, int out_size, void* d_ws, size_t ws_size,
                              hipStream_t stream) {
  const float* x      = (const float*)d_in[0];
  const float* sp     = (const float*)d_in[1];
  const float* w_pos  = (const float*)d_in[2];
  const float* b_pos  = (const float*)d_in[3];
  const float* w_q    = (const float*)d_in[4];
  const float* w_qdw  = (const float*)d_in[5];
  const float* w_kv   = (const float*)d_in[6];
  const float* w_kvdw = (const float*)d_in[7];
  const float* w_out  = (const float*)d_in[8];
  float* out = (float*)d_out;

  const size_t N_x   = (size_t)2 * 128 * HXW;  // 15,745,024
  const size_t N_t   = (size_t)2 * 256 * HXW;
  const size_t N_s   = (size_t)2 * 128 * HSW;
  const size_t N_att = (size_t)2 * 100 * 128 * 64;

  float* ws = (float*)d_ws;
  unsigned short* xpb = (unsigned short*)ws;
  unsigned short* kT  = (unsigned short*)ws;
  unsigned short* vv  = kT + N_x;
  unsigned short* tkv = (unsigned short*)(ws + N_x);
  float* att = ws + N_x;
  float* rev = att + N_att;
  float* spp = ws + N_x + N_t / 2;
  float* tq  = spp + N_s;
  unsigned short* qn  = (unsigned short*)(tq + N_s);
  unsigned short* wkb = qn + N_s;              // 32768 ushorts
  (void)ws_size; (void)in_sizes; (void)n_in; (void)out_size;

  // 0. wkb = bf16(w_kv)
  cvt_bf16_kernel<<<128, 256, 0, stream>>>(w_kv, wkb, 256 * 128);
  // 1. xpb = bf16(x + dwconv3(x, w_pos, b_pos))   (bf16 NCHW)
  {
    int total4 = (int)(N_x / 4);
    dwconv4_bf16_kernel<<<(total4 + 255) / 256, 256, 0, stream>>>(x, w_pos, b_pos, xpb, total4);
  }
  // 2. spp = sp + dwconv3(sp, w_pos, b_pos)
  {
    int total = (int)N_s;
    dwconv3_kernel<<<(total + 255) / 256, 256, 0, stream>>>(sp, w_pos, b_pos, spp, 128, HS, HS, total, 1);
  }
  // 3. tq = conv1(spp, w_q)
  {
    int HW = HSW;
    dim3 grid((HW + 63) / 64, 2, 2);
    conv1_kernel<128><<<grid, 256, 0, stream>>>(spp, w_q, tq, HW);
  }
  // 4. qn = bf16_nhwc(dwconv3(tq, w_qdw)) * 32^-0.5
  {
    int total = (int)N_s;
    dwconv_q_kernel<<<(total + 255) / 256, 256, 0, stream>>>(tq, w_qdw, qn, total);
  }
  // 5. tkv = bf16_nhwc(mfma_conv1(xpb, wkb))   (xpb dead after)
  {
    dim3 grid(HXW / 64, 2);
    conv1_kv_mfma_kernel<<<grid, 256, 0, stream>>>(xpb, wkb, tkv);
  }
  // 6. kT (NHWC) + vv (NCHW) = bf16(dwconv3(tkv, w_kvdw))   (overwrites xpb)
  {
    dim3 grid(8, 124, 2);
    dwconv_kv_kernel<<<grid, 256, 0, stream>>>(tkv, w_kvdw, kT, vv);
  }
  // 7. attention -> att (2,100,128,64)
  {
    dim3 grid(100, 2, 2);
    attn_mfma_kernel<<<grid, 512, 0, stream>>>(qn, kT, vv, att);
  }
  // 8. rev = reverse(att)
  {
    int total = (int)N_s;
    reverse_kernel<<<(total + 255) / 256, 256, 0, stream>>>(att, rev);
  }
  // 9. out = conv1(rev, w_out)
  {
    int HW = HSW;
    dim3 grid((HW + 63) / 64, 2, 2);
    conv1_kernel<128><<<grid, 256, 0, stream>>>(rev, w_out, out, HW);
  }
}

// Round 2
// 322.189 us; speedup vs baseline: 1.0032x; 1.0032x over previous
//
#include <hip/hip_runtime.h>
#include <cstdint>

#define HS 62
#define HX 248
#define HXW (HX * HX)  // 61504
#define HSW (HS * HS)  // 3844
#define HXP 256        // padded row stride for vv (128-B aligned rows)
#define HXWP (HX * HXP)  // 63488 padded plane

typedef __attribute__((ext_vector_type(8))) short bf16x8;
typedef __attribute__((ext_vector_type(4))) float f32x4;
typedef __attribute__((ext_vector_type(2))) float f32x2;

static __device__ __forceinline__ unsigned short f2bf(float f) {
  uint32_t u = __builtin_bit_cast(uint32_t, f);
  u += 0x7fff + ((u >> 16) & 1);  // RNE
  return (unsigned short)(u >> 16);
}
static __device__ __forceinline__ float bf2f(unsigned short u) {
  uint32_t x = (uint32_t)u << 16;
  return __builtin_bit_cast(float, x);
}
static __device__ __forceinline__ float bflo(uint32_t u) {
  return __builtin_bit_cast(float, u << 16);
}
static __device__ __forceinline__ float bfhi(uint32_t u) {
  return __builtin_bit_cast(float, u & 0xffff0000u);
}

// packed fp32 FMA: acc = a*b + acc (2 lanes of fp32, CDNA v_pk_fma_f32)
static __device__ __forceinline__ void pkfma(f32x2& acc, f32x2 a, f32x2 b) {
  asm("v_pk_fma_f32 %0, %1, %2, %0" : "+v"(acc) : "v"(a), "v"(b));
}
// packed f32->bf16 RNE convert: returns (bf16(lo) | bf16(hi)<<16)
static __device__ __forceinline__ uint32_t cvtpk(float lo, float hi) {
  uint32_t r;
  asm("v_cvt_pk_bf16_f32 %0, %1, %2" : "=v"(r) : "v"(lo), "v"(hi));
  return r;
}
// unpack u32 holding 2 bf16 -> packed f32 pair
static __device__ __forceinline__ f32x2 unp(uint32_t u) {
  f32x2 r;
  r.x = __builtin_bit_cast(float, u << 16);
  r.y = __builtin_bit_cast(float, u & 0xffff0000u);
  return r;
}

// ---------------------------------------------------------------------------
// Depthwise 3x3 scalar (62x62 tensors), fp32 out, bias+residual.
// ---------------------------------------------------------------------------
__global__ void dwconv3_kernel(const float* __restrict__ x, const float* __restrict__ w,
                               const float* __restrict__ bias, float* __restrict__ y,
                               int C, int H, int W, int total, int residual) {
  int i = blockIdx.x * 256 + threadIdx.x;
  if (i >= total) return;
  int wx = i % W;
  int t = i / W;
  int hy = t % H;
  int bc = t / H;
  int c = bc % C;
  const float* xb = x + (size_t)bc * H * W;
  const float* wc = w + c * 9;
  float s = bias ? bias[c] : 0.0f;
  for (int di = -1; di <= 1; di++) {
    int h2 = hy + di;
    if (h2 < 0 || h2 >= H) continue;
    for (int dj = -1; dj <= 1; dj++) {
      int w2 = wx + dj;
      if (w2 < 0 || w2 >= W) continue;
      s += xb[(size_t)h2 * W + w2] * wc[(di + 1) * 3 + (dj + 1)];
    }
  }
  if (residual) s += xb[(size_t)hy * W + wx];
  y[i] = s;
}

// ---------------------------------------------------------------------------
// Depthwise 3x3 x-path: fp32 NCHW in -> bf16 NCHW out, residual. 4 px/thread.
// ---------------------------------------------------------------------------
__global__ void dwconv4_bf16_kernel(const float* __restrict__ x, const float* __restrict__ w,
                                    const float* __restrict__ bias,
                                    unsigned short* __restrict__ y, int total4) {
  int i = blockIdx.x * 256 + threadIdx.x;
  if (i >= total4) return;
  int W4 = HX >> 2;
  int wq = (i % W4) * 4;
  int t = i / W4;
  int hy = t % HX;
  int bc = t / HX;
  int c = bc & 127;
  const float* xb = x + (size_t)bc * HXW;
  const float* wc = w + c * 9;
  float bv = bias[c];
  float s0 = bv, s1 = bv, s2 = bv, s3 = bv;
  for (int di = -1; di <= 1; di++) {
    int h2 = hy + di;
    if (h2 < 0 || h2 >= HX) continue;
    const float* row = xb + (size_t)h2 * HX + wq;
    float4 cv = *(const float4*)row;
    float lf = (wq > 0) ? row[-1] : 0.0f;
    float rt = (wq + 4 < HX) ? row[4] : 0.0f;
    float w0 = wc[(di + 1) * 3 + 0];
    float w1 = wc[(di + 1) * 3 + 1];
    float w2 = wc[(di + 1) * 3 + 2];
    s0 += w0 * lf   + w1 * cv.x + w2 * cv.y;
    s1 += w0 * cv.x + w1 * cv.y + w2 * cv.z;
    s2 += w0 * cv.y + w1 * cv.z + w2 * cv.w;
    s3 += w0 * cv.z + w1 * cv.w + w2 * rt;
  }
  {
    float4 cc = *(const float4*)(xb + (size_t)hy * HX + wq);
    s0 += cc.x; s1 += cc.y; s2 += cc.z; s3 += cc.w;
  }
  uint2 d;
  d.x = (uint32_t)f2bf(s0) | ((uint32_t)f2bf(s1) << 16);
  d.y = (uint32_t)f2bf(s2) | ((uint32_t)f2bf(s3) << 16);
  *(uint2*)(y + (size_t)bc * HXW + (size_t)hy * HX + wq) = d;
}

// ---------------------------------------------------------------------------
// fp32 -> bf16 flat convert (for w_kv).
// ---------------------------------------------------------------------------
__global__ void cvt_bf16_kernel(const float* __restrict__ src, unsigned short* __restrict__ dst,
                                int n) {
  int i = blockIdx.x * 256 + threadIdx.x;
  if (i < n) dst[i] = f2bf(src[i]);
}

// ---------------------------------------------------------------------------
// Depthwise 3x3 q path: fp32 NCHW in -> bf16 NHWC out, pre-scaled by 32^-0.5.
// ---------------------------------------------------------------------------
__global__ void dwconv_q_kernel(const float* __restrict__ x, const float* __restrict__ w,
                                unsigned short* __restrict__ qn, int total) {
  int i = blockIdx.x * 256 + threadIdx.x;
  if (i >= total) return;
  int wx = i % HS;
  int t = i / HS;
  int hy = t % HS;
  int bc = t / HS;
  int c = bc & 127;
  int b = bc >> 7;
  const float* xb = x + (size_t)bc * HSW;
  const float* wc = w + c * 9;
  float s = 0.0f;
  for (int di = -1; di <= 1; di++) {
    int h2 = hy + di;
    if (h2 < 0 || h2 >= HS) continue;
    for (int dj = -1; dj <= 1; dj++) {
      int w2 = wx + dj;
      if (w2 < 0 || w2 >= HS) continue;
      s += xb[(size_t)h2 * HS + w2] * wc[(di + 1) * 3 + (dj + 1)];
    }
  }
  qn[((size_t)(b * HSW + hy * HS + wx)) * 128 + c] = f2bf(s * 0.17677669529663688f);
}

// ---------------------------------------------------------------------------
// MFMA 1x1 conv kv path, v3: weights staged in LDS per 64-o quarter.
// Block = 64 px x 256 o, 4 waves. Grid (961, 2).
// ---------------------------------------------------------------------------
__global__ __launch_bounds__(256) void conv1_kv_mfma_kernel(
    const unsigned short* __restrict__ xpb,  // (2,128,61504) bf16 NCHW
    const unsigned short* __restrict__ wkb,  // (256,128) bf16
    unsigned short* __restrict__ y) {        // (2,61504,256) bf16 NHWC
  int b = blockIdx.y;
  int p0 = blockIdx.x * 64;
  int tid = threadIdx.x;
  int wave = tid >> 6, lane = tid & 63, quad = lane >> 4, l15 = lane & 15;
  __shared__ __align__(16) unsigned short bufA[64 * 136];  // 17,408 B
  __shared__ __align__(16) unsigned short bufW[64 * 136];  // 17,408 B

  // phase 1: stage X-tile as bufA[px][c], stride 136
  {
    int c = tid >> 1, half = tid & 1;
    const unsigned short* src = xpb + ((size_t)(b * 128 + c)) * HXW + p0 + half * 32;
#pragma unroll
    for (int j = 0; j < 8; j++) {
      uint2 v = *(const uint2*)(src + j * 4);
      int px = half * 32 + j * 4;
      bufA[(px + 0) * 136 + c] = (unsigned short)(v.x & 0xffff);
      bufA[(px + 1) * 136 + c] = (unsigned short)(v.x >> 16);
      bufA[(px + 2) * 136 + c] = (unsigned short)(v.y & 0xffff);
      bufA[(px + 3) * 136 + c] = (unsigned short)(v.y >> 16);
    }
  }
  __syncthreads();
  bf16x8 A[4];
#pragma unroll
  for (int kb = 0; kb < 4; kb++)
    A[kb] = __builtin_bit_cast(bf16x8,
        *(const uint4*)&bufA[(wave * 16 + l15) * 136 + kb * 32 + quad * 8]);
  // bufA becomes the output stage after the next barrier.

  const f32x4 zf = {0.f, 0.f, 0.f, 0.f};
#pragma unroll 1
  for (int h = 0; h < 2; h++) {
#pragma unroll 1
    for (int oq = 0; oq < 2; oq++) {
      __syncthreads();  // bufW reusable; (h>0: bufA flush complete)
      {  // cooperative coalesced load of one 64-o weight quarter -> bufW
        int orow = tid >> 2;          // 0..63
        int cseg = (tid & 3) * 32;    // 0,32,64,96
        const unsigned short* src = wkb + (size_t)(h * 128 + oq * 64 + orow) * 128 + cseg;
        unsigned short* dst = &bufW[orow * 136 + cseg];
        *(uint4*)(dst)      = *(const uint4*)(src);
        *(uint4*)(dst + 8)  = *(const uint4*)(src + 8);
        *(uint4*)(dst + 16) = *(const uint4*)(src + 16);
        *(uint4*)(dst + 24) = *(const uint4*)(src + 24);
      }
      __syncthreads();
#pragma unroll
      for (int ot = 0; ot < 4; ot++) {
        const unsigned short* wrow = &bufW[(ot * 16 + l15) * 136 + quad * 8];
        f32x4 D = zf;
        D = __builtin_amdgcn_mfma_f32_16x16x32_bf16(A[0], __builtin_bit_cast(bf16x8, *(const uint4*)(wrow)),      D, 0, 0, 0);
        D = __builtin_amdgcn_mfma_f32_16x16x32_bf16(A[1], __builtin_bit_cast(bf16x8, *(const uint4*)(wrow + 32)), D, 0, 0, 0);
        D = __builtin_amdgcn_mfma_f32_16x16x32_bf16(A[2], __builtin_bit_cast(bf16x8, *(const uint4*)(wrow + 64)), D, 0, 0, 0);
        D = __builtin_amdgcn_mfma_f32_16x16x32_bf16(A[3], __builtin_bit_cast(bf16x8, *(const uint4*)(wrow + 96)), D, 0, 0, 0);
#pragma unroll
        for (int r = 0; r < 4; r++)
          bufA[(wave * 16 + quad * 4 + r) * 136 + (oq * 4 + ot) * 16 + l15] = f2bf(D[r]);
      }
    }
    __syncthreads();
    {  // flush this o-half: 64 px x 128 o, coalesced
      int px = tid >> 2, og = (tid & 3) * 32;
      const uint4* srcp = (const uint4*)&bufA[px * 136 + og];
      uint4* dstp = (uint4*)(y + ((size_t)b * HXW + p0 + px) * 256 + h * 128 + og);
#pragma unroll
      for (int j = 0; j < 4; j++) dstp[j] = srcp[j];
    }
  }
}

// ---------------------------------------------------------------------------
// Fused depthwise 3x3 K/V from bf16 NHWC tkv — v3: column-streaming with
// 64-px strips + padded vv rows (full 128-B-line V writes) + XCD swizzle.
//   - Each wave owns 16 consecutive px (two 8-px column streams); a column
//     (3 vertical uint2 taps) loads once and feeds 3 px x 3 rows in regs.
//   - vv gets row stride HXP=256 so each (ch,row) 64-px strip segment is a
//     whole aligned 128-B line written by ONE block -> no RMW/read-allocate.
//   - Block-id swizzle: each XCD gets a contiguous vertical run of row-pairs
//     (halo rows then reuse that XCD's L2).
// Grid (496, 2), block 256. Strip 3 covers px 192..255 (248..255 = pad,
// compute skipped, V pad cols written with garbage, never read).
// ---------------------------------------------------------------------------
template <bool VT, bool VB>
static __device__ __forceinline__ void dwkv_row(
    const unsigned short* __restrict__ r0, const unsigned short* __restrict__ r1,
    const unsigned short* __restrict__ r2, const f32x2 (&wp)[9][2],
    int px0, f32x2 (&acc)[8][2]) {
  const f32x2 z2 = {0.f, 0.f};
#pragma unroll
  for (int p = 0; p < 8; p++) { acc[p][0] = z2; acc[p][1] = z2; }
#pragma unroll
  for (int j = 0; j < 10; j++) {
    int xcol = px0 - 1 + j;
    int xc = xcol;
    if (j == 0) xc = (xcol < 0) ? 0 : xcol;
    if (j == 9) xc = (xcol > HX - 1) ? HX - 1 : xcol;
    size_t off = (size_t)xc * 256;
    uint2 u1 = *(const uint2*)(r1 + off);
    uint2 u0, u2;
    if constexpr (VT) u0 = *(const uint2*)(r0 + off);
    if constexpr (VB) u2 = *(const uint2*)(r2 + off);
    if (j == 0 || j == 9) {  // only edge columns can be out of range
      bool oob = (j == 0) ? (xcol < 0) : (xcol > HX - 1);
      if (oob) {
        u1.x = 0u; u1.y = 0u;
        if constexpr (VT) { u0.x = 0u; u0.y = 0u; }
        if constexpr (VB) { u2.x = 0u; u2.y = 0u; }
      }
    }
    f32x2 d1a = unp(u1.x), d1b = unp(u1.y);
    f32x2 d0a, d0b, d2a, d2b;
    if constexpr (VT) { d0a = unp(u0.x); d0b = unp(u0.y); }
    if constexpr (VB) { d2a = unp(u2.x); d2b = unp(u2.y); }
    // this column is: LEFT tap (w col 0) of px j, CENTER (w col 1) of px j-1,
    // RIGHT (w col 2) of px j-2.  w rows: top=t, mid=3+t, bot=6+t.
    if (j <= 7) {
      if constexpr (VT) { pkfma(acc[j][0], wp[0][0], d0a); pkfma(acc[j][1], wp[0][1], d0b); }
      pkfma(acc[j][0], wp[3][0], d1a); pkfma(acc[j][1], wp[3][1], d1b);
      if constexpr (VB) { pkfma(acc[j][0], wp[6][0], d2a); pkfma(acc[j][1], wp[6][1], d2b); }
    }
    if (j >= 1 && j <= 8) {
      if constexpr (VT) { pkfma(acc[j - 1][0], wp[1][0], d0a); pkfma(acc[j - 1][1], wp[1][1], d0b); }
      pkfma(acc[j - 1][0], wp[4][0], d1a); pkfma(acc[j - 1][1], wp[4][1], d1b);
      if constexpr (VB) { pkfma(acc[j - 1][0], wp[7][0], d2a); pkfma(acc[j - 1][1], wp[7][1], d2b); }
    }
    if (j >= 2) {
      if constexpr (VT) { pkfma(acc[j - 2][0], wp[2][0], d0a); pkfma(acc[j - 2][1], wp[2][1], d0b); }
      pkfma(acc[j - 2][0], wp[5][0], d1a); pkfma(acc[j - 2][1], wp[5][1], d1b);
      if constexpr (VB) { pkfma(acc[j - 2][0], wp[8][0], d2a); pkfma(acc[j - 2][1], wp[8][1], d2b); }
    }
  }
}

__global__ __launch_bounds__(256, 4) void dwconv_kv_kernel(const unsigned short* __restrict__ tkv,
                                                           const float* __restrict__ w,
                                                           unsigned short* __restrict__ kT,
                                                           unsigned short* __restrict__ vv) {
  // XCD swizzle: fid -> (strip, g) such that each XCD owns a contiguous
  // vertical run of row-pairs within one strip. 496 = 8 XCDs * 62 slots.
  int fid = blockIdx.x;
  int xcd = fid & 7, slot = fid >> 3;
  int gi = xcd * 62 + slot;          // 0..495
  int strip = gi / 124;              // 0..3
  int g = gi % 124;                  // row-pair index
  int b = blockIdx.y;
  int x0 = strip * 64;
  int tid = threadIdx.x;
  int cq = tid & 63;                 // channel quad (lane)
  int pg = tid >> 6;                 // wave id
  int ch0 = cq * 4;

  f32x2 wp[9][2];
#pragma unroll
  for (int t = 0; t < 9; t++) {
    wp[t][0].x = w[(ch0 + 0) * 9 + t];
    wp[t][0].y = w[(ch0 + 1) * 9 + t];
    wp[t][1].x = w[(ch0 + 2) * 9 + t];
    wp[t][1].y = w[(ch0 + 3) * 9 + t];
  }

  __shared__ unsigned short vt[128 * 67];      // [ch][64px] stride 67 (16.75 KB)
  const unsigned short* base = tkv + (size_t)b * HXW * 256 + ch0;

#pragma unroll 1
  for (int r = 0; r < 2; r++) {
    int hy = g * 2 + r;
    const unsigned short* r1 = base + (size_t)hy * (HX * 256);
    const unsigned short* r0 = (hy > 0) ? (r1 - HX * 256) : r1;
    const unsigned short* r2 = (hy < HX - 1) ? (r1 + HX * 256) : r1;

#pragma unroll
    for (int half = 0; half < 2; half++) {
      int px0 = x0 + pg * 16 + half * 8;
      if (px0 < HX) {  // strip 3 / wave 3 / half 1 -> pure pad, skip
        f32x2 acc[8][2];
        if (hy == 0)            dwkv_row<false, true >(r0, r1, r2, wp, px0, acc);
        else if (hy == HX - 1)  dwkv_row<true,  false>(r0, r1, r2, wp, px0, acc);
        else                    dwkv_row<true,  true >(r0, r1, r2, wp, px0, acc);

        if (cq < 32) {  // K half: direct NHWC store, packed bf16 convert
          unsigned short* kb = kT + ((size_t)b * HXW + (size_t)hy * HX + px0) * 128 + ch0;
#pragma unroll
          for (int p = 0; p < 8; p++) {
            uint2 d;
            d.x = cvtpk(acc[p][0].x, acc[p][0].y);
            d.y = cvtpk(acc[p][1].x, acc[p][1].y);
            *(uint2*)(kb + (size_t)p * 128) = d;
          }
        } else {        // V half: stage transposed into LDS
          int c0 = ch0 - 128;
          int pxr = pg * 16 + half * 8;
#pragma unroll
          for (int p = 0; p < 8; p++) {
            vt[(c0 + 0) * 67 + pxr + p] = f2bf(acc[p][0].x);
            vt[(c0 + 1) * 67 + pxr + p] = f2bf(acc[p][0].y);
            vt[(c0 + 2) * 67 + pxr + p] = f2bf(acc[p][1].x);
            vt[(c0 + 3) * 67 + pxr + p] = f2bf(acc[p][1].y);
          }
        }
      }
    }
    __syncthreads();
    {  // cooperative NCHW store of the V row: 64 px = one full 128-B line
      int cv = tid & 127;
      int phx = (tid >> 7) * 32;
      unsigned short* dst = vv + (size_t)(b * 128 + cv) * HXWP + (size_t)hy * HXP + x0 + phx;
      const unsigned short* srcv = vt + cv * 67 + phx;
#pragma unroll
      for (int jj = 0; jj < 8; jj++) {
        uint2 d;
        d.x = (uint32_t)srcv[jj * 4 + 0] | ((uint32_t)srcv[jj * 4 + 1] << 16);
        d.y = (uint32_t)srcv[jj * 4 + 2] | ((uint32_t)srcv[jj * 4 + 3] << 16);
        *(uint2*)(dst + jj * 4) = d;
      }
    }
    __syncthreads();
  }
}

// ---------------------------------------------------------------------------
// 1x1 conv tiled SGEMM (fp32) — small tensors (q path, output projection).
// ---------------------------------------------------------------------------
template <int O>
__global__ __launch_bounds__(256) void conv1_kernel(const float* __restrict__ x,
                                                    const float* __restrict__ w,
                                                    float* __restrict__ y, int HW) {
  constexpr int K = 128;
  constexpr int BK = 32;
  __shared__ __align__(16) float ws_s[BK][64];
  __shared__ __align__(16) float xs_s[BK][64];
  int b = blockIdx.z;
  int o0 = blockIdx.y * 64;
  int p0 = blockIdx.x * 64;
  const float* xb = x + (size_t)b * K * HW;
  int tx = threadIdx.x & 15;
  int ty = threadIdx.x >> 4;
  float acc[4][4] = {};
  int lo = threadIdx.x >> 2;
  int lk = (threadIdx.x & 3) * 8;
  int lc = threadIdx.x >> 3;
  int lp = (threadIdx.x & 7) * 8;

  for (int k0 = 0; k0 < K; k0 += BK) {
    __syncthreads();
    {
      const float* wp = w + (size_t)(o0 + lo) * K + k0 + lk;
      float4 a = *(const float4*)wp;
      float4 bq = *(const float4*)(wp + 4);
      ws_s[lk + 0][lo] = a.x;  ws_s[lk + 1][lo] = a.y;
      ws_s[lk + 2][lo] = a.z;  ws_s[lk + 3][lo] = a.w;
      ws_s[lk + 4][lo] = bq.x; ws_s[lk + 5][lo] = bq.y;
      ws_s[lk + 6][lo] = bq.z; ws_s[lk + 7][lo] = bq.w;
    }
    {
      int p = p0 + lp;
      const float* xp = xb + (size_t)(k0 + lc) * HW;
      float4 a, bq;
      if (p + 7 < HW) {
        a = *(const float4*)(xp + p);
        bq = *(const float4*)(xp + p + 4);
      } else {
        float tv[8];
#pragma unroll
        for (int j = 0; j < 8; j++) tv[j] = (p + j < HW) ? xp[p + j] : 0.0f;
        a = make_float4(tv[0], tv[1], tv[2], tv[3]);
        bq = make_float4(tv[4], tv[5], tv[6], tv[7]);
      }
      *(float4*)&xs_s[lc][lp] = a;
      *(float4*)&xs_s[lc][lp + 4] = bq;
    }
    __syncthreads();
#pragma unroll
    for (int k = 0; k < BK; k++) {
      float4 wv = *(const float4*)&ws_s[k][ty * 4];
      float4 xv = *(const float4*)&xs_s[k][tx * 4];
      acc[0][0] += wv.x * xv.x; acc[0][1] += wv.x * xv.y; acc[0][2] += wv.x * xv.z; acc[0][3] += wv.x * xv.w;
      acc[1][0] += wv.y * xv.x; acc[1][1] += wv.y * xv.y; acc[1][2] += wv.y * xv.z; acc[1][3] += wv.y * xv.w;
      acc[2][0] += wv.z * xv.x; acc[2][1] += wv.z * xv.y; acc[2][2] += wv.z * xv.z; acc[2][3] += wv.z * xv.w;
      acc[3][0] += wv.w * xv.x; acc[3][1] += wv.w * xv.y; acc[3][2] += wv.w * xv.z; acc[3][3] += wv.w * xv.w;
    }
  }
  int p = p0 + tx * 4;
  float* yb = y + (size_t)b * O * HW + (size_t)(o0 + ty * 4) * HW;
#pragma unroll
  for (int j = 0; j < 4; j++) {
    float* yr = yb + (size_t)j * HW + p;
    if (p + 3 < HW) {
      *(float4*)yr = make_float4(acc[j][0], acc[j][1], acc[j][2], acc[j][3]);
    } else {
#pragma unroll
      for (int e = 0; e < 4; e++) if (p + e < HW) yr[e] = acc[j][e];
    }
  }
}

// ---------------------------------------------------------------------------
// MFMA windowed attention, head-pair blocks. 512 thr = 8 waves.
// V now has padded strides: row HXP, plane HXWP.
// ---------------------------------------------------------------------------
__global__ __launch_bounds__(512) void attn_mfma_kernel(
    const unsigned short* __restrict__ qn,   // (2,62,62,128) bf16, pre-scaled
    const unsigned short* __restrict__ kT,   // (2,248,248,128) bf16 NHWC
    const unsigned short* __restrict__ vp,   // (2,128,248,256p) bf16 NCHW padded
    float* __restrict__ o) {
  int n = blockIdx.x, hp = blockIdx.y, b = blockIdx.z;
  int wi = n / 10, wj = n % 10;
  int wave = threadIdx.x >> 6;
  int hd = wave & 1, oct = wave >> 1;
  int h = hp * 2 + hd;
  int lane = threadIdx.x & 63;
  int quad = lane >> 4;
  int l15 = lane & 15;
  int y0 = 24 * wi, x0 = 24 * wj;

  __shared__ __align__(16) unsigned short lds[20480];  // 40,960 B
  unsigned short* Pw = lds + wave * 2560;              // [q][40keys] 5KB/wave

  bf16x8 QB[4];
#pragma unroll
  for (int nt = 0; nt < 4; nt++) {
    int qq = nt * 16 + l15;
    int qy = 6 * wi + (qq >> 3), qx = 6 * wj + (qq & 7);
    QB[nt] = __builtin_bit_cast(bf16x8,
        *(const uint4*)(qn + ((size_t)(b * HSW + qy * HS + qx)) * 128 + h * 32 + quad * 8));
  }

  f32x4 Oacc[2][4];
#pragma unroll
  for (int a = 0; a < 2; a++)
#pragma unroll
    for (int c = 0; c < 4; c++) Oacc[a][c] = f32x4{0.f, 0.f, 0.f, 0.f};
  float lsum[4] = {0.f, 0.f, 0.f, 0.f};

  const unsigned short* kb = kT + (size_t)b * HXW * 128 + h * 32;
  const unsigned short* vb = vp + ((size_t)(b * 128 + h * 32)) * HXWP;
  const f32x4 zf = {0.f, 0.f, 0.f, 0.f};

#define LOADROW(r, K0, K1, V0, V1)                                              \
  {                                                                             \
    int y = y0 + (r);                                                           \
    const unsigned short* krow = kb + ((size_t)(y * HX + x0)) * 128;            \
    K0 = *(const uint4*)(krow + (size_t)l15 * 128 + quad * 8);                  \
    K1 = *(const uint4*)(krow + (size_t)(16 + l15) * 128 + quad * 8);           \
    const unsigned short* vrow = vb + (size_t)y * HXP + x0 + quad * 8;          \
    V0 = *(const uint4*)(vrow + (size_t)l15 * HXWP);                            \
    V1 = *(const uint4*)(vrow + (size_t)(16 + l15) * HXWP);                     \
  }

  auto compute = [&](uint4 k0, uint4 k1, uint4 v0, uint4 v1) {
    bf16x8 KA0 = __builtin_bit_cast(bf16x8, k0);
    bf16x8 KA1 = __builtin_bit_cast(bf16x8, k1);
    bf16x8 VA0 = __builtin_bit_cast(bf16x8, v0);
    bf16x8 VA1 = __builtin_bit_cast(bf16x8, v1);
    f32x4 S[2][4];
#pragma unroll
    for (int nt = 0; nt < 4; nt++) {
      S[0][nt] = __builtin_amdgcn_mfma_f32_16x16x32_bf16(KA0, QB[nt], zf, 0, 0, 0);
      S[1][nt] = __builtin_amdgcn_mfma_f32_16x16x32_bf16(KA1, QB[nt], zf, 0, 0, 0);
    }
#pragma unroll
    for (int nt = 0; nt < 4; nt++) {
      float pv[2][4];
      float cs = 0.f;
#pragma unroll
      for (int mt = 0; mt < 2; mt++)
#pragma unroll
        for (int r = 0; r < 4; r++) {
          pv[mt][r] = __expf(S[mt][nt][r]);
          cs += pv[mt][r];
        }
      lsum[nt] += cs;
#pragma unroll
      for (int mt = 0; mt < 2; mt++) {
        uint2 d;
        d.x = (uint32_t)f2bf(pv[mt][0]) | ((uint32_t)f2bf(pv[mt][1]) << 16);
        d.y = (uint32_t)f2bf(pv[mt][2]) | ((uint32_t)f2bf(pv[mt][3]) << 16);
        *(uint2*)(Pw + (16 * nt + l15) * 40 + 16 * mt + quad * 4) = d;
      }
    }
#pragma unroll
    for (int nt = 0; nt < 4; nt++) {
      bf16x8 PB = __builtin_bit_cast(bf16x8, *(const uint4*)(Pw + (16 * nt + l15) * 40 + quad * 8));
      Oacc[0][nt] = __builtin_amdgcn_mfma_f32_16x16x32_bf16(VA0, PB, Oacc[0][nt], 0, 0, 0);
      Oacc[1][nt] = __builtin_amdgcn_mfma_f32_16x16x32_bf16(VA1, PB, Oacc[1][nt], 0, 0, 0);
    }
  };

  int rbase = oct * 8;
  uint4 kA0, kA1, vA0, vA1, kB0, kB1, vB0, vB1;
  LOADROW(rbase + 0, kA0, kA1, vA0, vA1);
  LOADROW(rbase + 1, kB0, kB1, vB0, vB1);
#pragma unroll 1
  for (int r = 0; r < 8; r += 2) {
    compute(kA0, kA1, vA0, vA1);
    {
      int rn = (r + 2 < 8) ? (r + 2) : 6;  // clamped, branch-free
      LOADROW(rbase + rn, kA0, kA1, vA0, vA1);
    }
    compute(kB0, kB1, vB0, vB1);
    {
      int rn = (r + 3 < 8) ? (r + 3) : 7;  // clamped, branch-free
      LOADROW(rbase + rn, kB0, kB1, vB0, vB1);
    }
  }
#undef LOADROW

#pragma unroll
  for (int nt = 0; nt < 4; nt++) {
    lsum[nt] += __shfl_xor(lsum[nt], 16, 64);
    lsum[nt] += __shfl_xor(lsum[nt], 32, 64);
  }

  float* mO = (float*)lds;                 // [oct][32ch][64q]  32 KB
  float* mL = (float*)(lds + 16384);       // [oct][64q]
#pragma unroll 1
  for (int p = 0; p < 2; p++) {
    __syncthreads();
    if (hd == p) {
#pragma unroll
      for (int mt = 0; mt < 2; mt++)
#pragma unroll
        for (int nt = 0; nt < 4; nt++)
#pragma unroll
          for (int r = 0; r < 4; r++)
            mO[oct * 2048 + (16 * mt + quad * 4 + r) * 64 + 16 * nt + l15] = Oacc[mt][nt][r];
      if (quad == 0) {
#pragma unroll
        for (int nt = 0; nt < 4; nt++) mL[oct * 64 + nt * 16 + l15] = lsum[nt];
      }
    }
    __syncthreads();
    {
      int q = threadIdx.x & 63;
      int cg = threadIdx.x >> 6;  // 0..7 -> 4 ch each
      float inv = 1.0f / (mL[q] + mL[64 + q] + mL[128 + q] + mL[192 + q]);
      float* ob = o + (((size_t)(b * 100 + n)) * 128 + (hp * 2 + p) * 32 + cg * 4) * 64 + q;
#pragma unroll
      for (int e = 0; e < 4; e++) {
        int ch = cg * 4 + e;
        float s = mO[ch * 64 + q] + mO[2048 + ch * 64 + q] +
                  mO[4096 + ch * 64 + q] + mO[6144 + ch * 64 + q];
        ob[(size_t)e * 64] = s * inv;
      }
    }
  }
}

// ---------------------------------------------------------------------------
// Reverse: scatter-average overlapping 8x8 windows (step 6) into (2,128,62,62)
// ---------------------------------------------------------------------------
__global__ void reverse_kernel(const float* __restrict__ win, float* __restrict__ out) {
  int i = blockIdx.x * 256 + threadIdx.x;
  const int total = 2 * 128 * HSW;
  if (i >= total) return;
  int x = i % HS;
  int t = i / HS;
  int y = t % HS;
  t /= HS;
  int c = t % 128;
  int b = t / 128;
  int wi0 = (y >= 7) ? (y - 2) / 6 : 0;
  int wi1 = min(9, y / 6);
  int wj0 = (x >= 7) ? (x - 2) / 6 : 0;
  int wj1 = min(9, x / 6);
  float s = 0.0f;
  for (int wi = wi0; wi <= wi1; wi++)
    for (int wj = wj0; wj <= wj1; wj++) {
      int di = y - 6 * wi, dj = x - 6 * wj;
      s += win[(((size_t)(b * 100 + wi * 10 + wj)) * 128 + c) * 64 + di * 8 + dj];
    }
  float cnt = (float)((wi1 - wi0 + 1) * (wj1 - wj0 + 1));
  out[i] = s / cnt;
}

// ---------------------------------------------------------------------------
extern "C" void kernel_launch(void* const* d_in, const int* in_sizes, int n_in,
                              void* d_out, int out_size, void* d_ws, size_t ws_size,
                              hipStream_t stream) {
  const float* x      = (const float*)d_in[0];
  const float* sp     = (const float*)d_in[1];
  const float* w_pos  = (const float*)d_in[2];
  const float* b_pos  = (const float*)d_in[3];
  const float* w_q    = (const float*)d_in[4];
  const float* w_qdw  = (const float*)d_in[5];
  const float* w_kv   = (const float*)d_in[6];
  const float* w_kvdw = (const float*)d_in[7];
  const float* w_out  = (const float*)d_in[8];
  float* out = (float*)d_out;

  const size_t N_x   = (size_t)2 * 128 * HXW;   // 15,745,024 (shorts for kT/xpb)
  const size_t N_vp  = (size_t)2 * 128 * HXWP;  // 16,252,928 (padded vv, shorts)
  const size_t N_s   = (size_t)2 * 128 * HSW;
  const size_t N_att = (size_t)2 * 100 * 128 * 64;

  float* ws = (float*)d_ws;
  // shorts-based layout (all counts even -> float-aligned):
  unsigned short* xpb = (unsigned short*)ws;          // N_x shorts, dead after step 5
  unsigned short* kT  = (unsigned short*)ws;          // N_x shorts (overwrites xpb)
  unsigned short* vv  = kT + N_x;                     // N_vp shorts (padded rows)
  unsigned short* tkv = vv + N_vp;                    // 2*N_x shorts
  float* att = (float*)tkv;                           // reuse (tkv dead after step 6)
  float* rev = att + N_att;
  float* spp = (float*)(tkv + 2 * N_x);
  float* tq  = spp + N_s;
  unsigned short* qn  = (unsigned short*)(tq + N_s);  // N_s shorts
  unsigned short* wkb = qn + N_s;                     // 32768 shorts
  (void)ws_size; (void)in_sizes; (void)n_in; (void)out_size;

  // 0. wkb = bf16(w_kv)
  cvt_bf16_kernel<<<128, 256, 0, stream>>>(w_kv, wkb, 256 * 128);
  // 1. xpb = bf16(x + dwconv3(x, w_pos, b_pos))   (bf16 NCHW)
  {
    int total4 = (int)(N_x / 4);
    dwconv4_bf16_kernel<<<(total4 + 255) / 256, 256, 0, stream>>>(x, w_pos, b_pos, xpb, total4);
  }
  // 2. spp = sp + dwconv3(sp, w_pos, b_pos)
  {
    int total = (int)N_s;
    dwconv3_kernel<<<(total + 255) / 256, 256, 0, stream>>>(sp, w_pos, b_pos, spp, 128, HS, HS, total, 1);
  }
  // 3. tq = conv1(spp, w_q)
  {
    int HW = HSW;
    dim3 grid((HW + 63) / 64, 2, 2);
    conv1_kernel<128><<<grid, 256, 0, stream>>>(spp, w_q, tq, HW);
  }
  // 4. qn = bf16_nhwc(dwconv3(tq, w_qdw)) * 32^-0.5
  {
    int total = (int)N_s;
    dwconv_q_kernel<<<(total + 255) / 256, 256, 0, stream>>>(tq, w_qdw, qn, total);
  }
  // 5. tkv = bf16_nhwc(mfma_conv1(xpb, wkb))   (xpb dead after)
  {
    dim3 grid(HXW / 64, 2);
    conv1_kv_mfma_kernel<<<grid, 256, 0, stream>>>(xpb, wkb, tkv);
  }
  // 6. kT (NHWC) + vv (NCHW padded) = bf16(dwconv3(tkv, w_kvdw)) (overwrites xpb)
  {
    dim3 grid(496, 2);
    dwconv_kv_kernel<<<grid, 256, 0, stream>>>(tkv, w_kvdw, kT, vv);
  }
  // 7. attention -> att (2,100,128,64)
  {
    dim3 grid(100, 2, 2);
    attn_mfma_kernel<<<grid, 512, 0, stream>>>(qn, kT, vv, att);
  }
  // 8. rev = reverse(att)
  {
    int total = (int)N_s;
    reverse_kernel<<<(total + 255) / 256, 256, 0, stream>>>(att, rev);
  }
  // 9. out = conv1(rev, w_out)
  {
    int HW = HSW;
    dim3 grid((HW + 63) / 64, 2, 2);
    conv1_kernel<128><<<grid, 256, 0, stream>>>(rev, w_out, out, HW);
  }
}

// Round 3
// 284.704 us; speedup vs baseline: 1.1353x; 1.1317x over previous
//
#include <hip/hip_runtime.h>
#include <cstdint>

#define HS 62
#define HX 248
#define HXW (HX * HX)  // 61504
#define HSW (HS * HS)  // 3844
#define HXP 256        // padded row stride for vv (128-B aligned rows)
#define HXWP (HX * HXP)  // 63488 padded plane

typedef __attribute__((ext_vector_type(8))) short bf16x8;
typedef __attribute__((ext_vector_type(4))) float f32x4;
typedef __attribute__((ext_vector_type(2))) float f32x2;

static __device__ __forceinline__ unsigned short f2bf(float f) {
  uint32_t u = __builtin_bit_cast(uint32_t, f);
  u += 0x7fff + ((u >> 16) & 1);  // RNE
  return (unsigned short)(u >> 16);
}
static __device__ __forceinline__ float bf2f(unsigned short u) {
  uint32_t x = (uint32_t)u << 16;
  return __builtin_bit_cast(float, x);
}
static __device__ __forceinline__ float bflo(uint32_t u) {
  return __builtin_bit_cast(float, u << 16);
}
static __device__ __forceinline__ float bfhi(uint32_t u) {
  return __builtin_bit_cast(float, u & 0xffff0000u);
}

// packed fp32 FMA: acc = a*b + acc (2 lanes of fp32, CDNA v_pk_fma_f32)
static __device__ __forceinline__ void pkfma(f32x2& acc, f32x2 a, f32x2 b) {
  asm("v_pk_fma_f32 %0, %1, %2, %0" : "+v"(acc) : "v"(a), "v"(b));
}
// packed f32->bf16 RNE convert: returns (bf16(lo) | bf16(hi)<<16)
static __device__ __forceinline__ uint32_t cvtpk(float lo, float hi) {
  uint32_t r;
  asm("v_cvt_pk_bf16_f32 %0, %1, %2" : "=v"(r) : "v"(lo), "v"(hi));
  return r;
}
// unpack u32 holding 2 bf16 -> packed f32 pair
static __device__ __forceinline__ f32x2 unp(uint32_t u) {
  f32x2 r;
  r.x = __builtin_bit_cast(float, u << 16);
  r.y = __builtin_bit_cast(float, u & 0xffff0000u);
  return r;
}

// ---------------------------------------------------------------------------
// Depthwise 3x3 scalar (62x62 tensors), fp32 out, bias+residual.
// ---------------------------------------------------------------------------
__global__ void dwconv3_kernel(const float* __restrict__ x, const float* __restrict__ w,
                               const float* __restrict__ bias, float* __restrict__ y,
                               int C, int H, int W, int total, int residual) {
  int i = blockIdx.x * 256 + threadIdx.x;
  if (i >= total) return;
  int wx = i % W;
  int t = i / W;
  int hy = t % H;
  int bc = t / H;
  int c = bc % C;
  const float* xb = x + (size_t)bc * H * W;
  const float* wc = w + c * 9;
  float s = bias ? bias[c] : 0.0f;
  for (int di = -1; di <= 1; di++) {
    int h2 = hy + di;
    if (h2 < 0 || h2 >= H) continue;
    for (int dj = -1; dj <= 1; dj++) {
      int w2 = wx + dj;
      if (w2 < 0 || w2 >= W) continue;
      s += xb[(size_t)h2 * W + w2] * wc[(di + 1) * 3 + (dj + 1)];
    }
  }
  if (residual) s += xb[(size_t)hy * W + wx];
  y[i] = s;
}

// ---------------------------------------------------------------------------
// Depthwise 3x3 x-path: fp32 NCHW in -> bf16 NCHW out, residual. 4 px/thread.
// ---------------------------------------------------------------------------
__global__ void dwconv4_bf16_kernel(const float* __restrict__ x, const float* __restrict__ w,
                                    const float* __restrict__ bias,
                                    unsigned short* __restrict__ y, int total4) {
  int i = blockIdx.x * 256 + threadIdx.x;
  if (i >= total4) return;
  int W4 = HX >> 2;
  int wq = (i % W4) * 4;
  int t = i / W4;
  int hy = t % HX;
  int bc = t / HX;
  int c = bc & 127;
  const float* xb = x + (size_t)bc * HXW;
  const float* wc = w + c * 9;
  float bv = bias[c];
  float s0 = bv, s1 = bv, s2 = bv, s3 = bv;
  for (int di = -1; di <= 1; di++) {
    int h2 = hy + di;
    if (h2 < 0 || h2 >= HX) continue;
    const float* row = xb + (size_t)h2 * HX + wq;
    float4 cv = *(const float4*)row;
    float lf = (wq > 0) ? row[-1] : 0.0f;
    float rt = (wq + 4 < HX) ? row[4] : 0.0f;
    float w0 = wc[(di + 1) * 3 + 0];
    float w1 = wc[(di + 1) * 3 + 1];
    float w2 = wc[(di + 1) * 3 + 2];
    s0 += w0 * lf   + w1 * cv.x + w2 * cv.y;
    s1 += w0 * cv.x + w1 * cv.y + w2 * cv.z;
    s2 += w0 * cv.y + w1 * cv.z + w2 * cv.w;
    s3 += w0 * cv.z + w1 * cv.w + w2 * rt;
  }
  {
    float4 cc = *(const float4*)(xb + (size_t)hy * HX + wq);
    s0 += cc.x; s1 += cc.y; s2 += cc.z; s3 += cc.w;
  }
  uint2 d;
  d.x = (uint32_t)f2bf(s0) | ((uint32_t)f2bf(s1) << 16);
  d.y = (uint32_t)f2bf(s2) | ((uint32_t)f2bf(s3) << 16);
  *(uint2*)(y + (size_t)bc * HXW + (size_t)hy * HX + wq) = d;
}

// ---------------------------------------------------------------------------
// fp32 -> bf16 flat convert (for w_kv).
// ---------------------------------------------------------------------------
__global__ void cvt_bf16_kernel(const float* __restrict__ src, unsigned short* __restrict__ dst,
                                int n) {
  int i = blockIdx.x * 256 + threadIdx.x;
  if (i < n) dst[i] = f2bf(src[i]);
}

// ---------------------------------------------------------------------------
// Depthwise 3x3 q path: fp32 NCHW in -> bf16 NHWC out, pre-scaled by 32^-0.5.
// ---------------------------------------------------------------------------
__global__ void dwconv_q_kernel(const float* __restrict__ x, const float* __restrict__ w,
                                unsigned short* __restrict__ qn, int total) {
  int i = blockIdx.x * 256 + threadIdx.x;
  if (i >= total) return;
  int wx = i % HS;
  int t = i / HS;
  int hy = t % HS;
  int bc = t / HS;
  int c = bc & 127;
  int b = bc >> 7;
  const float* xb = x + (size_t)bc * HSW;
  const float* wc = w + c * 9;
  float s = 0.0f;
  for (int di = -1; di <= 1; di++) {
    int h2 = hy + di;
    if (h2 < 0 || h2 >= HS) continue;
    for (int dj = -1; dj <= 1; dj++) {
      int w2 = wx + dj;
      if (w2 < 0 || w2 >= HS) continue;
      s += xb[(size_t)h2 * HS + w2] * wc[(di + 1) * 3 + (dj + 1)];
    }
  }
  qn[((size_t)(b * HSW + hy * HS + wx)) * 128 + c] = f2bf(s * 0.17677669529663688f);
}

// ---------------------------------------------------------------------------
// MFMA 1x1 conv kv path, v3: weights staged in LDS per 64-o quarter.
// Block = 64 px x 256 o, 4 waves. Grid (961, 2).
// ---------------------------------------------------------------------------
__global__ __launch_bounds__(256) void conv1_kv_mfma_kernel(
    const unsigned short* __restrict__ xpb,  // (2,128,61504) bf16 NCHW
    const unsigned short* __restrict__ wkb,  // (256,128) bf16
    unsigned short* __restrict__ y) {        // (2,61504,256) bf16 NHWC
  int b = blockIdx.y;
  int p0 = blockIdx.x * 64;
  int tid = threadIdx.x;
  int wave = tid >> 6, lane = tid & 63, quad = lane >> 4, l15 = lane & 15;
  __shared__ __align__(16) unsigned short bufA[64 * 136];  // 17,408 B
  __shared__ __align__(16) unsigned short bufW[64 * 136];  // 17,408 B

  // phase 1: stage X-tile as bufA[px][c], stride 136
  {
    int c = tid >> 1, half = tid & 1;
    const unsigned short* src = xpb + ((size_t)(b * 128 + c)) * HXW + p0 + half * 32;
#pragma unroll
    for (int j = 0; j < 8; j++) {
      uint2 v = *(const uint2*)(src + j * 4);
      int px = half * 32 + j * 4;
      bufA[(px + 0) * 136 + c] = (unsigned short)(v.x & 0xffff);
      bufA[(px + 1) * 136 + c] = (unsigned short)(v.x >> 16);
      bufA[(px + 2) * 136 + c] = (unsigned short)(v.y & 0xffff);
      bufA[(px + 3) * 136 + c] = (unsigned short)(v.y >> 16);
    }
  }
  __syncthreads();
  bf16x8 A[4];
#pragma unroll
  for (int kb = 0; kb < 4; kb++)
    A[kb] = __builtin_bit_cast(bf16x8,
        *(const uint4*)&bufA[(wave * 16 + l15) * 136 + kb * 32 + quad * 8]);
  // bufA becomes the output stage after the next barrier.

  const f32x4 zf = {0.f, 0.f, 0.f, 0.f};
#pragma unroll 1
  for (int h = 0; h < 2; h++) {
#pragma unroll 1
    for (int oq = 0; oq < 2; oq++) {
      __syncthreads();  // bufW reusable; (h>0: bufA flush complete)
      {  // cooperative coalesced load of one 64-o weight quarter -> bufW
        int orow = tid >> 2;          // 0..63
        int cseg = (tid & 3) * 32;    // 0,32,64,96
        const unsigned short* src = wkb + (size_t)(h * 128 + oq * 64 + orow) * 128 + cseg;
        unsigned short* dst = &bufW[orow * 136 + cseg];
        *(uint4*)(dst)      = *(const uint4*)(src);
        *(uint4*)(dst + 8)  = *(const uint4*)(src + 8);
        *(uint4*)(dst + 16) = *(const uint4*)(src + 16);
        *(uint4*)(dst + 24) = *(const uint4*)(src + 24);
      }
      __syncthreads();
#pragma unroll
      for (int ot = 0; ot < 4; ot++) {
        const unsigned short* wrow = &bufW[(ot * 16 + l15) * 136 + quad * 8];
        f32x4 D = zf;
        D = __builtin_amdgcn_mfma_f32_16x16x32_bf16(A[0], __builtin_bit_cast(bf16x8, *(const uint4*)(wrow)),      D, 0, 0, 0);
        D = __builtin_amdgcn_mfma_f32_16x16x32_bf16(A[1], __builtin_bit_cast(bf16x8, *(const uint4*)(wrow + 32)), D, 0, 0, 0);
        D = __builtin_amdgcn_mfma_f32_16x16x32_bf16(A[2], __builtin_bit_cast(bf16x8, *(const uint4*)(wrow + 64)), D, 0, 0, 0);
        D = __builtin_amdgcn_mfma_f32_16x16x32_bf16(A[3], __builtin_bit_cast(bf16x8, *(const uint4*)(wrow + 96)), D, 0, 0, 0);
#pragma unroll
        for (int r = 0; r < 4; r++)
          bufA[(wave * 16 + quad * 4 + r) * 136 + (oq * 4 + ot) * 16 + l15] = f2bf(D[r]);
      }
    }
    __syncthreads();
    {  // flush this o-half: 64 px x 128 o, coalesced
      int px = tid >> 2, og = (tid & 3) * 32;
      const uint4* srcp = (const uint4*)&bufA[px * 136 + og];
      uint4* dstp = (uint4*)(y + ((size_t)b * HXW + p0 + px) * 256 + h * 128 + og);
#pragma unroll
      for (int j = 0; j < 4; j++) dstp[j] = srcp[j];
    }
  }
}

// ---------------------------------------------------------------------------
// Fused depthwise 3x3 K/V from bf16 NHWC tkv — v4: 2-channel lanes, 512-thr
// blocks, fused row-pair column streaming.
//   - v3 post-mortem: VGPR snapped to 64 < ~95 live -> scratch spills
//     (+~40 MB write, +fetch, latency-bound). Fix: shrink per-lane state
//     (wp 36->18, 2ch/lane) and pin the 128-reg tier via waves_per_eu(4).
//   - Fused row-pair: 4 row-taps per column feed BOTH output rows (was 6),
//     1 barrier per block (was 4).
//   - Waves alternate K/V roles (wave-uniform store paths).
// Grid (496, 2), block 512.
// ---------------------------------------------------------------------------
template <bool VT, bool VB>
static __device__ __forceinline__ void dwkv_rowpair(
    const unsigned short* __restrict__ rm1, const unsigned short* __restrict__ r0,
    const unsigned short* __restrict__ r1, const unsigned short* __restrict__ r2,
    const f32x2 (&wp)[9], int px0, f32x2 (&a0)[8], f32x2 (&a1)[8]) {
  const f32x2 z2 = {0.f, 0.f};
#pragma unroll
  for (int p = 0; p < 8; p++) { a0[p] = z2; a1[p] = z2; }
#pragma unroll
  for (int j = 0; j < 10; j++) {
    int xcol = px0 - 1 + j;
    int xc = xcol;
    if (j == 0) xc = (xcol < 0) ? 0 : xcol;
    if (j == 9) xc = (xcol > HX - 1) ? HX - 1 : xcol;
    size_t off = (size_t)xc * 256;
    uint32_t um1 = 0, u0, u1, u2 = 0;
    u0 = *(const uint32_t*)(r0 + off);
    u1 = *(const uint32_t*)(r1 + off);
    if constexpr (VT) um1 = *(const uint32_t*)(rm1 + off);
    if constexpr (VB) u2 = *(const uint32_t*)(r2 + off);
    if (j == 0 || j == 9) {  // only edge columns can be out of range
      bool oob = (j == 0) ? (xcol < 0) : (xcol > HX - 1);
      if (oob) { um1 = 0u; u0 = 0u; u1 = 0u; u2 = 0u; }
    }
    f32x2 dm1, d0 = unp(u0), d1 = unp(u1), d2;
    if constexpr (VT) dm1 = unp(um1);
    if constexpr (VB) d2 = unp(u2);
    // column j: LEFT tap (h=0) of px j, CENTER (h=1) of px j-1, RIGHT (h=2)
    // of px j-2. out row0 taps rows (m1,0,1) = v(0,1,2); row1 taps (0,1,2).
    if (j <= 7) {
      if constexpr (VT) pkfma(a0[j], wp[0], dm1);
      pkfma(a0[j], wp[3], d0);
      pkfma(a0[j], wp[6], d1);
      pkfma(a1[j], wp[0], d0);
      pkfma(a1[j], wp[3], d1);
      if constexpr (VB) pkfma(a1[j], wp[6], d2);
    }
    if (j >= 1 && j <= 8) {
      if constexpr (VT) pkfma(a0[j - 1], wp[1], dm1);
      pkfma(a0[j - 1], wp[4], d0);
      pkfma(a0[j - 1], wp[7], d1);
      pkfma(a1[j - 1], wp[1], d0);
      pkfma(a1[j - 1], wp[4], d1);
      if constexpr (VB) pkfma(a1[j - 1], wp[7], d2);
    }
    if (j >= 2) {
      if constexpr (VT) pkfma(a0[j - 2], wp[2], dm1);
      pkfma(a0[j - 2], wp[5], d0);
      pkfma(a0[j - 2], wp[8], d1);
      pkfma(a1[j - 2], wp[2], d0);
      pkfma(a1[j - 2], wp[5], d1);
      if constexpr (VB) pkfma(a1[j - 2], wp[8], d2);
    }
  }
}

#define VTS 72                    // vt channel stride (shorts): 144 B, 16-B aligned
#define VTROW (128 * VTS + 16)    // vt row stride (shorts), +16 shifts banks

__global__ __launch_bounds__(512) __attribute__((amdgpu_waves_per_eu(4)))
void dwconv_kv_kernel(const unsigned short* __restrict__ tkv,
                      const float* __restrict__ w,
                      unsigned short* __restrict__ kT,
                      unsigned short* __restrict__ vv) {
  // XCD swizzle: consecutive fid round-robin across XCDs; give each XCD a
  // contiguous vertical run of row-pairs within one strip.
  int fid = blockIdx.x;
  int xcd = fid & 7, slot = fid >> 3;
  int gi = xcd * 62 + slot;          // 0..495
  int strip = gi / 124;              // 0..3
  int g = gi % 124;                  // row-pair index
  int b = blockIdx.y;
  int x0 = strip * 64;
  int tid = threadIdx.x;
  int cl = tid & 127;                // channel lane: ch = 2*cl, 2*cl+1
  int pg = tid >> 7;                 // 0..3 px-group (wave-pair uniform)
  int ch0 = cl * 2;
  int hy0 = g * 2;

  f32x2 wp[9];
#pragma unroll
  for (int t = 0; t < 9; t++) {
    wp[t].x = w[ch0 * 9 + t];
    wp[t].y = w[(ch0 + 1) * 9 + t];
  }

  __shared__ __align__(16) unsigned short vt[2 * VTROW];  // 36,928 B

  const unsigned short* r0 = tkv + (size_t)b * HXW * 256 + (size_t)hy0 * (HX * 256) + ch0;
  const unsigned short* r1 = r0 + HX * 256;
  const unsigned short* rm1 = r0 - HX * 256;   // deref only when VT
  const unsigned short* r2 = r1 + HX * 256;    // deref only when VB
  bool isK = (cl < 64);
  int c0 = ch0 - 128;                // V-lane channel base

#pragma unroll 1
  for (int half = 0; half < 2; half++) {
    int px0 = x0 + pg * 16 + half * 8;
    if (px0 < HX) {  // strip 3 / pg 3 / half 1 is pure pad: skip
      f32x2 a0[8], a1[8];
      if (g == 0)        dwkv_rowpair<false, true >(rm1, r0, r1, r2, wp, px0, a0, a1);
      else if (g == 123) dwkv_rowpair<true,  false>(rm1, r0, r1, r2, wp, px0, a0, a1);
      else               dwkv_rowpair<true,  true >(rm1, r0, r1, r2, wp, px0, a0, a1);

      if (isK) {  // K rows: direct NHWC store, 2 ch packed per dword
        unsigned short* kb0 = kT + ((size_t)b * HXW + (size_t)hy0 * HX + px0) * 128 + ch0;
        unsigned short* kb1 = kb0 + (size_t)HX * 128;
#pragma unroll
        for (int p = 0; p < 8; p++) {
          *(uint32_t*)(kb0 + (size_t)p * 128) = cvtpk(a0[p].x, a0[p].y);
          *(uint32_t*)(kb1 + (size_t)p * 128) = cvtpk(a1[p].x, a1[p].y);
        }
      } else {    // V rows: stage transposed [row][ch][px] into LDS
        int pxr = pg * 16 + half * 8;
        unsigned short* v0 = vt + c0 * VTS + pxr;        // ch c0, row 0
        unsigned short* v1 = v0 + VTS;                   // ch c0+1
        uint2 d;
        d.x = cvtpk(a0[0].x, a0[1].x); d.y = cvtpk(a0[2].x, a0[3].x);
        *(uint2*)(v0) = d;
        d.x = cvtpk(a0[4].x, a0[5].x); d.y = cvtpk(a0[6].x, a0[7].x);
        *(uint2*)(v0 + 4) = d;
        d.x = cvtpk(a0[0].y, a0[1].y); d.y = cvtpk(a0[2].y, a0[3].y);
        *(uint2*)(v1) = d;
        d.x = cvtpk(a0[4].y, a0[5].y); d.y = cvtpk(a0[6].y, a0[7].y);
        *(uint2*)(v1 + 4) = d;
        d.x = cvtpk(a1[0].x, a1[1].x); d.y = cvtpk(a1[2].x, a1[3].x);
        *(uint2*)(v0 + VTROW) = d;
        d.x = cvtpk(a1[4].x, a1[5].x); d.y = cvtpk(a1[6].x, a1[7].x);
        *(uint2*)(v0 + VTROW + 4) = d;
        d.x = cvtpk(a1[0].y, a1[1].y); d.y = cvtpk(a1[2].y, a1[3].y);
        *(uint2*)(v1 + VTROW) = d;
        d.x = cvtpk(a1[4].y, a1[5].y); d.y = cvtpk(a1[6].y, a1[7].y);
        *(uint2*)(v1 + VTROW + 4) = d;
      }
    }
  }
  __syncthreads();
  {  // cooperative NCHW store of both V rows (full 128-B lines, padded rows)
    int ch = tid >> 2;
    int row = (tid >> 1) & 1;
    int ph = (tid & 1) * 32;
    const unsigned short* srcv = vt + row * VTROW + ch * VTS + ph;
    unsigned short* dst = vv + (size_t)(b * 128 + ch) * HXWP + (size_t)(hy0 + row) * HXP + x0 + ph;
#pragma unroll
    for (int j = 0; j < 4; j++)
      *(uint4*)(dst + j * 8) = *(const uint4*)(srcv + j * 8);
  }
}

// ---------------------------------------------------------------------------
// 1x1 conv tiled SGEMM (fp32) — small tensors (q path, output projection).
// ---------------------------------------------------------------------------
template <int O>
__global__ __launch_bounds__(256) void conv1_kernel(const float* __restrict__ x,
                                                    const float* __restrict__ w,
                                                    float* __restrict__ y, int HW) {
  constexpr int K = 128;
  constexpr int BK = 32;
  __shared__ __align__(16) float ws_s[BK][64];
  __shared__ __align__(16) float xs_s[BK][64];
  int b = blockIdx.z;
  int o0 = blockIdx.y * 64;
  int p0 = blockIdx.x * 64;
  const float* xb = x + (size_t)b * K * HW;
  int tx = threadIdx.x & 15;
  int ty = threadIdx.x >> 4;
  float acc[4][4] = {};
  int lo = threadIdx.x >> 2;
  int lk = (threadIdx.x & 3) * 8;
  int lc = threadIdx.x >> 3;
  int lp = (threadIdx.x & 7) * 8;

  for (int k0 = 0; k0 < K; k0 += BK) {
    __syncthreads();
    {
      const float* wp = w + (size_t)(o0 + lo) * K + k0 + lk;
      float4 a = *(const float4*)wp;
      float4 bq = *(const float4*)(wp + 4);
      ws_s[lk + 0][lo] = a.x;  ws_s[lk + 1][lo] = a.y;
      ws_s[lk + 2][lo] = a.z;  ws_s[lk + 3][lo] = a.w;
      ws_s[lk + 4][lo] = bq.x; ws_s[lk + 5][lo] = bq.y;
      ws_s[lk + 6][lo] = bq.z; ws_s[lk + 7][lo] = bq.w;
    }
    {
      int p = p0 + lp;
      const float* xp = xb + (size_t)(k0 + lc) * HW;
      float4 a, bq;
      if (p + 7 < HW) {
        a = *(const float4*)(xp + p);
        bq = *(const float4*)(xp + p + 4);
      } else {
        float tv[8];
#pragma unroll
        for (int j = 0; j < 8; j++) tv[j] = (p + j < HW) ? xp[p + j] : 0.0f;
        a = make_float4(tv[0], tv[1], tv[2], tv[3]);
        bq = make_float4(tv[4], tv[5], tv[6], tv[7]);
      }
      *(float4*)&xs_s[lc][lp] = a;
      *(float4*)&xs_s[lc][lp + 4] = bq;
    }
    __syncthreads();
#pragma unroll
    for (int k = 0; k < BK; k++) {
      float4 wv = *(const float4*)&ws_s[k][ty * 4];
      float4 xv = *(const float4*)&xs_s[k][tx * 4];
      acc[0][0] += wv.x * xv.x; acc[0][1] += wv.x * xv.y; acc[0][2] += wv.x * xv.z; acc[0][3] += wv.x * xv.w;
      acc[1][0] += wv.y * xv.x; acc[1][1] += wv.y * xv.y; acc[1][2] += wv.y * xv.z; acc[1][3] += wv.y * xv.w;
      acc[2][0] += wv.z * xv.x; acc[2][1] += wv.z * xv.y; acc[2][2] += wv.z * xv.z; acc[2][3] += wv.z * xv.w;
      acc[3][0] += wv.w * xv.x; acc[3][1] += wv.w * xv.y; acc[3][2] += wv.w * xv.z; acc[3][3] += wv.w * xv.w;
    }
  }
  int p = p0 + tx * 4;
  float* yb = y + (size_t)b * O * HW + (size_t)(o0 + ty * 4) * HW;
#pragma unroll
  for (int j = 0; j < 4; j++) {
    float* yr = yb + (size_t)j * HW + p;
    if (p + 3 < HW) {
      *(float4*)yr = make_float4(acc[j][0], acc[j][1], acc[j][2], acc[j][3]);
    } else {
#pragma unroll
      for (int e = 0; e < 4; e++) if (p + e < HW) yr[e] = acc[j][e];
    }
  }
}

// ---------------------------------------------------------------------------
// MFMA windowed attention, head-pair blocks. 512 thr = 8 waves.
// V has padded strides: row HXP, plane HXWP.
// ---------------------------------------------------------------------------
__global__ __launch_bounds__(512) void attn_mfma_kernel(
    const unsigned short* __restrict__ qn,   // (2,62,62,128) bf16, pre-scaled
    const unsigned short* __restrict__ kT,   // (2,248,248,128) bf16 NHWC
    const unsigned short* __restrict__ vp,   // (2,128,248,256p) bf16 NCHW padded
    float* __restrict__ o) {
  int n = blockIdx.x, hp = blockIdx.y, b = blockIdx.z;
  int wi = n / 10, wj = n % 10;
  int wave = threadIdx.x >> 6;
  int hd = wave & 1, oct = wave >> 1;
  int h = hp * 2 + hd;
  int lane = threadIdx.x & 63;
  int quad = lane >> 4;
  int l15 = lane & 15;
  int y0 = 24 * wi, x0 = 24 * wj;

  __shared__ __align__(16) unsigned short lds[20480];  // 40,960 B
  unsigned short* Pw = lds + wave * 2560;              // [q][40keys] 5KB/wave

  bf16x8 QB[4];
#pragma unroll
  for (int nt = 0; nt < 4; nt++) {
    int qq = nt * 16 + l15;
    int qy = 6 * wi + (qq >> 3), qx = 6 * wj + (qq & 7);
    QB[nt] = __builtin_bit_cast(bf16x8,
        *(const uint4*)(qn + ((size_t)(b * HSW + qy * HS + qx)) * 128 + h * 32 + quad * 8));
  }

  f32x4 Oacc[2][4];
#pragma unroll
  for (int a = 0; a < 2; a++)
#pragma unroll
    for (int c = 0; c < 4; c++) Oacc[a][c] = f32x4{0.f, 0.f, 0.f, 0.f};
  float lsum[4] = {0.f, 0.f, 0.f, 0.f};

  const unsigned short* kb = kT + (size_t)b * HXW * 128 + h * 32;
  const unsigned short* vb = vp + ((size_t)(b * 128 + h * 32)) * HXWP;
  const f32x4 zf = {0.f, 0.f, 0.f, 0.f};

#define LOADROW(r, K0, K1, V0, V1)                                              \
  {                                                                             \
    int y = y0 + (r);                                                           \
    const unsigned short* krow = kb + ((size_t)(y * HX + x0)) * 128;            \
    K0 = *(const uint4*)(krow + (size_t)l15 * 128 + quad * 8);                  \
    K1 = *(const uint4*)(krow + (size_t)(16 + l15) * 128 + quad * 8);           \
    const unsigned short* vrow = vb + (size_t)y * HXP + x0 + quad * 8;          \
    V0 = *(const uint4*)(vrow + (size_t)l15 * HXWP);                            \
    V1 = *(const uint4*)(vrow + (size_t)(16 + l15) * HXWP);                     \
  }

  auto compute = [&](uint4 k0, uint4 k1, uint4 v0, uint4 v1) {
    bf16x8 KA0 = __builtin_bit_cast(bf16x8, k0);
    bf16x8 KA1 = __builtin_bit_cast(bf16x8, k1);
    bf16x8 VA0 = __builtin_bit_cast(bf16x8, v0);
    bf16x8 VA1 = __builtin_bit_cast(bf16x8, v1);
    f32x4 S[2][4];
#pragma unroll
    for (int nt = 0; nt < 4; nt++) {
      S[0][nt] = __builtin_amdgcn_mfma_f32_16x16x32_bf16(KA0, QB[nt], zf, 0, 0, 0);
      S[1][nt] = __builtin_amdgcn_mfma_f32_16x16x32_bf16(KA1, QB[nt], zf, 0, 0, 0);
    }
#pragma unroll
    for (int nt = 0; nt < 4; nt++) {
      float pv[2][4];
      float cs = 0.f;
#pragma unroll
      for (int mt = 0; mt < 2; mt++)
#pragma unroll
        for (int r = 0; r < 4; r++) {
          pv[mt][r] = __expf(S[mt][nt][r]);
          cs += pv[mt][r];
        }
      lsum[nt] += cs;
#pragma unroll
      for (int mt = 0; mt < 2; mt++) {
        uint2 d;
        d.x = (uint32_t)f2bf(pv[mt][0]) | ((uint32_t)f2bf(pv[mt][1]) << 16);
        d.y = (uint32_t)f2bf(pv[mt][2]) | ((uint32_t)f2bf(pv[mt][3]) << 16);
        *(uint2*)(Pw + (16 * nt + l15) * 40 + 16 * mt + quad * 4) = d;
      }
    }
#pragma unroll
    for (int nt = 0; nt < 4; nt++) {
      bf16x8 PB = __builtin_bit_cast(bf16x8, *(const uint4*)(Pw + (16 * nt + l15) * 40 + quad * 8));
      Oacc[0][nt] = __builtin_amdgcn_mfma_f32_16x16x32_bf16(VA0, PB, Oacc[0][nt], 0, 0, 0);
      Oacc[1][nt] = __builtin_amdgcn_mfma_f32_16x16x32_bf16(VA1, PB, Oacc[1][nt], 0, 0, 0);
    }
  };

  int rbase = oct * 8;
  uint4 kA0, kA1, vA0, vA1, kB0, kB1, vB0, vB1;
  LOADROW(rbase + 0, kA0, kA1, vA0, vA1);
  LOADROW(rbase + 1, kB0, kB1, vB0, vB1);
#pragma unroll 1
  for (int r = 0; r < 8; r += 2) {
    compute(kA0, kA1, vA0, vA1);
    {
      int rn = (r + 2 < 8) ? (r + 2) : 6;  // clamped, branch-free
      LOADROW(rbase + rn, kA0, kA1, vA0, vA1);
    }
    compute(kB0, kB1, vB0, vB1);
    {
      int rn = (r + 3 < 8) ? (r + 3) : 7;  // clamped, branch-free
      LOADROW(rbase + rn, kB0, kB1, vB0, vB1);
    }
  }
#undef LOADROW

#pragma unroll
  for (int nt = 0; nt < 4; nt++) {
    lsum[nt] += __shfl_xor(lsum[nt], 16, 64);
    lsum[nt] += __shfl_xor(lsum[nt], 32, 64);
  }

  float* mO = (float*)lds;                 // [oct][32ch][64q]  32 KB
  float* mL = (float*)(lds + 16384);       // [oct][64q]
#pragma unroll 1
  for (int p = 0; p < 2; p++) {
    __syncthreads();
    if (hd == p) {
#pragma unroll
      for (int mt = 0; mt < 2; mt++)
#pragma unroll
        for (int nt = 0; nt < 4; nt++)
#pragma unroll
          for (int r = 0; r < 4; r++)
            mO[oct * 2048 + (16 * mt + quad * 4 + r) * 64 + 16 * nt + l15] = Oacc[mt][nt][r];
      if (quad == 0) {
#pragma unroll
        for (int nt = 0; nt < 4; nt++) mL[oct * 64 + nt * 16 + l15] = lsum[nt];
      }
    }
    __syncthreads();
    {
      int q = threadIdx.x & 63;
      int cg = threadIdx.x >> 6;  // 0..7 -> 4 ch each
      float inv = 1.0f / (mL[q] + mL[64 + q] + mL[128 + q] + mL[192 + q]);
      float* ob = o + (((size_t)(b * 100 + n)) * 128 + (hp * 2 + p) * 32 + cg * 4) * 64 + q;
#pragma unroll
      for (int e = 0; e < 4; e++) {
        int ch = cg * 4 + e;
        float s = mO[ch * 64 + q] + mO[2048 + ch * 64 + q] +
                  mO[4096 + ch * 64 + q] + mO[6144 + ch * 64 + q];
        ob[(size_t)e * 64] = s * inv;
      }
    }
  }
}

// ---------------------------------------------------------------------------
// Reverse: scatter-average overlapping 8x8 windows (step 6) into (2,128,62,62)
// ---------------------------------------------------------------------------
__global__ void reverse_kernel(const float* __restrict__ win, float* __restrict__ out) {
  int i = blockIdx.x * 256 + threadIdx.x;
  const int total = 2 * 128 * HSW;
  if (i >= total) return;
  int x = i % HS;
  int t = i / HS;
  int y = t % HS;
  t /= HS;
  int c = t % 128;
  int b = t / 128;
  int wi0 = (y >= 7) ? (y - 2) / 6 : 0;
  int wi1 = min(9, y / 6);
  int wj0 = (x >= 7) ? (x - 2) / 6 : 0;
  int wj1 = min(9, x / 6);
  float s = 0.0f;
  for (int wi = wi0; wi <= wi1; wi++)
    for (int wj = wj0; wj <= wj1; wj++) {
      int di = y - 6 * wi, dj = x - 6 * wj;
      s += win[(((size_t)(b * 100 + wi * 10 + wj)) * 128 + c) * 64 + di * 8 + dj];
    }
  float cnt = (float)((wi1 - wi0 + 1) * (wj1 - wj0 + 1));
  out[i] = s / cnt;
}

// ---------------------------------------------------------------------------
extern "C" void kernel_launch(void* const* d_in, const int* in_sizes, int n_in,
                              void* d_out, int out_size, void* d_ws, size_t ws_size,
                              hipStream_t stream) {
  const float* x      = (const float*)d_in[0];
  const float* sp     = (const float*)d_in[1];
  const float* w_pos  = (const float*)d_in[2];
  const float* b_pos  = (const float*)d_in[3];
  const float* w_q    = (const float*)d_in[4];
  const float* w_qdw  = (const float*)d_in[5];
  const float* w_kv   = (const float*)d_in[6];
  const float* w_kvdw = (const float*)d_in[7];
  const float* w_out  = (const float*)d_in[8];
  float* out = (float*)d_out;

  const size_t N_x   = (size_t)2 * 128 * HXW;   // 15,745,024 (shorts for kT/xpb)
  const size_t N_vp  = (size_t)2 * 128 * HXWP;  // 16,252,928 (padded vv, shorts)
  const size_t N_s   = (size_t)2 * 128 * HSW;
  const size_t N_att = (size_t)2 * 100 * 128 * 64;

  float* ws = (float*)d_ws;
  // shorts-based layout (all counts even -> float-aligned):
  unsigned short* xpb = (unsigned short*)ws;          // N_x shorts, dead after step 5
  unsigned short* kT  = (unsigned short*)ws;          // N_x shorts (overwrites xpb)
  unsigned short* vv  = kT + N_x;                     // N_vp shorts (padded rows)
  unsigned short* tkv = vv + N_vp;                    // 2*N_x shorts
  float* att = (float*)tkv;                           // reuse (tkv dead after step 6)
  float* rev = att + N_att;
  float* spp = (float*)(tkv + 2 * N_x);
  float* tq  = spp + N_s;
  unsigned short* qn  = (unsigned short*)(tq + N_s);  // N_s shorts
  unsigned short* wkb = qn + N_s;                     // 32768 shorts
  (void)ws_size; (void)in_sizes; (void)n_in; (void)out_size;

  // 0. wkb = bf16(w_kv)
  cvt_bf16_kernel<<<128, 256, 0, stream>>>(w_kv, wkb, 256 * 128);
  // 1. xpb = bf16(x + dwconv3(x, w_pos, b_pos))   (bf16 NCHW)
  {
    int total4 = (int)(N_x / 4);
    dwconv4_bf16_kernel<<<(total4 + 255) / 256, 256, 0, stream>>>(x, w_pos, b_pos, xpb, total4);
  }
  // 2. spp = sp + dwconv3(sp, w_pos, b_pos)
  {
    int total = (int)N_s;
    dwconv3_kernel<<<(total + 255) / 256, 256, 0, stream>>>(sp, w_pos, b_pos, spp, 128, HS, HS, total, 1);
  }
  // 3. tq = conv1(spp, w_q)
  {
    int HW = HSW;
    dim3 grid((HW + 63) / 64, 2, 2);
    conv1_kernel<128><<<grid, 256, 0, stream>>>(spp, w_q, tq, HW);
  }
  // 4. qn = bf16_nhwc(dwconv3(tq, w_qdw)) * 32^-0.5
  {
    int total = (int)N_s;
    dwconv_q_kernel<<<(total + 255) / 256, 256, 0, stream>>>(tq, w_qdw, qn, total);
  }
  // 5. tkv = bf16_nhwc(mfma_conv1(xpb, wkb))   (xpb dead after)
  {
    dim3 grid(HXW / 64, 2);
    conv1_kv_mfma_kernel<<<grid, 256, 0, stream>>>(xpb, wkb, tkv);
  }
  // 6. kT (NHWC) + vv (NCHW padded) = bf16(dwconv3(tkv, w_kvdw)) (overwrites xpb)
  {
    dim3 grid(496, 2);
    dwconv_kv_kernel<<<grid, 512, 0, stream>>>(tkv, w_kvdw, kT, vv);
  }
  // 7. attention -> att (2,100,128,64)
  {
    dim3 grid(100, 2, 2);
    attn_mfma_kernel<<<grid, 512, 0, stream>>>(qn, kT, vv, att);
  }
  // 8. rev = reverse(att)
  {
    int total = (int)N_s;
    reverse_kernel<<<(total + 255) / 256, 256, 0, stream>>>(att, rev);
  }
  // 9. out = conv1(rev, w_out)
  {
    int HW = HSW;
    dim3 grid((HW + 63) / 64, 2, 2);
    conv1_kernel<128><<<grid, 256, 0, stream>>>(rev, w_out, out, HW);
  }
}

// Round 4
// 269.622 us; speedup vs baseline: 1.1988x; 1.0559x over previous
//
#include <hip/hip_runtime.h>
#include <cstdint>

#define HS 62
#define HX 248
#define HXW (HX * HX)  // 61504
#define HSW (HS * HS)  // 3844
#define HXP 256        // padded row stride for vv (128-B aligned rows)
#define HXWP (HX * HXP)  // 63488 padded plane

typedef __attribute__((ext_vector_type(8))) short bf16x8;
typedef __attribute__((ext_vector_type(4))) float f32x4;
typedef __attribute__((ext_vector_type(2))) float f32x2;

static __device__ __forceinline__ unsigned short f2bf(float f) {
  uint32_t u = __builtin_bit_cast(uint32_t, f);
  u += 0x7fff + ((u >> 16) & 1);  // RNE
  return (unsigned short)(u >> 16);
}
static __device__ __forceinline__ float bf2f(unsigned short u) {
  uint32_t x = (uint32_t)u << 16;
  return __builtin_bit_cast(float, x);
}
static __device__ __forceinline__ float bflo(uint32_t u) {
  return __builtin_bit_cast(float, u << 16);
}
static __device__ __forceinline__ float bfhi(uint32_t u) {
  return __builtin_bit_cast(float, u & 0xffff0000u);
}

// packed fp32 FMA: acc = a*b + acc (2 lanes of fp32, CDNA v_pk_fma_f32)
static __device__ __forceinline__ void pkfma(f32x2& acc, f32x2 a, f32x2 b) {
  asm("v_pk_fma_f32 %0, %1, %2, %0" : "+v"(acc) : "v"(a), "v"(b));
}
// packed f32->bf16 RNE convert: returns (bf16(lo) | bf16(hi)<<16)
static __device__ __forceinline__ uint32_t cvtpk(float lo, float hi) {
  uint32_t r;
  asm("v_cvt_pk_bf16_f32 %0, %1, %2" : "=v"(r) : "v"(lo), "v"(hi));
  return r;
}
// unpack u32 holding 2 bf16 -> packed f32 pair
static __device__ __forceinline__ f32x2 unp(uint32_t u) {
  f32x2 r;
  r.x = __builtin_bit_cast(float, u << 16);
  r.y = __builtin_bit_cast(float, u & 0xffff0000u);
  return r;
}

// ---------------------------------------------------------------------------
// Depthwise 3x3 scalar (62x62 tensors), fp32 out, bias+residual.
// ---------------------------------------------------------------------------
__global__ void dwconv3_kernel(const float* __restrict__ x, const float* __restrict__ w,
                               const float* __restrict__ bias, float* __restrict__ y,
                               int C, int H, int W, int total, int residual) {
  int i = blockIdx.x * 256 + threadIdx.x;
  if (i >= total) return;
  int wx = i % W;
  int t = i / W;
  int hy = t % H;
  int bc = t / H;
  int c = bc % C;
  const float* xb = x + (size_t)bc * H * W;
  const float* wc = w + c * 9;
  float s = bias ? bias[c] : 0.0f;
  for (int di = -1; di <= 1; di++) {
    int h2 = hy + di;
    if (h2 < 0 || h2 >= H) continue;
    for (int dj = -1; dj <= 1; dj++) {
      int w2 = wx + dj;
      if (w2 < 0 || w2 >= W) continue;
      s += xb[(size_t)h2 * W + w2] * wc[(di + 1) * 3 + (dj + 1)];
    }
  }
  if (residual) s += xb[(size_t)hy * W + wx];
  y[i] = s;
}

// ---------------------------------------------------------------------------
// Depthwise 3x3 x-path v2: fp32 NCHW in -> bf16 NCHW out, residual.
// 8 px x 2 rows per thread: 4 input rows loaded once feed both output rows
// (1.0 load-instr/px vs 2.5), float4 loads, uint4 stores. Halo rows zeroed
// in registers (0*finite = +0 keeps per-element FP order identical to the
// skip-row formulation). total = 2*128*124*31 threads.
// ---------------------------------------------------------------------------
__global__ __launch_bounds__(256) void dwconv8x2_bf16_kernel(
    const float* __restrict__ x, const float* __restrict__ w,
    const float* __restrict__ bias, unsigned short* __restrict__ y, int total) {
  int i = blockIdx.x * 256 + threadIdx.x;
  if (i >= total) return;
  int wq = (i % 31) * 8;
  int t = i / 31;
  int hp = t % 124;
  int bc = t / 124;
  int c = bc & 127;
  int hy = hp * 2;
  const float* xb = x + (size_t)bc * HXW;
  const float* wc = w + c * 9;
  float bv = bias[c];

  float rm1[10], r0[10], r1[10], r2[10];
  auto loadrow = [&](int h2, float (&r)[10]) {
    const float* row = xb + (size_t)h2 * HX + wq;
    float4 a = *(const float4*)row;
    float4 b2 = *(const float4*)(row + 4);
    r[1] = a.x;  r[2] = a.y;  r[3] = a.z;  r[4] = a.w;
    r[5] = b2.x; r[6] = b2.y; r[7] = b2.z; r[8] = b2.w;
    r[0] = (wq > 0) ? row[-1] : 0.0f;
    r[9] = (wq + 8 < HX) ? row[8] : 0.0f;
  };
  loadrow((hy > 0) ? hy - 1 : 0, rm1);
  loadrow(hy, r0);
  loadrow(hy + 1, r1);
  loadrow((hy + 2 < HX) ? hy + 2 : HX - 1, r2);
  if (hp == 0) {
#pragma unroll
    for (int k = 0; k < 10; k++) rm1[k] = 0.0f;
  }
  if (hp == 123) {
#pragma unroll
    for (int k = 0; k < 10; k++) r2[k] = 0.0f;
  }

  float w0 = wc[0], w1 = wc[1], w2 = wc[2];
  float w3 = wc[3], w4 = wc[4], w5 = wc[5];
  float w6 = wc[6], w7 = wc[7], w8 = wc[8];

  float o0[8], o1[8];
#pragma unroll
  for (int k = 0; k < 8; k++) {
    float s = bv;
    s += w0 * rm1[k]; s += w1 * rm1[k + 1]; s += w2 * rm1[k + 2];
    s += w3 * r0[k];  s += w4 * r0[k + 1];  s += w5 * r0[k + 2];
    s += w6 * r1[k];  s += w7 * r1[k + 1];  s += w8 * r1[k + 2];
    o0[k] = s + r0[k + 1];
    float u = bv;
    u += w0 * r0[k]; u += w1 * r0[k + 1]; u += w2 * r0[k + 2];
    u += w3 * r1[k]; u += w4 * r1[k + 1]; u += w5 * r1[k + 2];
    u += w6 * r2[k]; u += w7 * r2[k + 1]; u += w8 * r2[k + 2];
    o1[k] = u + r1[k + 1];
  }
  uint4 d0, d1;
  d0.x = cvtpk(o0[0], o0[1]); d0.y = cvtpk(o0[2], o0[3]);
  d0.z = cvtpk(o0[4], o0[5]); d0.w = cvtpk(o0[6], o0[7]);
  d1.x = cvtpk(o1[0], o1[1]); d1.y = cvtpk(o1[2], o1[3]);
  d1.z = cvtpk(o1[4], o1[5]); d1.w = cvtpk(o1[6], o1[7]);
  unsigned short* yb = y + (size_t)bc * HXW + (size_t)hy * HX + wq;
  *(uint4*)yb = d0;
  *(uint4*)(yb + HX) = d1;
}

// ---------------------------------------------------------------------------
// fp32 -> bf16 flat convert (for w_kv).
// ---------------------------------------------------------------------------
__global__ void cvt_bf16_kernel(const float* __restrict__ src, unsigned short* __restrict__ dst,
                                int n) {
  int i = blockIdx.x * 256 + threadIdx.x;
  if (i < n) dst[i] = f2bf(src[i]);
}

// ---------------------------------------------------------------------------
// Depthwise 3x3 q path: fp32 NCHW in -> bf16 NHWC out, pre-scaled by 32^-0.5.
// ---------------------------------------------------------------------------
__global__ void dwconv_q_kernel(const float* __restrict__ x, const float* __restrict__ w,
                                unsigned short* __restrict__ qn, int total) {
  int i = blockIdx.x * 256 + threadIdx.x;
  if (i >= total) return;
  int wx = i % HS;
  int t = i / HS;
  int hy = t % HS;
  int bc = t / HS;
  int c = bc & 127;
  int b = bc >> 7;
  const float* xb = x + (size_t)bc * HSW;
  const float* wc = w + c * 9;
  float s = 0.0f;
  for (int di = -1; di <= 1; di++) {
    int h2 = hy + di;
    if (h2 < 0 || h2 >= HS) continue;
    for (int dj = -1; dj <= 1; dj++) {
      int w2 = wx + dj;
      if (w2 < 0 || w2 >= HS) continue;
      s += xb[(size_t)h2 * HS + w2] * wc[(di + 1) * 3 + (dj + 1)];
    }
  }
  qn[((size_t)(b * HSW + hy * HS + wx)) * 128 + c] = f2bf(s * 0.17677669529663688f);
}

// ---------------------------------------------------------------------------
// MFMA 1x1 conv kv path, v3: weights staged in LDS per 64-o quarter.
// Block = 64 px x 256 o, 4 waves. Grid (961, 2).
// ---------------------------------------------------------------------------
__global__ __launch_bounds__(256) void conv1_kv_mfma_kernel(
    const unsigned short* __restrict__ xpb,  // (2,128,61504) bf16 NCHW
    const unsigned short* __restrict__ wkb,  // (256,128) bf16
    unsigned short* __restrict__ y) {        // (2,61504,256) bf16 NHWC
  int b = blockIdx.y;
  int p0 = blockIdx.x * 64;
  int tid = threadIdx.x;
  int wave = tid >> 6, lane = tid & 63, quad = lane >> 4, l15 = lane & 15;
  __shared__ __align__(16) unsigned short bufA[64 * 136];  // 17,408 B
  __shared__ __align__(16) unsigned short bufW[64 * 136];  // 17,408 B

  // phase 1: stage X-tile as bufA[px][c], stride 136
  {
    int c = tid >> 1, half = tid & 1;
    const unsigned short* src = xpb + ((size_t)(b * 128 + c)) * HXW + p0 + half * 32;
#pragma unroll
    for (int j = 0; j < 8; j++) {
      uint2 v = *(const uint2*)(src + j * 4);
      int px = half * 32 + j * 4;
      bufA[(px + 0) * 136 + c] = (unsigned short)(v.x & 0xffff);
      bufA[(px + 1) * 136 + c] = (unsigned short)(v.x >> 16);
      bufA[(px + 2) * 136 + c] = (unsigned short)(v.y & 0xffff);
      bufA[(px + 3) * 136 + c] = (unsigned short)(v.y >> 16);
    }
  }
  __syncthreads();
  bf16x8 A[4];
#pragma unroll
  for (int kb = 0; kb < 4; kb++)
    A[kb] = __builtin_bit_cast(bf16x8,
        *(const uint4*)&bufA[(wave * 16 + l15) * 136 + kb * 32 + quad * 8]);
  // bufA becomes the output stage after the next barrier.

  const f32x4 zf = {0.f, 0.f, 0.f, 0.f};
#pragma unroll 1
  for (int h = 0; h < 2; h++) {
#pragma unroll 1
    for (int oq = 0; oq < 2; oq++) {
      __syncthreads();  // bufW reusable; (h>0: bufA flush complete)
      {  // cooperative coalesced load of one 64-o weight quarter -> bufW
        int orow = tid >> 2;          // 0..63
        int cseg = (tid & 3) * 32;    // 0,32,64,96
        const unsigned short* src = wkb + (size_t)(h * 128 + oq * 64 + orow) * 128 + cseg;
        unsigned short* dst = &bufW[orow * 136 + cseg];
        *(uint4*)(dst)      = *(const uint4*)(src);
        *(uint4*)(dst + 8)  = *(const uint4*)(src + 8);
        *(uint4*)(dst + 16) = *(const uint4*)(src + 16);
        *(uint4*)(dst + 24) = *(const uint4*)(src + 24);
      }
      __syncthreads();
#pragma unroll
      for (int ot = 0; ot < 4; ot++) {
        const unsigned short* wrow = &bufW[(ot * 16 + l15) * 136 + quad * 8];
        f32x4 D = zf;
        D = __builtin_amdgcn_mfma_f32_16x16x32_bf16(A[0], __builtin_bit_cast(bf16x8, *(const uint4*)(wrow)),      D, 0, 0, 0);
        D = __builtin_amdgcn_mfma_f32_16x16x32_bf16(A[1], __builtin_bit_cast(bf16x8, *(const uint4*)(wrow + 32)), D, 0, 0, 0);
        D = __builtin_amdgcn_mfma_f32_16x16x32_bf16(A[2], __builtin_bit_cast(bf16x8, *(const uint4*)(wrow + 64)), D, 0, 0, 0);
        D = __builtin_amdgcn_mfma_f32_16x16x32_bf16(A[3], __builtin_bit_cast(bf16x8, *(const uint4*)(wrow + 96)), D, 0, 0, 0);
#pragma unroll
        for (int r = 0; r < 4; r++)
          bufA[(wave * 16 + quad * 4 + r) * 136 + (oq * 4 + ot) * 16 + l15] = f2bf(D[r]);
      }
    }
    __syncthreads();
    {  // flush this o-half: 64 px x 128 o, coalesced
      int px = tid >> 2, og = (tid & 3) * 32;
      const uint4* srcp = (const uint4*)&bufA[px * 136 + og];
      uint4* dstp = (uint4*)(y + ((size_t)b * HXW + p0 + px) * 256 + h * 128 + og);
#pragma unroll
      for (int j = 0; j < 4; j++) dstp[j] = srcp[j];
    }
  }
}

// ---------------------------------------------------------------------------
// Fused depthwise 3x3 K/V from bf16 NHWC tkv — v4: 2-channel lanes, 512-thr
// blocks, fused row-pair column streaming.
// Grid (496, 2), block 512.
// ---------------------------------------------------------------------------
template <bool VT, bool VB>
static __device__ __forceinline__ void dwkv_rowpair(
    const unsigned short* __restrict__ rm1, const unsigned short* __restrict__ r0,
    const unsigned short* __restrict__ r1, const unsigned short* __restrict__ r2,
    const f32x2 (&wp)[9], int px0, f32x2 (&a0)[8], f32x2 (&a1)[8]) {
  const f32x2 z2 = {0.f, 0.f};
#pragma unroll
  for (int p = 0; p < 8; p++) { a0[p] = z2; a1[p] = z2; }
#pragma unroll
  for (int j = 0; j < 10; j++) {
    int xcol = px0 - 1 + j;
    int xc = xcol;
    if (j == 0) xc = (xcol < 0) ? 0 : xcol;
    if (j == 9) xc = (xcol > HX - 1) ? HX - 1 : xcol;
    size_t off = (size_t)xc * 256;
    uint32_t um1 = 0, u0, u1, u2 = 0;
    u0 = *(const uint32_t*)(r0 + off);
    u1 = *(const uint32_t*)(r1 + off);
    if constexpr (VT) um1 = *(const uint32_t*)(rm1 + off);
    if constexpr (VB) u2 = *(const uint32_t*)(r2 + off);
    if (j == 0 || j == 9) {  // only edge columns can be out of range
      bool oob = (j == 0) ? (xcol < 0) : (xcol > HX - 1);
      if (oob) { um1 = 0u; u0 = 0u; u1 = 0u; u2 = 0u; }
    }
    f32x2 dm1, d0 = unp(u0), d1 = unp(u1), d2;
    if constexpr (VT) dm1 = unp(um1);
    if constexpr (VB) d2 = unp(u2);
    // column j: LEFT tap (h=0) of px j, CENTER (h=1) of px j-1, RIGHT (h=2)
    // of px j-2. out row0 taps rows (m1,0,1) = v(0,1,2); row1 taps (0,1,2).
    if (j <= 7) {
      if constexpr (VT) pkfma(a0[j], wp[0], dm1);
      pkfma(a0[j], wp[3], d0);
      pkfma(a0[j], wp[6], d1);
      pkfma(a1[j], wp[0], d0);
      pkfma(a1[j], wp[3], d1);
      if constexpr (VB) pkfma(a1[j], wp[6], d2);
    }
    if (j >= 1 && j <= 8) {
      if constexpr (VT) pkfma(a0[j - 1], wp[1], dm1);
      pkfma(a0[j - 1], wp[4], d0);
      pkfma(a0[j - 1], wp[7], d1);
      pkfma(a1[j - 1], wp[1], d0);
      pkfma(a1[j - 1], wp[4], d1);
      if constexpr (VB) pkfma(a1[j - 1], wp[7], d2);
    }
    if (j >= 2) {
      if constexpr (VT) pkfma(a0[j - 2], wp[2], dm1);
      pkfma(a0[j - 2], wp[5], d0);
      pkfma(a0[j - 2], wp[8], d1);
      pkfma(a1[j - 2], wp[2], d0);
      pkfma(a1[j - 2], wp[5], d1);
      if constexpr (VB) pkfma(a1[j - 2], wp[8], d2);
    }
  }
}

#define VTS 72                    // vt channel stride (shorts): 144 B, 16-B aligned
#define VTROW (128 * VTS + 16)    // vt row stride (shorts), +16 shifts banks

__global__ __launch_bounds__(512) __attribute__((amdgpu_waves_per_eu(4)))
void dwconv_kv_kernel(const unsigned short* __restrict__ tkv,
                      const float* __restrict__ w,
                      unsigned short* __restrict__ kT,
                      unsigned short* __restrict__ vv) {
  // XCD swizzle: consecutive fid round-robin across XCDs; give each XCD a
  // contiguous vertical run of row-pairs within one strip.
  int fid = blockIdx.x;
  int xcd = fid & 7, slot = fid >> 3;
  int gi = xcd * 62 + slot;          // 0..495
  int strip = gi / 124;              // 0..3
  int g = gi % 124;                  // row-pair index
  int b = blockIdx.y;
  int x0 = strip * 64;
  int tid = threadIdx.x;
  int cl = tid & 127;                // channel lane: ch = 2*cl, 2*cl+1
  int pg = tid >> 7;                 // 0..3 px-group (wave-pair uniform)
  int ch0 = cl * 2;
  int hy0 = g * 2;

  f32x2 wp[9];
#pragma unroll
  for (int t = 0; t < 9; t++) {
    wp[t].x = w[ch0 * 9 + t];
    wp[t].y = w[(ch0 + 1) * 9 + t];
  }

  __shared__ __align__(16) unsigned short vt[2 * VTROW];  // 36,928 B

  const unsigned short* r0 = tkv + (size_t)b * HXW * 256 + (size_t)hy0 * (HX * 256) + ch0;
  const unsigned short* r1 = r0 + HX * 256;
  const unsigned short* rm1 = r0 - HX * 256;   // deref only when VT
  const unsigned short* r2 = r1 + HX * 256;    // deref only when VB
  bool isK = (cl < 64);
  int c0 = ch0 - 128;                // V-lane channel base

#pragma unroll 1
  for (int half = 0; half < 2; half++) {
    int px0 = x0 + pg * 16 + half * 8;
    if (px0 < HX) {  // strip 3 / pg 3 / half 1 is pure pad: skip
      f32x2 a0[8], a1[8];
      if (g == 0)        dwkv_rowpair<false, true >(rm1, r0, r1, r2, wp, px0, a0, a1);
      else if (g == 123) dwkv_rowpair<true,  false>(rm1, r0, r1, r2, wp, px0, a0, a1);
      else               dwkv_rowpair<true,  true >(rm1, r0, r1, r2, wp, px0, a0, a1);

      if (isK) {  // K rows: direct NHWC store, 2 ch packed per dword
        unsigned short* kb0 = kT + ((size_t)b * HXW + (size_t)hy0 * HX + px0) * 128 + ch0;
        unsigned short* kb1 = kb0 + (size_t)HX * 128;
#pragma unroll
        for (int p = 0; p < 8; p++) {
          *(uint32_t*)(kb0 + (size_t)p * 128) = cvtpk(a0[p].x, a0[p].y);
          *(uint32_t*)(kb1 + (size_t)p * 128) = cvtpk(a1[p].x, a1[p].y);
        }
      } else {    // V rows: stage transposed [row][ch][px] into LDS
        int pxr = pg * 16 + half * 8;
        unsigned short* v0 = vt + c0 * VTS + pxr;        // ch c0, row 0
        unsigned short* v1 = v0 + VTS;                   // ch c0+1
        uint2 d;
        d.x = cvtpk(a0[0].x, a0[1].x); d.y = cvtpk(a0[2].x, a0[3].x);
        *(uint2*)(v0) = d;
        d.x = cvtpk(a0[4].x, a0[5].x); d.y = cvtpk(a0[6].x, a0[7].x);
        *(uint2*)(v0 + 4) = d;
        d.x = cvtpk(a0[0].y, a0[1].y); d.y = cvtpk(a0[2].y, a0[3].y);
        *(uint2*)(v1) = d;
        d.x = cvtpk(a0[4].y, a0[5].y); d.y = cvtpk(a0[6].y, a0[7].y);
        *(uint2*)(v1 + 4) = d;
        d.x = cvtpk(a1[0].x, a1[1].x); d.y = cvtpk(a1[2].x, a1[3].x);
        *(uint2*)(v0 + VTROW) = d;
        d.x = cvtpk(a1[4].x, a1[5].x); d.y = cvtpk(a1[6].x, a1[7].x);
        *(uint2*)(v0 + VTROW + 4) = d;
        d.x = cvtpk(a1[0].y, a1[1].y); d.y = cvtpk(a1[2].y, a1[3].y);
        *(uint2*)(v1 + VTROW) = d;
        d.x = cvtpk(a1[4].y, a1[5].y); d.y = cvtpk(a1[6].y, a1[7].y);
        *(uint2*)(v1 + VTROW + 4) = d;
      }
    }
  }
  __syncthreads();
  {  // cooperative NCHW store of both V rows (full 128-B lines, padded rows)
    int ch = tid >> 2;
    int row = (tid >> 1) & 1;
    int ph = (tid & 1) * 32;
    const unsigned short* srcv = vt + row * VTROW + ch * VTS + ph;
    unsigned short* dst = vv + (size_t)(b * 128 + ch) * HXWP + (size_t)(hy0 + row) * HXP + x0 + ph;
#pragma unroll
    for (int j = 0; j < 4; j++)
      *(uint4*)(dst + j * 8) = *(const uint4*)(srcv + j * 8);
  }
}

// ---------------------------------------------------------------------------
// 1x1 conv tiled SGEMM (fp32) — small tensors (q path, output projection).
// ---------------------------------------------------------------------------
template <int O>
__global__ __launch_bounds__(256) void conv1_kernel(const float* __restrict__ x,
                                                    const float* __restrict__ w,
                                                    float* __restrict__ y, int HW) {
  constexpr int K = 128;
  constexpr int BK = 32;
  __shared__ __align__(16) float ws_s[BK][64];
  __shared__ __align__(16) float xs_s[BK][64];
  int b = blockIdx.z;
  int o0 = blockIdx.y * 64;
  int p0 = blockIdx.x * 64;
  const float* xb = x + (size_t)b * K * HW;
  int tx = threadIdx.x & 15;
  int ty = threadIdx.x >> 4;
  float acc[4][4] = {};
  int lo = threadIdx.x >> 2;
  int lk = (threadIdx.x & 3) * 8;
  int lc = threadIdx.x >> 3;
  int lp = (threadIdx.x & 7) * 8;

  for (int k0 = 0; k0 < K; k0 += BK) {
    __syncthreads();
    {
      const float* wp = w + (size_t)(o0 + lo) * K + k0 + lk;
      float4 a = *(const float4*)wp;
      float4 bq = *(const float4*)(wp + 4);
      ws_s[lk + 0][lo] = a.x;  ws_s[lk + 1][lo] = a.y;
      ws_s[lk + 2][lo] = a.z;  ws_s[lk + 3][lo] = a.w;
      ws_s[lk + 4][lo] = bq.x; ws_s[lk + 5][lo] = bq.y;
      ws_s[lk + 6][lo] = bq.z; ws_s[lk + 7][lo] = bq.w;
    }
    {
      int p = p0 + lp;
      const float* xp = xb + (size_t)(k0 + lc) * HW;
      float4 a, bq;
      if (p + 7 < HW) {
        a = *(const float4*)(xp + p);
        bq = *(const float4*)(xp + p + 4);
      } else {
        float tv[8];
#pragma unroll
        for (int j = 0; j < 8; j++) tv[j] = (p + j < HW) ? xp[p + j] : 0.0f;
        a = make_float4(tv[0], tv[1], tv[2], tv[3]);
        bq = make_float4(tv[4], tv[5], tv[6], tv[7]);
      }
      *(float4*)&xs_s[lc][lp] = a;
      *(float4*)&xs_s[lc][lp + 4] = bq;
    }
    __syncthreads();
#pragma unroll
    for (int k = 0; k < BK; k++) {
      float4 wv = *(const float4*)&ws_s[k][ty * 4];
      float4 xv = *(const float4*)&xs_s[k][tx * 4];
      acc[0][0] += wv.x * xv.x; acc[0][1] += wv.x * xv.y; acc[0][2] += wv.x * xv.z; acc[0][3] += wv.x * xv.w;
      acc[1][0] += wv.y * xv.x; acc[1][1] += wv.y * xv.y; acc[1][2] += wv.y * xv.z; acc[1][3] += wv.y * xv.w;
      acc[2][0] += wv.z * xv.x; acc[2][1] += wv.z * xv.y; acc[2][2] += wv.z * xv.z; acc[2][3] += wv.z * xv.w;
      acc[3][0] += wv.w * xv.x; acc[3][1] += wv.w * xv.y; acc[3][2] += wv.w * xv.z; acc[3][3] += wv.w * xv.w;
    }
  }
  int p = p0 + tx * 4;
  float* yb = y + (size_t)b * O * HW + (size_t)(o0 + ty * 4) * HW;
#pragma unroll
  for (int j = 0; j < 4; j++) {
    float* yr = yb + (size_t)j * HW + p;
    if (p + 3 < HW) {
      *(float4*)yr = make_float4(acc[j][0], acc[j][1], acc[j][2], acc[j][3]);
    } else {
#pragma unroll
      for (int e = 0; e < 4; e++) if (p + e < HW) yr[e] = acc[j][e];
    }
  }
}

// ---------------------------------------------------------------------------
// MFMA windowed attention, head-pair blocks. 512 thr = 8 waves.
// V has padded strides: row HXP, plane HXWP.
// ---------------------------------------------------------------------------
__global__ __launch_bounds__(512) void attn_mfma_kernel(
    const unsigned short* __restrict__ qn,   // (2,62,62,128) bf16, pre-scaled
    const unsigned short* __restrict__ kT,   // (2,248,248,128) bf16 NHWC
    const unsigned short* __restrict__ vp,   // (2,128,248,256p) bf16 NCHW padded
    float* __restrict__ o) {
  int n = blockIdx.x, hp = blockIdx.y, b = blockIdx.z;
  int wi = n / 10, wj = n % 10;
  int wave = threadIdx.x >> 6;
  int hd = wave & 1, oct = wave >> 1;
  int h = hp * 2 + hd;
  int lane = threadIdx.x & 63;
  int quad = lane >> 4;
  int l15 = lane & 15;
  int y0 = 24 * wi, x0 = 24 * wj;

  __shared__ __align__(16) unsigned short lds[20480];  // 40,960 B
  unsigned short* Pw = lds + wave * 2560;              // [q][40keys] 5KB/wave

  bf16x8 QB[4];
#pragma unroll
  for (int nt = 0; nt < 4; nt++) {
    int qq = nt * 16 + l15;
    int qy = 6 * wi + (qq >> 3), qx = 6 * wj + (qq & 7);
    QB[nt] = __builtin_bit_cast(bf16x8,
        *(const uint4*)(qn + ((size_t)(b * HSW + qy * HS + qx)) * 128 + h * 32 + quad * 8));
  }

  f32x4 Oacc[2][4];
#pragma unroll
  for (int a = 0; a < 2; a++)
#pragma unroll
    for (int c = 0; c < 4; c++) Oacc[a][c] = f32x4{0.f, 0.f, 0.f, 0.f};
  float lsum[4] = {0.f, 0.f, 0.f, 0.f};

  const unsigned short* kb = kT + (size_t)b * HXW * 128 + h * 32;
  const unsigned short* vb = vp + ((size_t)(b * 128 + h * 32)) * HXWP;
  const f32x4 zf = {0.f, 0.f, 0.f, 0.f};

#define LOADROW(r, K0, K1, V0, V1)                                              \
  {                                                                             \
    int y = y0 + (r);                                                           \
    const unsigned short* krow = kb + ((size_t)(y * HX + x0)) * 128;            \
    K0 = *(const uint4*)(krow + (size_t)l15 * 128 + quad * 8);                  \
    K1 = *(const uint4*)(krow + (size_t)(16 + l15) * 128 + quad * 8);           \
    const unsigned short* vrow = vb + (size_t)y * HXP + x0 + quad * 8;          \
    V0 = *(const uint4*)(vrow + (size_t)l15 * HXWP);                            \
    V1 = *(const uint4*)(vrow + (size_t)(16 + l15) * HXWP);                     \
  }

  auto compute = [&](uint4 k0, uint4 k1, uint4 v0, uint4 v1) {
    bf16x8 KA0 = __builtin_bit_cast(bf16x8, k0);
    bf16x8 KA1 = __builtin_bit_cast(bf16x8, k1);
    bf16x8 VA0 = __builtin_bit_cast(bf16x8, v0);
    bf16x8 VA1 = __builtin_bit_cast(bf16x8, v1);
    f32x4 S[2][4];
#pragma unroll
    for (int nt = 0; nt < 4; nt++) {
      S[0][nt] = __builtin_amdgcn_mfma_f32_16x16x32_bf16(KA0, QB[nt], zf, 0, 0, 0);
      S[1][nt] = __builtin_amdgcn_mfma_f32_16x16x32_bf16(KA1, QB[nt], zf, 0, 0, 0);
    }
#pragma unroll
    for (int nt = 0; nt < 4; nt++) {
      float pv[2][4];
      float cs = 0.f;
#pragma unroll
      for (int mt = 0; mt < 2; mt++)
#pragma unroll
        for (int r = 0; r < 4; r++) {
          pv[mt][r] = __expf(S[mt][nt][r]);
          cs += pv[mt][r];
        }
      lsum[nt] += cs;
#pragma unroll
      for (int mt = 0; mt < 2; mt++) {
        uint2 d;
        d.x = (uint32_t)f2bf(pv[mt][0]) | ((uint32_t)f2bf(pv[mt][1]) << 16);
        d.y = (uint32_t)f2bf(pv[mt][2]) | ((uint32_t)f2bf(pv[mt][3]) << 16);
        *(uint2*)(Pw + (16 * nt + l15) * 40 + 16 * mt + quad * 4) = d;
      }
    }
#pragma unroll
    for (int nt = 0; nt < 4; nt++) {
      bf16x8 PB = __builtin_bit_cast(bf16x8, *(const uint4*)(Pw + (16 * nt + l15) * 40 + quad * 8));
      Oacc[0][nt] = __builtin_amdgcn_mfma_f32_16x16x32_bf16(VA0, PB, Oacc[0][nt], 0, 0, 0);
      Oacc[1][nt] = __builtin_amdgcn_mfma_f32_16x16x32_bf16(VA1, PB, Oacc[1][nt], 0, 0, 0);
    }
  };

  int rbase = oct * 8;
  uint4 kA0, kA1, vA0, vA1, kB0, kB1, vB0, vB1;
  LOADROW(rbase + 0, kA0, kA1, vA0, vA1);
  LOADROW(rbase + 1, kB0, kB1, vB0, vB1);
#pragma unroll 1
  for (int r = 0; r < 8; r += 2) {
    compute(kA0, kA1, vA0, vA1);
    {
      int rn = (r + 2 < 8) ? (r + 2) : 6;  // clamped, branch-free
      LOADROW(rbase + rn, kA0, kA1, vA0, vA1);
    }
    compute(kB0, kB1, vB0, vB1);
    {
      int rn = (r + 3 < 8) ? (r + 3) : 7;  // clamped, branch-free
      LOADROW(rbase + rn, kB0, kB1, vB0, vB1);
    }
  }
#undef LOADROW

#pragma unroll
  for (int nt = 0; nt < 4; nt++) {
    lsum[nt] += __shfl_xor(lsum[nt], 16, 64);
    lsum[nt] += __shfl_xor(lsum[nt], 32, 64);
  }

  float* mO = (float*)lds;                 // [oct][32ch][64q]  32 KB
  float* mL = (float*)(lds + 16384);       // [oct][64q]
#pragma unroll 1
  for (int p = 0; p < 2; p++) {
    __syncthreads();
    if (hd == p) {
#pragma unroll
      for (int mt = 0; mt < 2; mt++)
#pragma unroll
        for (int nt = 0; nt < 4; nt++)
#pragma unroll
          for (int r = 0; r < 4; r++)
            mO[oct * 2048 + (16 * mt + quad * 4 + r) * 64 + 16 * nt + l15] = Oacc[mt][nt][r];
      if (quad == 0) {
#pragma unroll
        for (int nt = 0; nt < 4; nt++) mL[oct * 64 + nt * 16 + l15] = lsum[nt];
      }
    }
    __syncthreads();
    {
      int q = threadIdx.x & 63;
      int cg = threadIdx.x >> 6;  // 0..7 -> 4 ch each
      float inv = 1.0f / (mL[q] + mL[64 + q] + mL[128 + q] + mL[192 + q]);
      float* ob = o + (((size_t)(b * 100 + n)) * 128 + (hp * 2 + p) * 32 + cg * 4) * 64 + q;
#pragma unroll
      for (int e = 0; e < 4; e++) {
        int ch = cg * 4 + e;
        float s = mO[ch * 64 + q] + mO[2048 + ch * 64 + q] +
                  mO[4096 + ch * 64 + q] + mO[6144 + ch * 64 + q];
        ob[(size_t)e * 64] = s * inv;
      }
    }
  }
}

// ---------------------------------------------------------------------------
// Reverse: scatter-average overlapping 8x8 windows (step 6) into (2,128,62,62)
// ---------------------------------------------------------------------------
__global__ void reverse_kernel(const float* __restrict__ win, float* __restrict__ out) {
  int i = blockIdx.x * 256 + threadIdx.x;
  const int total = 2 * 128 * HSW;
  if (i >= total) return;
  int x = i % HS;
  int t = i / HS;
  int y = t % HS;
  t /= HS;
  int c = t % 128;
  int b = t / 128;
  int wi0 = (y >= 7) ? (y - 2) / 6 : 0;
  int wi1 = min(9, y / 6);
  int wj0 = (x >= 7) ? (x - 2) / 6 : 0;
  int wj1 = min(9, x / 6);
  float s = 0.0f;
  for (int wi = wi0; wi <= wi1; wi++)
    for (int wj = wj0; wj <= wj1; wj++) {
      int di = y - 6 * wi, dj = x - 6 * wj;
      s += win[(((size_t)(b * 100 + wi * 10 + wj)) * 128 + c) * 64 + di * 8 + dj];
    }
  float cnt = (float)((wi1 - wi0 + 1) * (wj1 - wj0 + 1));
  out[i] = s / cnt;
}

// ---------------------------------------------------------------------------
extern "C" void kernel_launch(void* const* d_in, const int* in_sizes, int n_in,
                              void* d_out, int out_size, void* d_ws, size_t ws_size,
                              hipStream_t stream) {
  const float* x      = (const float*)d_in[0];
  const float* sp     = (const float*)d_in[1];
  const float* w_pos  = (const float*)d_in[2];
  const float* b_pos  = (const float*)d_in[3];
  const float* w_q    = (const float*)d_in[4];
  const float* w_qdw  = (const float*)d_in[5];
  const float* w_kv   = (const float*)d_in[6];
  const float* w_kvdw = (const float*)d_in[7];
  const float* w_out  = (const float*)d_in[8];
  float* out = (float*)d_out;

  const size_t N_x   = (size_t)2 * 128 * HXW;   // 15,745,024 (shorts for kT/xpb)
  const size_t N_vp  = (size_t)2 * 128 * HXWP;  // 16,252,928 (padded vv, shorts)
  const size_t N_s   = (size_t)2 * 128 * HSW;
  const size_t N_att = (size_t)2 * 100 * 128 * 64;

  float* ws = (float*)d_ws;
  // shorts-based layout (all counts even -> float-aligned):
  unsigned short* xpb = (unsigned short*)ws;          // N_x shorts, dead after step 5
  unsigned short* kT  = (unsigned short*)ws;          // N_x shorts (overwrites xpb)
  unsigned short* vv  = kT + N_x;                     // N_vp shorts (padded rows)
  unsigned short* tkv = vv + N_vp;                    // 2*N_x shorts
  float* att = (float*)tkv;                           // reuse (tkv dead after step 6)
  float* rev = att + N_att;
  float* spp = (float*)(tkv + 2 * N_x);
  float* tq  = spp + N_s;
  unsigned short* qn  = (unsigned short*)(tq + N_s);  // N_s shorts
  unsigned short* wkb = qn + N_s;                     // 32768 shorts
  (void)ws_size; (void)in_sizes; (void)n_in; (void)out_size;

  // 0. wkb = bf16(w_kv)
  cvt_bf16_kernel<<<128, 256, 0, stream>>>(w_kv, wkb, 256 * 128);
  // 1. xpb = bf16(x + dwconv3(x, w_pos, b_pos))   (bf16 NCHW), 8px x 2rows/thread
  {
    int total = 2 * 128 * 124 * 31;
    dwconv8x2_bf16_kernel<<<(total + 255) / 256, 256, 0, stream>>>(x, w_pos, b_pos, xpb, total);
  }
  // 2. spp = sp + dwconv3(sp, w_pos, b_pos)
  {
    int total = (int)N_s;
    dwconv3_kernel<<<(total + 255) / 256, 256, 0, stream>>>(sp, w_pos, b_pos, spp, 128, HS, HS, total, 1);
  }
  // 3. tq = conv1(spp, w_q)
  {
    int HW = HSW;
    dim3 grid((HW + 63) / 64, 2, 2);
    conv1_kernel<128><<<grid, 256, 0, stream>>>(spp, w_q, tq, HW);
  }
  // 4. qn = bf16_nhwc(dwconv3(tq, w_qdw)) * 32^-0.5
  {
    int total = (int)N_s;
    dwconv_q_kernel<<<(total + 255) / 256, 256, 0, stream>>>(tq, w_qdw, qn, total);
  }
  // 5. tkv = bf16_nhwc(mfma_conv1(xpb, wkb))   (xpb dead after)
  {
    dim3 grid(HXW / 64, 2);
    conv1_kv_mfma_kernel<<<grid, 256, 0, stream>>>(xpb, wkb, tkv);
  }
  // 6. kT (NHWC) + vv (NCHW padded) = bf16(dwconv3(tkv, w_kvdw)) (overwrites xpb)
  {
    dim3 grid(496, 2);
    dwconv_kv_kernel<<<grid, 512, 0, stream>>>(tkv, w_kvdw, kT, vv);
  }
  // 7. attention -> att (2,100,128,64)
  {
    dim3 grid(100, 2, 2);
    attn_mfma_kernel<<<grid, 512, 0, stream>>>(qn, kT, vv, att);
  }
  // 8. rev = reverse(att)
  {
    int total = (int)N_s;
    reverse_kernel<<<(total + 255) / 256, 256, 0, stream>>>(att, rev);
  }
  // 9. out = conv1(rev, w_out)
  {
    int HW = HSW;
    dim3 grid((HW + 63) / 64, 2, 2);
    conv1_kernel<128><<<grid, 256, 0, stream>>>(rev, w_out, out, HW);
  }
}

// Round 5
// 268.571 us; speedup vs baseline: 1.2035x; 1.0039x over previous
//
#include <hip/hip_runtime.h>
#include <cstdint>

#define HS 62
#define HX 248
#define HXW (HX * HX)  // 61504
#define HSW (HS * HS)  // 3844
#define HXP 256        // padded row stride for vv (128-B aligned rows)
#define HXWP (HX * HXP)  // 63488 padded plane

typedef __attribute__((ext_vector_type(8))) short bf16x8;
typedef __attribute__((ext_vector_type(4))) float f32x4;
typedef __attribute__((ext_vector_type(2))) float f32x2;

static __device__ __forceinline__ unsigned short f2bf(float f) {
  uint32_t u = __builtin_bit_cast(uint32_t, f);
  u += 0x7fff + ((u >> 16) & 1);  // RNE
  return (unsigned short)(u >> 16);
}
static __device__ __forceinline__ float bf2f(unsigned short u) {
  uint32_t x = (uint32_t)u << 16;
  return __builtin_bit_cast(float, x);
}
static __device__ __forceinline__ float bflo(uint32_t u) {
  return __builtin_bit_cast(float, u << 16);
}
static __device__ __forceinline__ float bfhi(uint32_t u) {
  return __builtin_bit_cast(float, u & 0xffff0000u);
}

// packed fp32 FMA: acc = a*b + acc (2 lanes of fp32, CDNA v_pk_fma_f32)
static __device__ __forceinline__ void pkfma(f32x2& acc, f32x2 a, f32x2 b) {
  asm("v_pk_fma_f32 %0, %1, %2, %0" : "+v"(acc) : "v"(a), "v"(b));
}
// packed f32->bf16 RNE convert: returns (bf16(lo) | bf16(hi)<<16)
static __device__ __forceinline__ uint32_t cvtpk(float lo, float hi) {
  uint32_t r;
  asm("v_cvt_pk_bf16_f32 %0, %1, %2" : "=v"(r) : "v"(lo), "v"(hi));
  return r;
}
// unpack u32 holding 2 bf16 -> packed f32 pair
static __device__ __forceinline__ f32x2 unp(uint32_t u) {
  f32x2 r;
  r.x = __builtin_bit_cast(float, u << 16);
  r.y = __builtin_bit_cast(float, u & 0xffff0000u);
  return r;
}

// ---------------------------------------------------------------------------
// Depthwise 3x3 scalar (62x62 tensors), fp32 out, bias+residual.
// ---------------------------------------------------------------------------
__global__ void dwconv3_kernel(const float* __restrict__ x, const float* __restrict__ w,
                               const float* __restrict__ bias, float* __restrict__ y,
                               int C, int H, int W, int total, int residual) {
  int i = blockIdx.x * 256 + threadIdx.x;
  if (i >= total) return;
  int wx = i % W;
  int t = i / W;
  int hy = t % H;
  int bc = t / H;
  int c = bc % C;
  const float* xb = x + (size_t)bc * H * W;
  const float* wc = w + c * 9;
  float s = bias ? bias[c] : 0.0f;
  for (int di = -1; di <= 1; di++) {
    int h2 = hy + di;
    if (h2 < 0 || h2 >= H) continue;
    for (int dj = -1; dj <= 1; dj++) {
      int w2 = wx + dj;
      if (w2 < 0 || w2 >= W) continue;
      s += xb[(size_t)h2 * W + w2] * wc[(di + 1) * 3 + (dj + 1)];
    }
  }
  if (residual) s += xb[(size_t)hy * W + wx];
  y[i] = s;
}

// ---------------------------------------------------------------------------
// Depthwise 3x3 x-path v2: fp32 NCHW in -> bf16 NCHW out, residual.
// 8 px x 2 rows per thread.
// ---------------------------------------------------------------------------
__global__ __launch_bounds__(256) void dwconv8x2_bf16_kernel(
    const float* __restrict__ x, const float* __restrict__ w,
    const float* __restrict__ bias, unsigned short* __restrict__ y, int total) {
  int i = blockIdx.x * 256 + threadIdx.x;
  if (i >= total) return;
  int wq = (i % 31) * 8;
  int t = i / 31;
  int hp = t % 124;
  int bc = t / 124;
  int c = bc & 127;
  int hy = hp * 2;
  const float* xb = x + (size_t)bc * HXW;
  const float* wc = w + c * 9;
  float bv = bias[c];

  float rm1[10], r0[10], r1[10], r2[10];
  auto loadrow = [&](int h2, float (&r)[10]) {
    const float* row = xb + (size_t)h2 * HX + wq;
    float4 a = *(const float4*)row;
    float4 b2 = *(const float4*)(row + 4);
    r[1] = a.x;  r[2] = a.y;  r[3] = a.z;  r[4] = a.w;
    r[5] = b2.x; r[6] = b2.y; r[7] = b2.z; r[8] = b2.w;
    r[0] = (wq > 0) ? row[-1] : 0.0f;
    r[9] = (wq + 8 < HX) ? row[8] : 0.0f;
  };
  loadrow((hy > 0) ? hy - 1 : 0, rm1);
  loadrow(hy, r0);
  loadrow(hy + 1, r1);
  loadrow((hy + 2 < HX) ? hy + 2 : HX - 1, r2);
  if (hp == 0) {
#pragma unroll
    for (int k = 0; k < 10; k++) rm1[k] = 0.0f;
  }
  if (hp == 123) {
#pragma unroll
    for (int k = 0; k < 10; k++) r2[k] = 0.0f;
  }

  float w0 = wc[0], w1 = wc[1], w2 = wc[2];
  float w3 = wc[3], w4 = wc[4], w5 = wc[5];
  float w6 = wc[6], w7 = wc[7], w8 = wc[8];

  float o0[8], o1[8];
#pragma unroll
  for (int k = 0; k < 8; k++) {
    float s = bv;
    s += w0 * rm1[k]; s += w1 * rm1[k + 1]; s += w2 * rm1[k + 2];
    s += w3 * r0[k];  s += w4 * r0[k + 1];  s += w5 * r0[k + 2];
    s += w6 * r1[k];  s += w7 * r1[k + 1];  s += w8 * r1[k + 2];
    o0[k] = s + r0[k + 1];
    float u = bv;
    u += w0 * r0[k]; u += w1 * r0[k + 1]; u += w2 * r0[k + 2];
    u += w3 * r1[k]; u += w4 * r1[k + 1]; u += w5 * r1[k + 2];
    u += w6 * r2[k]; u += w7 * r2[k + 1]; u += w8 * r2[k + 2];
    o1[k] = u + r1[k + 1];
  }
  uint4 d0, d1;
  d0.x = cvtpk(o0[0], o0[1]); d0.y = cvtpk(o0[2], o0[3]);
  d0.z = cvtpk(o0[4], o0[5]); d0.w = cvtpk(o0[6], o0[7]);
  d1.x = cvtpk(o1[0], o1[1]); d1.y = cvtpk(o1[2], o1[3]);
  d1.z = cvtpk(o1[4], o1[5]); d1.w = cvtpk(o1[6], o1[7]);
  unsigned short* yb = y + (size_t)bc * HXW + (size_t)hy * HX + wq;
  *(uint4*)yb = d0;
  *(uint4*)(yb + HX) = d1;
}

// ---------------------------------------------------------------------------
// fp32 -> bf16 flat convert (for w_kv).
// ---------------------------------------------------------------------------
__global__ void cvt_bf16_kernel(const float* __restrict__ src, unsigned short* __restrict__ dst,
                                int n) {
  int i = blockIdx.x * 256 + threadIdx.x;
  if (i < n) dst[i] = f2bf(src[i]);
}

// ---------------------------------------------------------------------------
// Depthwise 3x3 q path: fp32 NCHW in -> bf16 NHWC out, pre-scaled by 32^-0.5.
// ---------------------------------------------------------------------------
__global__ void dwconv_q_kernel(const float* __restrict__ x, const float* __restrict__ w,
                                unsigned short* __restrict__ qn, int total) {
  int i = blockIdx.x * 256 + threadIdx.x;
  if (i >= total) return;
  int wx = i % HS;
  int t = i / HS;
  int hy = t % HS;
  int bc = t / HS;
  int c = bc & 127;
  int b = bc >> 7;
  const float* xb = x + (size_t)bc * HSW;
  const float* wc = w + c * 9;
  float s = 0.0f;
  for (int di = -1; di <= 1; di++) {
    int h2 = hy + di;
    if (h2 < 0 || h2 >= HS) continue;
    for (int dj = -1; dj <= 1; dj++) {
      int w2 = wx + dj;
      if (w2 < 0 || w2 >= HS) continue;
      s += xb[(size_t)h2 * HS + w2] * wc[(di + 1) * 3 + (dj + 1)];
    }
  }
  qn[((size_t)(b * HSW + hy * HS + wx)) * 128 + c] = f2bf(s * 0.17677669529663688f);
}

// ---------------------------------------------------------------------------
// MFMA 1x1 conv kv path, v3: weights staged in LDS per 64-o quarter.
// Block = 64 px x 256 o, 4 waves. Grid (961, 2).
// ---------------------------------------------------------------------------
__global__ __launch_bounds__(256) void conv1_kv_mfma_kernel(
    const unsigned short* __restrict__ xpb,  // (2,128,61504) bf16 NCHW
    const unsigned short* __restrict__ wkb,  // (256,128) bf16
    unsigned short* __restrict__ y) {        // (2,61504,256) bf16 NHWC
  int b = blockIdx.y;
  int p0 = blockIdx.x * 64;
  int tid = threadIdx.x;
  int wave = tid >> 6, lane = tid & 63, quad = lane >> 4, l15 = lane & 15;
  __shared__ __align__(16) unsigned short bufA[64 * 136];  // 17,408 B
  __shared__ __align__(16) unsigned short bufW[64 * 136];  // 17,408 B

  // phase 1: stage X-tile as bufA[px][c], stride 136
  {
    int c = tid >> 1, half = tid & 1;
    const unsigned short* src = xpb + ((size_t)(b * 128 + c)) * HXW + p0 + half * 32;
#pragma unroll
    for (int j = 0; j < 8; j++) {
      uint2 v = *(const uint2*)(src + j * 4);
      int px = half * 32 + j * 4;
      bufA[(px + 0) * 136 + c] = (unsigned short)(v.x & 0xffff);
      bufA[(px + 1) * 136 + c] = (unsigned short)(v.x >> 16);
      bufA[(px + 2) * 136 + c] = (unsigned short)(v.y & 0xffff);
      bufA[(px + 3) * 136 + c] = (unsigned short)(v.y >> 16);
    }
  }
  __syncthreads();
  bf16x8 A[4];
#pragma unroll
  for (int kb = 0; kb < 4; kb++)
    A[kb] = __builtin_bit_cast(bf16x8,
        *(const uint4*)&bufA[(wave * 16 + l15) * 136 + kb * 32 + quad * 8]);
  // bufA becomes the output stage after the next barrier.

  const f32x4 zf = {0.f, 0.f, 0.f, 0.f};
#pragma unroll 1
  for (int h = 0; h < 2; h++) {
#pragma unroll 1
    for (int oq = 0; oq < 2; oq++) {
      __syncthreads();  // bufW reusable; (h>0: bufA flush complete)
      {  // cooperative coalesced load of one 64-o weight quarter -> bufW
        int orow = tid >> 2;          // 0..63
        int cseg = (tid & 3) * 32;    // 0,32,64,96
        const unsigned short* src = wkb + (size_t)(h * 128 + oq * 64 + orow) * 128 + cseg;
        unsigned short* dst = &bufW[orow * 136 + cseg];
        *(uint4*)(dst)      = *(const uint4*)(src);
        *(uint4*)(dst + 8)  = *(const uint4*)(src + 8);
        *(uint4*)(dst + 16) = *(const uint4*)(src + 16);
        *(uint4*)(dst + 24) = *(const uint4*)(src + 24);
      }
      __syncthreads();
#pragma unroll
      for (int ot = 0; ot < 4; ot++) {
        const unsigned short* wrow = &bufW[(ot * 16 + l15) * 136 + quad * 8];
        f32x4 D = zf;
        D = __builtin_amdgcn_mfma_f32_16x16x32_bf16(A[0], __builtin_bit_cast(bf16x8, *(const uint4*)(wrow)),      D, 0, 0, 0);
        D = __builtin_amdgcn_mfma_f32_16x16x32_bf16(A[1], __builtin_bit_cast(bf16x8, *(const uint4*)(wrow + 32)), D, 0, 0, 0);
        D = __builtin_amdgcn_mfma_f32_16x16x32_bf16(A[2], __builtin_bit_cast(bf16x8, *(const uint4*)(wrow + 64)), D, 0, 0, 0);
        D = __builtin_amdgcn_mfma_f32_16x16x32_bf16(A[3], __builtin_bit_cast(bf16x8, *(const uint4*)(wrow + 96)), D, 0, 0, 0);
#pragma unroll
        for (int r = 0; r < 4; r++)
          bufA[(wave * 16 + quad * 4 + r) * 136 + (oq * 4 + ot) * 16 + l15] = f2bf(D[r]);
      }
    }
    __syncthreads();
    {  // flush this o-half: 64 px x 128 o, coalesced
      int px = tid >> 2, og = (tid & 3) * 32;
      const uint4* srcp = (const uint4*)&bufA[px * 136 + og];
      uint4* dstp = (uint4*)(y + ((size_t)b * HXW + p0 + px) * 256 + h * 128 + og);
#pragma unroll
      for (int j = 0; j < 4; j++) dstp[j] = srcp[j];
    }
  }
}

// ---------------------------------------------------------------------------
// Fused depthwise 3x3 K/V from bf16 NHWC tkv — v4: 2-channel lanes, 512-thr
// blocks, fused row-pair column streaming. Grid (496, 2), block 512.
// ---------------------------------------------------------------------------
template <bool VT, bool VB>
static __device__ __forceinline__ void dwkv_rowpair(
    const unsigned short* __restrict__ rm1, const unsigned short* __restrict__ r0,
    const unsigned short* __restrict__ r1, const unsigned short* __restrict__ r2,
    const f32x2 (&wp)[9], int px0, f32x2 (&a0)[8], f32x2 (&a1)[8]) {
  const f32x2 z2 = {0.f, 0.f};
#pragma unroll
  for (int p = 0; p < 8; p++) { a0[p] = z2; a1[p] = z2; }
#pragma unroll
  for (int j = 0; j < 10; j++) {
    int xcol = px0 - 1 + j;
    int xc = xcol;
    if (j == 0) xc = (xcol < 0) ? 0 : xcol;
    if (j == 9) xc = (xcol > HX - 1) ? HX - 1 : xcol;
    size_t off = (size_t)xc * 256;
    uint32_t um1 = 0, u0, u1, u2 = 0;
    u0 = *(const uint32_t*)(r0 + off);
    u1 = *(const uint32_t*)(r1 + off);
    if constexpr (VT) um1 = *(const uint32_t*)(rm1 + off);
    if constexpr (VB) u2 = *(const uint32_t*)(r2 + off);
    if (j == 0 || j == 9) {  // only edge columns can be out of range
      bool oob = (j == 0) ? (xcol < 0) : (xcol > HX - 1);
      if (oob) { um1 = 0u; u0 = 0u; u1 = 0u; u2 = 0u; }
    }
    f32x2 dm1, d0 = unp(u0), d1 = unp(u1), d2;
    if constexpr (VT) dm1 = unp(um1);
    if constexpr (VB) d2 = unp(u2);
    if (j <= 7) {
      if constexpr (VT) pkfma(a0[j], wp[0], dm1);
      pkfma(a0[j], wp[3], d0);
      pkfma(a0[j], wp[6], d1);
      pkfma(a1[j], wp[0], d0);
      pkfma(a1[j], wp[3], d1);
      if constexpr (VB) pkfma(a1[j], wp[6], d2);
    }
    if (j >= 1 && j <= 8) {
      if constexpr (VT) pkfma(a0[j - 1], wp[1], dm1);
      pkfma(a0[j - 1], wp[4], d0);
      pkfma(a0[j - 1], wp[7], d1);
      pkfma(a1[j - 1], wp[1], d0);
      pkfma(a1[j - 1], wp[4], d1);
      if constexpr (VB) pkfma(a1[j - 1], wp[7], d2);
    }
    if (j >= 2) {
      if constexpr (VT) pkfma(a0[j - 2], wp[2], dm1);
      pkfma(a0[j - 2], wp[5], d0);
      pkfma(a0[j - 2], wp[8], d1);
      pkfma(a1[j - 2], wp[2], d0);
      pkfma(a1[j - 2], wp[5], d1);
      if constexpr (VB) pkfma(a1[j - 2], wp[8], d2);
    }
  }
}

#define VTS 72                    // vt channel stride (shorts): 144 B, 16-B aligned
#define VTROW (128 * VTS + 16)    // vt row stride (shorts), +16 shifts banks

__global__ __launch_bounds__(512) __attribute__((amdgpu_waves_per_eu(4)))
void dwconv_kv_kernel(const unsigned short* __restrict__ tkv,
                      const float* __restrict__ w,
                      unsigned short* __restrict__ kT,
                      unsigned short* __restrict__ vv) {
  int fid = blockIdx.x;
  int xcd = fid & 7, slot = fid >> 3;
  int gi = xcd * 62 + slot;          // 0..495
  int strip = gi / 124;              // 0..3
  int g = gi % 124;                  // row-pair index
  int b = blockIdx.y;
  int x0 = strip * 64;
  int tid = threadIdx.x;
  int cl = tid & 127;                // channel lane: ch = 2*cl, 2*cl+1
  int pg = tid >> 7;                 // 0..3 px-group (wave-pair uniform)
  int ch0 = cl * 2;
  int hy0 = g * 2;

  f32x2 wp[9];
#pragma unroll
  for (int t = 0; t < 9; t++) {
    wp[t].x = w[ch0 * 9 + t];
    wp[t].y = w[(ch0 + 1) * 9 + t];
  }

  __shared__ __align__(16) unsigned short vt[2 * VTROW];  // 36,928 B

  const unsigned short* r0 = tkv + (size_t)b * HXW * 256 + (size_t)hy0 * (HX * 256) + ch0;
  const unsigned short* r1 = r0 + HX * 256;
  const unsigned short* rm1 = r0 - HX * 256;   // deref only when VT
  const unsigned short* r2 = r1 + HX * 256;    // deref only when VB
  bool isK = (cl < 64);
  int c0 = ch0 - 128;                // V-lane channel base

#pragma unroll 1
  for (int half = 0; half < 2; half++) {
    int px0 = x0 + pg * 16 + half * 8;
    if (px0 < HX) {  // strip 3 / pg 3 / half 1 is pure pad: skip
      f32x2 a0[8], a1[8];
      if (g == 0)        dwkv_rowpair<false, true >(rm1, r0, r1, r2, wp, px0, a0, a1);
      else if (g == 123) dwkv_rowpair<true,  false>(rm1, r0, r1, r2, wp, px0, a0, a1);
      else               dwkv_rowpair<true,  true >(rm1, r0, r1, r2, wp, px0, a0, a1);

      if (isK) {  // K rows: direct NHWC store, 2 ch packed per dword
        unsigned short* kb0 = kT + ((size_t)b * HXW + (size_t)hy0 * HX + px0) * 128 + ch0;
        unsigned short* kb1 = kb0 + (size_t)HX * 128;
#pragma unroll
        for (int p = 0; p < 8; p++) {
          *(uint32_t*)(kb0 + (size_t)p * 128) = cvtpk(a0[p].x, a0[p].y);
          *(uint32_t*)(kb1 + (size_t)p * 128) = cvtpk(a1[p].x, a1[p].y);
        }
      } else {    // V rows: stage transposed [row][ch][px] into LDS
        int pxr = pg * 16 + half * 8;
        unsigned short* v0 = vt + c0 * VTS + pxr;        // ch c0, row 0
        unsigned short* v1 = v0 + VTS;                   // ch c0+1
        uint2 d;
        d.x = cvtpk(a0[0].x, a0[1].x); d.y = cvtpk(a0[2].x, a0[3].x);
        *(uint2*)(v0) = d;
        d.x = cvtpk(a0[4].x, a0[5].x); d.y = cvtpk(a0[6].x, a0[7].x);
        *(uint2*)(v0 + 4) = d;
        d.x = cvtpk(a0[0].y, a0[1].y); d.y = cvtpk(a0[2].y, a0[3].y);
        *(uint2*)(v1) = d;
        d.x = cvtpk(a0[4].y, a0[5].y); d.y = cvtpk(a0[6].y, a0[7].y);
        *(uint2*)(v1 + 4) = d;
        d.x = cvtpk(a1[0].x, a1[1].x); d.y = cvtpk(a1[2].x, a1[3].x);
        *(uint2*)(v0 + VTROW) = d;
        d.x = cvtpk(a1[4].x, a1[5].x); d.y = cvtpk(a1[6].x, a1[7].x);
        *(uint2*)(v0 + VTROW + 4) = d;
        d.x = cvtpk(a1[0].y, a1[1].y); d.y = cvtpk(a1[2].y, a1[3].y);
        *(uint2*)(v1 + VTROW) = d;
        d.x = cvtpk(a1[4].y, a1[5].y); d.y = cvtpk(a1[6].y, a1[7].y);
        *(uint2*)(v1 + VTROW + 4) = d;
      }
    }
  }
  __syncthreads();
  {  // cooperative NCHW store of both V rows (full 128-B lines, padded rows)
    int ch = tid >> 2;
    int row = (tid >> 1) & 1;
    int ph = (tid & 1) * 32;
    const unsigned short* srcv = vt + row * VTROW + ch * VTS + ph;
    unsigned short* dst = vv + (size_t)(b * 128 + ch) * HXWP + (size_t)(hy0 + row) * HXP + x0 + ph;
#pragma unroll
    for (int j = 0; j < 4; j++)
      *(uint4*)(dst + j * 8) = *(const uint4*)(srcv + j * 8);
  }
}

// ---------------------------------------------------------------------------
// 1x1 conv tiled SGEMM (fp32) — small tensors (q path, output projection).
// ---------------------------------------------------------------------------
template <int O>
__global__ __launch_bounds__(256) void conv1_kernel(const float* __restrict__ x,
                                                    const float* __restrict__ w,
                                                    float* __restrict__ y, int HW) {
  constexpr int K = 128;
  constexpr int BK = 32;
  __shared__ __align__(16) float ws_s[BK][64];
  __shared__ __align__(16) float xs_s[BK][64];
  int b = blockIdx.z;
  int o0 = blockIdx.y * 64;
  int p0 = blockIdx.x * 64;
  const float* xb = x + (size_t)b * K * HW;
  int tx = threadIdx.x & 15;
  int ty = threadIdx.x >> 4;
  float acc[4][4] = {};
  int lo = threadIdx.x >> 2;
  int lk = (threadIdx.x & 3) * 8;
  int lc = threadIdx.x >> 3;
  int lp = (threadIdx.x & 7) * 8;

  for (int k0 = 0; k0 < K; k0 += BK) {
    __syncthreads();
    {
      const float* wp = w + (size_t)(o0 + lo) * K + k0 + lk;
      float4 a = *(const float4*)wp;
      float4 bq = *(const float4*)(wp + 4);
      ws_s[lk + 0][lo] = a.x;  ws_s[lk + 1][lo] = a.y;
      ws_s[lk + 2][lo] = a.z;  ws_s[lk + 3][lo] = a.w;
      ws_s[lk + 4][lo] = bq.x; ws_s[lk + 5][lo] = bq.y;
      ws_s[lk + 6][lo] = bq.z; ws_s[lk + 7][lo] = bq.w;
    }
    {
      int p = p0 + lp;
      const float* xp = xb + (size_t)(k0 + lc) * HW;
      float4 a, bq;
      if (p + 7 < HW) {
        a = *(const float4*)(xp + p);
        bq = *(const float4*)(xp + p + 4);
      } else {
        float tv[8];
#pragma unroll
        for (int j = 0; j < 8; j++) tv[j] = (p + j < HW) ? xp[p + j] : 0.0f;
        a = make_float4(tv[0], tv[1], tv[2], tv[3]);
        bq = make_float4(tv[4], tv[5], tv[6], tv[7]);
      }
      *(float4*)&xs_s[lc][lp] = a;
      *(float4*)&xs_s[lc][lp + 4] = bq;
    }
    __syncthreads();
#pragma unroll
    for (int k = 0; k < BK; k++) {
      float4 wv = *(const float4*)&ws_s[k][ty * 4];
      float4 xv = *(const float4*)&xs_s[k][tx * 4];
      acc[0][0] += wv.x * xv.x; acc[0][1] += wv.x * xv.y; acc[0][2] += wv.x * xv.z; acc[0][3] += wv.x * xv.w;
      acc[1][0] += wv.y * xv.x; acc[1][1] += wv.y * xv.y; acc[1][2] += wv.y * xv.z; acc[1][3] += wv.y * xv.w;
      acc[2][0] += wv.z * xv.x; acc[2][1] += wv.z * xv.y; acc[2][2] += wv.z * xv.z; acc[2][3] += wv.z * xv.w;
      acc[3][0] += wv.w * xv.x; acc[3][1] += wv.w * xv.y; acc[3][2] += wv.w * xv.z; acc[3][3] += wv.w * xv.w;
    }
  }
  int p = p0 + tx * 4;
  float* yb = y + (size_t)b * O * HW + (size_t)(o0 + ty * 4) * HW;
#pragma unroll
  for (int j = 0; j < 4; j++) {
    float* yr = yb + (size_t)j * HW + p;
    if (p + 3 < HW) {
      *(float4*)yr = make_float4(acc[j][0], acc[j][1], acc[j][2], acc[j][3]);
    } else {
#pragma unroll
      for (int e = 0; e < 4; e++) if (p + e < HW) yr[e] = acc[j][e];
    }
  }
}

// ---------------------------------------------------------------------------
// MFMA windowed attention v2 — split-K halves, 800 blocks, XCD-swizzled.
// Each block: one (b, head-pair, key-half) x window; 8 waves (2 hd x 4 oct),
// each wave does 4 key rows straight-line. Writes UNNORMALIZED partial O
// (pO) and partial L (pL); attn_combine_kernel merges halves.
// ---------------------------------------------------------------------------
__global__ __launch_bounds__(512) void attn_mfma_kernel(
    const unsigned short* __restrict__ qn,   // (2,62,62,128) bf16, pre-scaled
    const unsigned short* __restrict__ kT,   // (2,248,248,128) bf16 NHWC
    const unsigned short* __restrict__ vp,   // (2,128,248,256p) bf16 NCHW padded
    float* __restrict__ pO,                  // (2b,100n,4head,2half,32ch,64q)
    float* __restrict__ pL) {                // (2b,100n,4head,2half,64q)
  // XCD swizzle: each XCD owns one (b,hp,half) x all 100 windows -> window
  // x-overlap K/V reuse stays in one L2.
  int fid = blockIdx.x;
  int xcd = fid & 7, slot = fid >> 3;        // slot 0..99
  int lin = xcd * 100 + slot;
  int n = lin % 100;
  int g2 = lin / 100;                        // 0..7
  int half = g2 & 1, hp = (g2 >> 1) & 1, b = g2 >> 2;
  int wi = n / 10, wj = n % 10;
  int wave = threadIdx.x >> 6;
  int hd = wave & 1, oct = wave >> 1;
  int h = hp * 2 + hd;
  int lane = threadIdx.x & 63;
  int quad = lane >> 4;
  int l15 = lane & 15;
  int y0 = 24 * wi, x0 = 24 * wj;

  __shared__ __align__(16) unsigned short lds[20480];  // 40,960 B
  unsigned short* Pw = lds + wave * 2560;              // [q][40keys] 5KB/wave

  bf16x8 QB[4];
#pragma unroll
  for (int nt = 0; nt < 4; nt++) {
    int qq = nt * 16 + l15;
    int qy = 6 * wi + (qq >> 3), qx = 6 * wj + (qq & 7);
    QB[nt] = __builtin_bit_cast(bf16x8,
        *(const uint4*)(qn + ((size_t)(b * HSW + qy * HS + qx)) * 128 + h * 32 + quad * 8));
  }

  f32x4 Oacc[2][4];
#pragma unroll
  for (int a = 0; a < 2; a++)
#pragma unroll
    for (int c = 0; c < 4; c++) Oacc[a][c] = f32x4{0.f, 0.f, 0.f, 0.f};
  float lsum[4] = {0.f, 0.f, 0.f, 0.f};

  const unsigned short* kb = kT + (size_t)b * HXW * 128 + h * 32;
  const unsigned short* vb = vp + ((size_t)(b * 128 + h * 32)) * HXWP;
  const f32x4 zf = {0.f, 0.f, 0.f, 0.f};

#define LOADROW(r, K0, K1, V0, V1)                                              \
  {                                                                             \
    int y = y0 + (r);                                                           \
    const unsigned short* krow = kb + ((size_t)(y * HX + x0)) * 128;            \
    K0 = *(const uint4*)(krow + (size_t)l15 * 128 + quad * 8);                  \
    K1 = *(const uint4*)(krow + (size_t)(16 + l15) * 128 + quad * 8);           \
    const unsigned short* vrow = vb + (size_t)y * HXP + x0 + quad * 8;          \
    V0 = *(const uint4*)(vrow + (size_t)l15 * HXWP);                            \
    V1 = *(const uint4*)(vrow + (size_t)(16 + l15) * HXWP);                     \
  }

  auto compute = [&](uint4 k0, uint4 k1, uint4 v0, uint4 v1) {
    bf16x8 KA0 = __builtin_bit_cast(bf16x8, k0);
    bf16x8 KA1 = __builtin_bit_cast(bf16x8, k1);
    bf16x8 VA0 = __builtin_bit_cast(bf16x8, v0);
    bf16x8 VA1 = __builtin_bit_cast(bf16x8, v1);
    f32x4 S[2][4];
#pragma unroll
    for (int nt = 0; nt < 4; nt++) {
      S[0][nt] = __builtin_amdgcn_mfma_f32_16x16x32_bf16(KA0, QB[nt], zf, 0, 0, 0);
      S[1][nt] = __builtin_amdgcn_mfma_f32_16x16x32_bf16(KA1, QB[nt], zf, 0, 0, 0);
    }
#pragma unroll
    for (int nt = 0; nt < 4; nt++) {
      float pv[2][4];
      float cs = 0.f;
#pragma unroll
      for (int mt = 0; mt < 2; mt++)
#pragma unroll
        for (int r = 0; r < 4; r++) {
          pv[mt][r] = __expf(S[mt][nt][r]);
          cs += pv[mt][r];
        }
      lsum[nt] += cs;
#pragma unroll
      for (int mt = 0; mt < 2; mt++) {
        uint2 d;
        d.x = (uint32_t)f2bf(pv[mt][0]) | ((uint32_t)f2bf(pv[mt][1]) << 16);
        d.y = (uint32_t)f2bf(pv[mt][2]) | ((uint32_t)f2bf(pv[mt][3]) << 16);
        *(uint2*)(Pw + (16 * nt + l15) * 40 + 16 * mt + quad * 4) = d;
      }
    }
#pragma unroll
    for (int nt = 0; nt < 4; nt++) {
      bf16x8 PB = __builtin_bit_cast(bf16x8, *(const uint4*)(Pw + (16 * nt + l15) * 40 + quad * 8));
      Oacc[0][nt] = __builtin_amdgcn_mfma_f32_16x16x32_bf16(VA0, PB, Oacc[0][nt], 0, 0, 0);
      Oacc[1][nt] = __builtin_amdgcn_mfma_f32_16x16x32_bf16(VA1, PB, Oacc[1][nt], 0, 0, 0);
    }
  };

  // 4 rows per wave, straight-line with 2-row prefetch.
  int rbase = half * 16 + oct * 4;
  uint4 kA0, kA1, vA0, vA1, kB0, kB1, vB0, vB1;
  LOADROW(rbase + 0, kA0, kA1, vA0, vA1);
  LOADROW(rbase + 1, kB0, kB1, vB0, vB1);
  compute(kA0, kA1, vA0, vA1);
  LOADROW(rbase + 2, kA0, kA1, vA0, vA1);
  compute(kB0, kB1, vB0, vB1);
  LOADROW(rbase + 3, kB0, kB1, vB0, vB1);
  compute(kA0, kA1, vA0, vA1);
  compute(kB0, kB1, vB0, vB1);
#undef LOADROW

#pragma unroll
  for (int nt = 0; nt < 4; nt++) {
    lsum[nt] += __shfl_xor(lsum[nt], 16, 64);
    lsum[nt] += __shfl_xor(lsum[nt], 32, 64);
  }

  float* mO = (float*)lds;                 // [oct][32ch][64q]  32 KB
  float* mL = (float*)(lds + 16384);       // [oct][64q]
#pragma unroll 1
  for (int p = 0; p < 2; p++) {
    __syncthreads();
    if (hd == p) {
#pragma unroll
      for (int mt = 0; mt < 2; mt++)
#pragma unroll
        for (int nt = 0; nt < 4; nt++)
#pragma unroll
          for (int r = 0; r < 4; r++)
            mO[oct * 2048 + (16 * mt + quad * 4 + r) * 64 + 16 * nt + l15] = Oacc[mt][nt][r];
      if (quad == 0) {
#pragma unroll
        for (int nt = 0; nt < 4; nt++) mL[oct * 64 + nt * 16 + l15] = lsum[nt];
      }
    }
    __syncthreads();
    {
      int q = threadIdx.x & 63;
      int cg = threadIdx.x >> 6;  // 0..7 -> 4 ch each
      float Lh = mL[q] + mL[64 + q] + mL[128 + q] + mL[192 + q];
      size_t pbase = ((((size_t)(b * 100 + n)) * 4 + (hp * 2 + p)) * 2 + half);
      float* ob = pO + pbase * 2048 + (size_t)(cg * 4) * 64 + q;
#pragma unroll
      for (int e = 0; e < 4; e++) {
        int ch = cg * 4 + e;
        float s = mO[ch * 64 + q] + mO[2048 + ch * 64 + q] +
                  mO[4096 + ch * 64 + q] + mO[6144 + ch * 64 + q];
        ob[(size_t)e * 64] = s;  // unnormalized
      }
      if (cg == 0) pL[pbase * 64 + q] = Lh;
    }
  }
}

// ---------------------------------------------------------------------------
// Combine the two key-half partials: att = (O0+O1)/(L0+L1).
// ---------------------------------------------------------------------------
__global__ void attn_combine_kernel(const float* __restrict__ pO,
                                    const float* __restrict__ pL,
                                    float* __restrict__ o) {
  int i = blockIdx.x * 256 + threadIdx.x;
  const int total = 2 * 100 * 128 * 64;
  if (i >= total) return;
  int q = i & 63;
  int t = i >> 6;
  int c = t & 127;
  int wn = t >> 7;             // b*100 + n
  int head = c >> 5, ch = c & 31;
  size_t base = ((size_t)wn * 4 + head) * 2;
  float s = pO[(base + 0) * 2048 + ch * 64 + q] + pO[(base + 1) * 2048 + ch * 64 + q];
  float L = pL[(base + 0) * 64 + q] + pL[(base + 1) * 64 + q];
  o[i] = s / L;
}

// ---------------------------------------------------------------------------
// Reverse: scatter-average overlapping 8x8 windows (step 6) into (2,128,62,62)
// ---------------------------------------------------------------------------
__global__ void reverse_kernel(const float* __restrict__ win, float* __restrict__ out) {
  int i = blockIdx.x * 256 + threadIdx.x;
  const int total = 2 * 128 * HSW;
  if (i >= total) return;
  int x = i % HS;
  int t = i / HS;
  int y = t % HS;
  t /= HS;
  int c = t % 128;
  int b = t / 128;
  int wi0 = (y >= 7) ? (y - 2) / 6 : 0;
  int wi1 = min(9, y / 6);
  int wj0 = (x >= 7) ? (x - 2) / 6 : 0;
  int wj1 = min(9, x / 6);
  float s = 0.0f;
  for (int wi = wi0; wi <= wi1; wi++)
    for (int wj = wj0; wj <= wj1; wj++) {
      int di = y - 6 * wi, dj = x - 6 * wj;
      s += win[(((size_t)(b * 100 + wi * 10 + wj)) * 128 + c) * 64 + di * 8 + dj];
    }
  float cnt = (float)((wi1 - wi0 + 1) * (wj1 - wj0 + 1));
  out[i] = s / cnt;
}

// ---------------------------------------------------------------------------
extern "C" void kernel_launch(void* const* d_in, const int* in_sizes, int n_in,
                              void* d_out, int out_size, void* d_ws, size_t ws_size,
                              hipStream_t stream) {
  const float* x      = (const float*)d_in[0];
  const float* sp     = (const float*)d_in[1];
  const float* w_pos  = (const float*)d_in[2];
  const float* b_pos  = (const float*)d_in[3];
  const float* w_q    = (const float*)d_in[4];
  const float* w_qdw  = (const float*)d_in[5];
  const float* w_kv   = (const float*)d_in[6];
  const float* w_kvdw = (const float*)d_in[7];
  const float* w_out  = (const float*)d_in[8];
  float* out = (float*)d_out;

  const size_t N_x   = (size_t)2 * 128 * HXW;   // 15,745,024 (shorts for kT/xpb)
  const size_t N_vp  = (size_t)2 * 128 * HXWP;  // 16,252,928 (padded vv, shorts)
  const size_t N_s   = (size_t)2 * 128 * HSW;
  const size_t N_att = (size_t)2 * 100 * 128 * 64;
  const size_t N_pO  = (size_t)2 * 100 * 4 * 2 * 2048;  // 3,276,800 floats
  const size_t N_pL  = (size_t)2 * 100 * 4 * 2 * 64;    // 102,400 floats

  float* ws = (float*)d_ws;
  // shorts-based layout (all counts even -> float-aligned):
  unsigned short* xpb = (unsigned short*)ws;          // N_x shorts, dead after step 5
  unsigned short* kT  = (unsigned short*)ws;          // N_x shorts (overwrites xpb)
  unsigned short* vv  = kT + N_x;                     // N_vp shorts (padded rows)
  unsigned short* tkv = vv + N_vp;                    // 2*N_x shorts
  float* att = (float*)tkv;                           // reuse (tkv dead after step 6)
  float* rev = att + N_att;
  float* pO  = rev + N_s;                             // partials, still in tkv region
  float* pL  = pO + N_pO;
  float* spp = (float*)(tkv + 2 * N_x);
  float* tq  = spp + N_s;
  unsigned short* qn  = (unsigned short*)(tq + N_s);  // N_s shorts
  unsigned short* wkb = qn + N_s;                     // 32768 shorts
  (void)ws_size; (void)in_sizes; (void)n_in; (void)out_size;

  // 0. wkb = bf16(w_kv)
  cvt_bf16_kernel<<<128, 256, 0, stream>>>(w_kv, wkb, 256 * 128);
  // 1. xpb = bf16(x + dwconv3(x, w_pos, b_pos))   (bf16 NCHW), 8px x 2rows/thread
  {
    int total = 2 * 128 * 124 * 31;
    dwconv8x2_bf16_kernel<<<(total + 255) / 256, 256, 0, stream>>>(x, w_pos, b_pos, xpb, total);
  }
  // 2. spp = sp + dwconv3(sp, w_pos, b_pos)
  {
    int total = (int)N_s;
    dwconv3_kernel<<<(total + 255) / 256, 256, 0, stream>>>(sp, w_pos, b_pos, spp, 128, HS, HS, total, 1);
  }
  // 3. tq = conv1(spp, w_q)
  {
    int HW = HSW;
    dim3 grid((HW + 63) / 64, 2, 2);
    conv1_kernel<128><<<grid, 256, 0, stream>>>(spp, w_q, tq, HW);
  }
  // 4. qn = bf16_nhwc(dwconv3(tq, w_qdw)) * 32^-0.5
  {
    int total = (int)N_s;
    dwconv_q_kernel<<<(total + 255) / 256, 256, 0, stream>>>(tq, w_qdw, qn, total);
  }
  // 5. tkv = bf16_nhwc(mfma_conv1(xpb, wkb))   (xpb dead after)
  {
    dim3 grid(HXW / 64, 2);
    conv1_kv_mfma_kernel<<<grid, 256, 0, stream>>>(xpb, wkb, tkv);
  }
  // 6. kT (NHWC) + vv (NCHW padded) = bf16(dwconv3(tkv, w_kvdw)) (overwrites xpb)
  {
    dim3 grid(496, 2);
    dwconv_kv_kernel<<<grid, 512, 0, stream>>>(tkv, w_kvdw, kT, vv);
  }
  // 7. attention partials -> pO,pL   (800 XCD-swizzled half-blocks)
  {
    attn_mfma_kernel<<<800, 512, 0, stream>>>(qn, kT, vv, pO, pL);
  }
  // 7b. combine halves -> att (2,100,128,64)
  {
    int total = (int)N_att;
    attn_combine_kernel<<<(total + 255) / 256, 256, 0, stream>>>(pO, pL, att);
  }
  // 8. rev = reverse(att)
  {
    int total = (int)N_s;
    reverse_kernel<<<(total + 255) / 256, 256, 0, stream>>>(att, rev);
  }
  // 9. out = conv1(rev, w_out)
  {
    int HW = HSW;
    dim3 grid((HW + 63) / 64, 2, 2);
    conv1_kernel<128><<<grid, 256, 0, stream>>>(rev, w_out, out, HW);
  }
}

// Round 6
// 257.011 us; speedup vs baseline: 1.2576x; 1.0450x over previous
//
#include <hip/hip_runtime.h>
#include <cstdint>

#define HS 62
#define HX 248
#define HXW (HX * HX)  // 61504
#define HSW (HS * HS)  // 3844
#define HXP 256        // padded row stride for vv (128-B aligned rows)
#define HXWP (HX * HXP)  // 63488 padded plane

typedef __attribute__((ext_vector_type(8))) short bf16x8;
typedef __attribute__((ext_vector_type(4))) float f32x4;
typedef __attribute__((ext_vector_type(2))) float f32x2;

static __device__ __forceinline__ unsigned short f2bf(float f) {
  uint32_t u = __builtin_bit_cast(uint32_t, f);
  u += 0x7fff + ((u >> 16) & 1);  // RNE
  return (unsigned short)(u >> 16);
}
static __device__ __forceinline__ float bf2f(unsigned short u) {
  uint32_t x = (uint32_t)u << 16;
  return __builtin_bit_cast(float, x);
}
static __device__ __forceinline__ float bflo(uint32_t u) {
  return __builtin_bit_cast(float, u << 16);
}
static __device__ __forceinline__ float bfhi(uint32_t u) {
  return __builtin_bit_cast(float, u & 0xffff0000u);
}

// packed fp32 FMA: acc = a*b + acc (2 lanes of fp32, CDNA v_pk_fma_f32)
static __device__ __forceinline__ void pkfma(f32x2& acc, f32x2 a, f32x2 b) {
  asm("v_pk_fma_f32 %0, %1, %2, %0" : "+v"(acc) : "v"(a), "v"(b));
}
// packed f32->bf16 RNE convert: returns (bf16(lo) | bf16(hi)<<16)
static __device__ __forceinline__ uint32_t cvtpk(float lo, float hi) {
  uint32_t r;
  asm("v_cvt_pk_bf16_f32 %0, %1, %2" : "=v"(r) : "v"(lo), "v"(hi));
  return r;
}
// unpack u32 holding 2 bf16 -> packed f32 pair
static __device__ __forceinline__ f32x2 unp(uint32_t u) {
  f32x2 r;
  r.x = __builtin_bit_cast(float, u << 16);
  r.y = __builtin_bit_cast(float, u & 0xffff0000u);
  return r;
}

// ---------------------------------------------------------------------------
// Depthwise 3x3 scalar (62x62 tensors), fp32 out, bias+residual.
// ---------------------------------------------------------------------------
__global__ void dwconv3_kernel(const float* __restrict__ x, const float* __restrict__ w,
                               const float* __restrict__ bias, float* __restrict__ y,
                               int C, int H, int W, int total, int residual) {
  int i = blockIdx.x * 256 + threadIdx.x;
  if (i >= total) return;
  int wx = i % W;
  int t = i / W;
  int hy = t % H;
  int bc = t / H;
  int c = bc % C;
  const float* xb = x + (size_t)bc * H * W;
  const float* wc = w + c * 9;
  float s = bias ? bias[c] : 0.0f;
  for (int di = -1; di <= 1; di++) {
    int h2 = hy + di;
    if (h2 < 0 || h2 >= H) continue;
    for (int dj = -1; dj <= 1; dj++) {
      int w2 = wx + dj;
      if (w2 < 0 || w2 >= W) continue;
      s += xb[(size_t)h2 * W + w2] * wc[(di + 1) * 3 + (dj + 1)];
    }
  }
  if (residual) s += xb[(size_t)hy * W + wx];
  y[i] = s;
}

// ---------------------------------------------------------------------------
// Depthwise 3x3 x-path v2: fp32 NCHW in -> bf16 NCHW out, residual.
// 8 px x 2 rows per thread.
// ---------------------------------------------------------------------------
__global__ __launch_bounds__(256) void dwconv8x2_bf16_kernel(
    const float* __restrict__ x, const float* __restrict__ w,
    const float* __restrict__ bias, unsigned short* __restrict__ y, int total) {
  int i = blockIdx.x * 256 + threadIdx.x;
  if (i >= total) return;
  int wq = (i % 31) * 8;
  int t = i / 31;
  int hp = t % 124;
  int bc = t / 124;
  int c = bc & 127;
  int hy = hp * 2;
  const float* xb = x + (size_t)bc * HXW;
  const float* wc = w + c * 9;
  float bv = bias[c];

  float rm1[10], r0[10], r1[10], r2[10];
  auto loadrow = [&](int h2, float (&r)[10]) {
    const float* row = xb + (size_t)h2 * HX + wq;
    float4 a = *(const float4*)row;
    float4 b2 = *(const float4*)(row + 4);
    r[1] = a.x;  r[2] = a.y;  r[3] = a.z;  r[4] = a.w;
    r[5] = b2.x; r[6] = b2.y; r[7] = b2.z; r[8] = b2.w;
    r[0] = (wq > 0) ? row[-1] : 0.0f;
    r[9] = (wq + 8 < HX) ? row[8] : 0.0f;
  };
  loadrow((hy > 0) ? hy - 1 : 0, rm1);
  loadrow(hy, r0);
  loadrow(hy + 1, r1);
  loadrow((hy + 2 < HX) ? hy + 2 : HX - 1, r2);
  if (hp == 0) {
#pragma unroll
    for (int k = 0; k < 10; k++) rm1[k] = 0.0f;
  }
  if (hp == 123) {
#pragma unroll
    for (int k = 0; k < 10; k++) r2[k] = 0.0f;
  }

  float w0 = wc[0], w1 = wc[1], w2 = wc[2];
  float w3 = wc[3], w4 = wc[4], w5 = wc[5];
  float w6 = wc[6], w7 = wc[7], w8 = wc[8];

  float o0[8], o1[8];
#pragma unroll
  for (int k = 0; k < 8; k++) {
    float s = bv;
    s += w0 * rm1[k]; s += w1 * rm1[k + 1]; s += w2 * rm1[k + 2];
    s += w3 * r0[k];  s += w4 * r0[k + 1];  s += w5 * r0[k + 2];
    s += w6 * r1[k];  s += w7 * r1[k + 1];  s += w8 * r1[k + 2];
    o0[k] = s + r0[k + 1];
    float u = bv;
    u += w0 * r0[k]; u += w1 * r0[k + 1]; u += w2 * r0[k + 2];
    u += w3 * r1[k]; u += w4 * r1[k + 1]; u += w5 * r1[k + 2];
    u += w6 * r2[k]; u += w7 * r2[k + 1]; u += w8 * r2[k + 2];
    o1[k] = u + r1[k + 1];
  }
  uint4 d0, d1;
  d0.x = cvtpk(o0[0], o0[1]); d0.y = cvtpk(o0[2], o0[3]);
  d0.z = cvtpk(o0[4], o0[5]); d0.w = cvtpk(o0[6], o0[7]);
  d1.x = cvtpk(o1[0], o1[1]); d1.y = cvtpk(o1[2], o1[3]);
  d1.z = cvtpk(o1[4], o1[5]); d1.w = cvtpk(o1[6], o1[7]);
  unsigned short* yb = y + (size_t)bc * HXW + (size_t)hy * HX + wq;
  *(uint4*)yb = d0;
  *(uint4*)(yb + HX) = d1;
}

// ---------------------------------------------------------------------------
// fp32 -> bf16 flat convert (for w_kv).
// ---------------------------------------------------------------------------
__global__ void cvt_bf16_kernel(const float* __restrict__ src, unsigned short* __restrict__ dst,
                                int n) {
  int i = blockIdx.x * 256 + threadIdx.x;
  if (i < n) dst[i] = f2bf(src[i]);
}

// ---------------------------------------------------------------------------
// Depthwise 3x3 q path: fp32 NCHW in -> bf16 NHWC out, pre-scaled by 32^-0.5.
// ---------------------------------------------------------------------------
__global__ void dwconv_q_kernel(const float* __restrict__ x, const float* __restrict__ w,
                                unsigned short* __restrict__ qn, int total) {
  int i = blockIdx.x * 256 + threadIdx.x;
  if (i >= total) return;
  int wx = i % HS;
  int t = i / HS;
  int hy = t % HS;
  int bc = t / HS;
  int c = bc & 127;
  int b = bc >> 7;
  const float* xb = x + (size_t)bc * HSW;
  const float* wc = w + c * 9;
  float s = 0.0f;
  for (int di = -1; di <= 1; di++) {
    int h2 = hy + di;
    if (h2 < 0 || h2 >= HS) continue;
    for (int dj = -1; dj <= 1; dj++) {
      int w2 = wx + dj;
      if (w2 < 0 || w2 >= HS) continue;
      s += xb[(size_t)h2 * HS + w2] * wc[(di + 1) * 3 + (dj + 1)];
    }
  }
  qn[((size_t)(b * HSW + hy * HS + wx)) * 128 + c] = f2bf(s * 0.17677669529663688f);
}

// ---------------------------------------------------------------------------
// MFMA 1x1 conv kv path, v3: weights staged in LDS per 64-o quarter.
// Block = 64 px x 256 o, 4 waves. Grid (961, 2).
// ---------------------------------------------------------------------------
__global__ __launch_bounds__(256) void conv1_kv_mfma_kernel(
    const unsigned short* __restrict__ xpb,  // (2,128,61504) bf16 NCHW
    const unsigned short* __restrict__ wkb,  // (256,128) bf16
    unsigned short* __restrict__ y) {        // (2,61504,256) bf16 NHWC
  int b = blockIdx.y;
  int p0 = blockIdx.x * 64;
  int tid = threadIdx.x;
  int wave = tid >> 6, lane = tid & 63, quad = lane >> 4, l15 = lane & 15;
  __shared__ __align__(16) unsigned short bufA[64 * 136];  // 17,408 B
  __shared__ __align__(16) unsigned short bufW[64 * 136];  // 17,408 B

  // phase 1: stage X-tile as bufA[px][c], stride 136
  {
    int c = tid >> 1, half = tid & 1;
    const unsigned short* src = xpb + ((size_t)(b * 128 + c)) * HXW + p0 + half * 32;
#pragma unroll
    for (int j = 0; j < 8; j++) {
      uint2 v = *(const uint2*)(src + j * 4);
      int px = half * 32 + j * 4;
      bufA[(px + 0) * 136 + c] = (unsigned short)(v.x & 0xffff);
      bufA[(px + 1) * 136 + c] = (unsigned short)(v.x >> 16);
      bufA[(px + 2) * 136 + c] = (unsigned short)(v.y & 0xffff);
      bufA[(px + 3) * 136 + c] = (unsigned short)(v.y >> 16);
    }
  }
  __syncthreads();
  bf16x8 A[4];
#pragma unroll
  for (int kb = 0; kb < 4; kb++)
    A[kb] = __builtin_bit_cast(bf16x8,
        *(const uint4*)&bufA[(wave * 16 + l15) * 136 + kb * 32 + quad * 8]);
  // bufA becomes the output stage after the next barrier.

  const f32x4 zf = {0.f, 0.f, 0.f, 0.f};
#pragma unroll 1
  for (int h = 0; h < 2; h++) {
#pragma unroll 1
    for (int oq = 0; oq < 2; oq++) {
      __syncthreads();  // bufW reusable; (h>0: bufA flush complete)
      {  // cooperative coalesced load of one 64-o weight quarter -> bufW
        int orow = tid >> 2;          // 0..63
        int cseg = (tid & 3) * 32;    // 0,32,64,96
        const unsigned short* src = wkb + (size_t)(h * 128 + oq * 64 + orow) * 128 + cseg;
        unsigned short* dst = &bufW[orow * 136 + cseg];
        *(uint4*)(dst)      = *(const uint4*)(src);
        *(uint4*)(dst + 8)  = *(const uint4*)(src + 8);
        *(uint4*)(dst + 16) = *(const uint4*)(src + 16);
        *(uint4*)(dst + 24) = *(const uint4*)(src + 24);
      }
      __syncthreads();
#pragma unroll
      for (int ot = 0; ot < 4; ot++) {
        const unsigned short* wrow = &bufW[(ot * 16 + l15) * 136 + quad * 8];
        f32x4 D = zf;
        D = __builtin_amdgcn_mfma_f32_16x16x32_bf16(A[0], __builtin_bit_cast(bf16x8, *(const uint4*)(wrow)),      D, 0, 0, 0);
        D = __builtin_amdgcn_mfma_f32_16x16x32_bf16(A[1], __builtin_bit_cast(bf16x8, *(const uint4*)(wrow + 32)), D, 0, 0, 0);
        D = __builtin_amdgcn_mfma_f32_16x16x32_bf16(A[2], __builtin_bit_cast(bf16x8, *(const uint4*)(wrow + 64)), D, 0, 0, 0);
        D = __builtin_amdgcn_mfma_f32_16x16x32_bf16(A[3], __builtin_bit_cast(bf16x8, *(const uint4*)(wrow + 96)), D, 0, 0, 0);
#pragma unroll
        for (int r = 0; r < 4; r++)
          bufA[(wave * 16 + quad * 4 + r) * 136 + (oq * 4 + ot) * 16 + l15] = f2bf(D[r]);
      }
    }
    __syncthreads();
    {  // flush this o-half: 64 px x 128 o, coalesced
      int px = tid >> 2, og = (tid & 3) * 32;
      const uint4* srcp = (const uint4*)&bufA[px * 136 + og];
      uint4* dstp = (uint4*)(y + ((size_t)b * HXW + p0 + px) * 256 + h * 128 + og);
#pragma unroll
      for (int j = 0; j < 4; j++) dstp[j] = srcp[j];
    }
  }
}

// ---------------------------------------------------------------------------
// Fused depthwise 3x3 K/V from bf16 NHWC tkv — v4: 2-channel lanes, 512-thr
// blocks, fused row-pair column streaming. Grid (496, 2), block 512.
// ---------------------------------------------------------------------------
template <bool VT, bool VB>
static __device__ __forceinline__ void dwkv_rowpair(
    const unsigned short* __restrict__ rm1, const unsigned short* __restrict__ r0,
    const unsigned short* __restrict__ r1, const unsigned short* __restrict__ r2,
    const f32x2 (&wp)[9], int px0, f32x2 (&a0)[8], f32x2 (&a1)[8]) {
  const f32x2 z2 = {0.f, 0.f};
#pragma unroll
  for (int p = 0; p < 8; p++) { a0[p] = z2; a1[p] = z2; }
#pragma unroll
  for (int j = 0; j < 10; j++) {
    int xcol = px0 - 1 + j;
    int xc = xcol;
    if (j == 0) xc = (xcol < 0) ? 0 : xcol;
    if (j == 9) xc = (xcol > HX - 1) ? HX - 1 : xcol;
    size_t off = (size_t)xc * 256;
    uint32_t um1 = 0, u0, u1, u2 = 0;
    u0 = *(const uint32_t*)(r0 + off);
    u1 = *(const uint32_t*)(r1 + off);
    if constexpr (VT) um1 = *(const uint32_t*)(rm1 + off);
    if constexpr (VB) u2 = *(const uint32_t*)(r2 + off);
    if (j == 0 || j == 9) {  // only edge columns can be out of range
      bool oob = (j == 0) ? (xcol < 0) : (xcol > HX - 1);
      if (oob) { um1 = 0u; u0 = 0u; u1 = 0u; u2 = 0u; }
    }
    f32x2 dm1, d0 = unp(u0), d1 = unp(u1), d2;
    if constexpr (VT) dm1 = unp(um1);
    if constexpr (VB) d2 = unp(u2);
    if (j <= 7) {
      if constexpr (VT) pkfma(a0[j], wp[0], dm1);
      pkfma(a0[j], wp[3], d0);
      pkfma(a0[j], wp[6], d1);
      pkfma(a1[j], wp[0], d0);
      pkfma(a1[j], wp[3], d1);
      if constexpr (VB) pkfma(a1[j], wp[6], d2);
    }
    if (j >= 1 && j <= 8) {
      if constexpr (VT) pkfma(a0[j - 1], wp[1], dm1);
      pkfma(a0[j - 1], wp[4], d0);
      pkfma(a0[j - 1], wp[7], d1);
      pkfma(a1[j - 1], wp[1], d0);
      pkfma(a1[j - 1], wp[4], d1);
      if constexpr (VB) pkfma(a1[j - 1], wp[7], d2);
    }
    if (j >= 2) {
      if constexpr (VT) pkfma(a0[j - 2], wp[2], dm1);
      pkfma(a0[j - 2], wp[5], d0);
      pkfma(a0[j - 2], wp[8], d1);
      pkfma(a1[j - 2], wp[2], d0);
      pkfma(a1[j - 2], wp[5], d1);
      if constexpr (VB) pkfma(a1[j - 2], wp[8], d2);
    }
  }
}

#define VTS 72                    // vt channel stride (shorts): 144 B, 16-B aligned
#define VTROW (128 * VTS + 16)    // vt row stride (shorts), +16 shifts banks

__global__ __launch_bounds__(512) __attribute__((amdgpu_waves_per_eu(4)))
void dwconv_kv_kernel(const unsigned short* __restrict__ tkv,
                      const float* __restrict__ w,
                      unsigned short* __restrict__ kT,
                      unsigned short* __restrict__ vv) {
  int fid = blockIdx.x;
  int xcd = fid & 7, slot = fid >> 3;
  int gi = xcd * 62 + slot;          // 0..495
  int strip = gi / 124;              // 0..3
  int g = gi % 124;                  // row-pair index
  int b = blockIdx.y;
  int x0 = strip * 64;
  int tid = threadIdx.x;
  int cl = tid & 127;                // channel lane: ch = 2*cl, 2*cl+1
  int pg = tid >> 7;                 // 0..3 px-group (wave-pair uniform)
  int ch0 = cl * 2;
  int hy0 = g * 2;

  f32x2 wp[9];
#pragma unroll
  for (int t = 0; t < 9; t++) {
    wp[t].x = w[ch0 * 9 + t];
    wp[t].y = w[(ch0 + 1) * 9 + t];
  }

  __shared__ __align__(16) unsigned short vt[2 * VTROW];  // 36,928 B

  const unsigned short* r0 = tkv + (size_t)b * HXW * 256 + (size_t)hy0 * (HX * 256) + ch0;
  const unsigned short* r1 = r0 + HX * 256;
  const unsigned short* rm1 = r0 - HX * 256;   // deref only when VT
  const unsigned short* r2 = r1 + HX * 256;    // deref only when VB
  bool isK = (cl < 64);
  int c0 = ch0 - 128;                // V-lane channel base

#pragma unroll 1
  for (int half = 0; half < 2; half++) {
    int px0 = x0 + pg * 16 + half * 8;
    if (px0 < HX) {  // strip 3 / pg 3 / half 1 is pure pad: skip
      f32x2 a0[8], a1[8];
      if (g == 0)        dwkv_rowpair<false, true >(rm1, r0, r1, r2, wp, px0, a0, a1);
      else if (g == 123) dwkv_rowpair<true,  false>(rm1, r0, r1, r2, wp, px0, a0, a1);
      else               dwkv_rowpair<true,  true >(rm1, r0, r1, r2, wp, px0, a0, a1);

      if (isK) {  // K rows: direct NHWC store, 2 ch packed per dword
        unsigned short* kb0 = kT + ((size_t)b * HXW + (size_t)hy0 * HX + px0) * 128 + ch0;
        unsigned short* kb1 = kb0 + (size_t)HX * 128;
#pragma unroll
        for (int p = 0; p < 8; p++) {
          *(uint32_t*)(kb0 + (size_t)p * 128) = cvtpk(a0[p].x, a0[p].y);
          *(uint32_t*)(kb1 + (size_t)p * 128) = cvtpk(a1[p].x, a1[p].y);
        }
      } else {    // V rows: stage transposed [row][ch][px] into LDS
        int pxr = pg * 16 + half * 8;
        unsigned short* v0 = vt + c0 * VTS + pxr;        // ch c0, row 0
        unsigned short* v1 = v0 + VTS;                   // ch c0+1
        uint2 d;
        d.x = cvtpk(a0[0].x, a0[1].x); d.y = cvtpk(a0[2].x, a0[3].x);
        *(uint2*)(v0) = d;
        d.x = cvtpk(a0[4].x, a0[5].x); d.y = cvtpk(a0[6].x, a0[7].x);
        *(uint2*)(v0 + 4) = d;
        d.x = cvtpk(a0[0].y, a0[1].y); d.y = cvtpk(a0[2].y, a0[3].y);
        *(uint2*)(v1) = d;
        d.x = cvtpk(a0[4].y, a0[5].y); d.y = cvtpk(a0[6].y, a0[7].y);
        *(uint2*)(v1 + 4) = d;
        d.x = cvtpk(a1[0].x, a1[1].x); d.y = cvtpk(a1[2].x, a1[3].x);
        *(uint2*)(v0 + VTROW) = d;
        d.x = cvtpk(a1[4].x, a1[5].x); d.y = cvtpk(a1[6].x, a1[7].x);
        *(uint2*)(v0 + VTROW + 4) = d;
        d.x = cvtpk(a1[0].y, a1[1].y); d.y = cvtpk(a1[2].y, a1[3].y);
        *(uint2*)(v1 + VTROW) = d;
        d.x = cvtpk(a1[4].y, a1[5].y); d.y = cvtpk(a1[6].y, a1[7].y);
        *(uint2*)(v1 + VTROW + 4) = d;
      }
    }
  }
  __syncthreads();
  {  // cooperative NCHW store of both V rows (full 128-B lines, padded rows)
    int ch = tid >> 2;
    int row = (tid >> 1) & 1;
    int ph = (tid & 1) * 32;
    const unsigned short* srcv = vt + row * VTROW + ch * VTS + ph;
    unsigned short* dst = vv + (size_t)(b * 128 + ch) * HXWP + (size_t)(hy0 + row) * HXP + x0 + ph;
#pragma unroll
    for (int j = 0; j < 4; j++)
      *(uint4*)(dst + j * 8) = *(const uint4*)(srcv + j * 8);
  }
}

// ---------------------------------------------------------------------------
// 1x1 conv tiled SGEMM (fp32) — small tensors (q path, output projection).
// ---------------------------------------------------------------------------
template <int O>
__global__ __launch_bounds__(256) void conv1_kernel(const float* __restrict__ x,
                                                    const float* __restrict__ w,
                                                    float* __restrict__ y, int HW) {
  constexpr int K = 128;
  constexpr int BK = 32;
  __shared__ __align__(16) float ws_s[BK][64];
  __shared__ __align__(16) float xs_s[BK][64];
  int b = blockIdx.z;
  int o0 = blockIdx.y * 64;
  int p0 = blockIdx.x * 64;
  const float* xb = x + (size_t)b * K * HW;
  int tx = threadIdx.x & 15;
  int ty = threadIdx.x >> 4;
  float acc[4][4] = {};
  int lo = threadIdx.x >> 2;
  int lk = (threadIdx.x & 3) * 8;
  int lc = threadIdx.x >> 3;
  int lp = (threadIdx.x & 7) * 8;

  for (int k0 = 0; k0 < K; k0 += BK) {
    __syncthreads();
    {
      const float* wp = w + (size_t)(o0 + lo) * K + k0 + lk;
      float4 a = *(const float4*)wp;
      float4 bq = *(const float4*)(wp + 4);
      ws_s[lk + 0][lo] = a.x;  ws_s[lk + 1][lo] = a.y;
      ws_s[lk + 2][lo] = a.z;  ws_s[lk + 3][lo] = a.w;
      ws_s[lk + 4][lo] = bq.x; ws_s[lk + 5][lo] = bq.y;
      ws_s[lk + 6][lo] = bq.z; ws_s[lk + 7][lo] = bq.w;
    }
    {
      int p = p0 + lp;
      const float* xp = xb + (size_t)(k0 + lc) * HW;
      float4 a, bq;
      if (p + 7 < HW) {
        a = *(const float4*)(xp + p);
        bq = *(const float4*)(xp + p + 4);
      } else {
        float tv[8];
#pragma unroll
        for (int j = 0; j < 8; j++) tv[j] = (p + j < HW) ? xp[p + j] : 0.0f;
        a = make_float4(tv[0], tv[1], tv[2], tv[3]);
        bq = make_float4(tv[4], tv[5], tv[6], tv[7]);
      }
      *(float4*)&xs_s[lc][lp] = a;
      *(float4*)&xs_s[lc][lp + 4] = bq;
    }
    __syncthreads();
#pragma unroll
    for (int k = 0; k < BK; k++) {
      float4 wv = *(const float4*)&ws_s[k][ty * 4];
      float4 xv = *(const float4*)&xs_s[k][tx * 4];
      acc[0][0] += wv.x * xv.x; acc[0][1] += wv.x * xv.y; acc[0][2] += wv.x * xv.z; acc[0][3] += wv.x * xv.w;
      acc[1][0] += wv.y * xv.x; acc[1][1] += wv.y * xv.y; acc[1][2] += wv.y * xv.z; acc[1][3] += wv.y * xv.w;
      acc[2][0] += wv.z * xv.x; acc[2][1] += wv.z * xv.y; acc[2][2] += wv.z * xv.z; acc[2][3] += wv.z * xv.w;
      acc[3][0] += wv.w * xv.x; acc[3][1] += wv.w * xv.y; acc[3][2] += wv.w * xv.z; acc[3][3] += wv.w * xv.w;
    }
  }
  int p = p0 + tx * 4;
  float* yb = y + (size_t)b * O * HW + (size_t)(o0 + ty * 4) * HW;
#pragma unroll
  for (int j = 0; j < 4; j++) {
    float* yr = yb + (size_t)j * HW + p;
    if (p + 3 < HW) {
      *(float4*)yr = make_float4(acc[j][0], acc[j][1], acc[j][2], acc[j][3]);
    } else {
#pragma unroll
      for (int e = 0; e < 4; e++) if (p + e < HW) yr[e] = acc[j][e];
    }
  }
}

// ---------------------------------------------------------------------------
// MFMA windowed attention v3 — one head per block. Grid 800 = (b,4h,100n),
// XCD-swizzled so each XCD owns one (b,h) slice x all windows. 256 thr =
// 4 oct-waves x 8 key rows (identical per-wave FP order to round-4 version).
// Single-pass epilogue, direct normalized output. No partials, no combine.
// ---------------------------------------------------------------------------
__global__ __launch_bounds__(256) void attn_mfma_kernel(
    const unsigned short* __restrict__ qn,   // (2,62,62,128) bf16, pre-scaled
    const unsigned short* __restrict__ kT,   // (2,248,248,128) bf16 NHWC
    const unsigned short* __restrict__ vp,   // (2,128,248,256p) bf16 NCHW padded
    float* __restrict__ o) {                 // (2,100,128,64)
  int fid = blockIdx.x;
  int xcd = fid & 7, slot = fid >> 3;        // slot 0..99
  int lin = xcd * 100 + slot;
  int n = lin % 100;
  int bh = lin / 100;                        // 0..7
  int h = bh & 3, b = bh >> 2;
  int wi = n / 10, wj = n % 10;
  int wave = threadIdx.x >> 6;               // oct 0..3
  int oct = wave;
  int lane = threadIdx.x & 63;
  int quad = lane >> 4;
  int l15 = lane & 15;
  int y0 = 24 * wi, x0 = 24 * wj;

  __shared__ __align__(16) unsigned short lds[16896];  // 33,792 B
  unsigned short* Pw = lds + wave * 2560;              // [q][40keys] 5KB/wave

  bf16x8 QB[4];
#pragma unroll
  for (int nt = 0; nt < 4; nt++) {
    int qq = nt * 16 + l15;
    int qy = 6 * wi + (qq >> 3), qx = 6 * wj + (qq & 7);
    QB[nt] = __builtin_bit_cast(bf16x8,
        *(const uint4*)(qn + ((size_t)(b * HSW + qy * HS + qx)) * 128 + h * 32 + quad * 8));
  }

  f32x4 Oacc[2][4];
#pragma unroll
  for (int a = 0; a < 2; a++)
#pragma unroll
    for (int c = 0; c < 4; c++) Oacc[a][c] = f32x4{0.f, 0.f, 0.f, 0.f};
  float lsum[4] = {0.f, 0.f, 0.f, 0.f};

  const unsigned short* kb = kT + (size_t)b * HXW * 128 + h * 32;
  const unsigned short* vb = vp + ((size_t)(b * 128 + h * 32)) * HXWP;
  const f32x4 zf = {0.f, 0.f, 0.f, 0.f};

#define LOADROW(r, K0, K1, V0, V1)                                              \
  {                                                                             \
    int y = y0 + (r);                                                           \
    const unsigned short* krow = kb + ((size_t)(y * HX + x0)) * 128;            \
    K0 = *(const uint4*)(krow + (size_t)l15 * 128 + quad * 8);                  \
    K1 = *(const uint4*)(krow + (size_t)(16 + l15) * 128 + quad * 8);           \
    const unsigned short* vrow = vb + (size_t)y * HXP + x0 + quad * 8;          \
    V0 = *(const uint4*)(vrow + (size_t)l15 * HXWP);                            \
    V1 = *(const uint4*)(vrow + (size_t)(16 + l15) * HXWP);                     \
  }

  auto compute = [&](uint4 k0, uint4 k1, uint4 v0, uint4 v1) {
    bf16x8 KA0 = __builtin_bit_cast(bf16x8, k0);
    bf16x8 KA1 = __builtin_bit_cast(bf16x8, k1);
    bf16x8 VA0 = __builtin_bit_cast(bf16x8, v0);
    bf16x8 VA1 = __builtin_bit_cast(bf16x8, v1);
    f32x4 S[2][4];
#pragma unroll
    for (int nt = 0; nt < 4; nt++) {
      S[0][nt] = __builtin_amdgcn_mfma_f32_16x16x32_bf16(KA0, QB[nt], zf, 0, 0, 0);
      S[1][nt] = __builtin_amdgcn_mfma_f32_16x16x32_bf16(KA1, QB[nt], zf, 0, 0, 0);
    }
#pragma unroll
    for (int nt = 0; nt < 4; nt++) {
      float pv[2][4];
      float cs = 0.f;
#pragma unroll
      for (int mt = 0; mt < 2; mt++)
#pragma unroll
        for (int r = 0; r < 4; r++) {
          pv[mt][r] = __expf(S[mt][nt][r]);
          cs += pv[mt][r];
        }
      lsum[nt] += cs;
#pragma unroll
      for (int mt = 0; mt < 2; mt++) {
        uint2 d;
        d.x = (uint32_t)f2bf(pv[mt][0]) | ((uint32_t)f2bf(pv[mt][1]) << 16);
        d.y = (uint32_t)f2bf(pv[mt][2]) | ((uint32_t)f2bf(pv[mt][3]) << 16);
        *(uint2*)(Pw + (16 * nt + l15) * 40 + 16 * mt + quad * 4) = d;
      }
    }
#pragma unroll
    for (int nt = 0; nt < 4; nt++) {
      bf16x8 PB = __builtin_bit_cast(bf16x8, *(const uint4*)(Pw + (16 * nt + l15) * 40 + quad * 8));
      Oacc[0][nt] = __builtin_amdgcn_mfma_f32_16x16x32_bf16(VA0, PB, Oacc[0][nt], 0, 0, 0);
      Oacc[1][nt] = __builtin_amdgcn_mfma_f32_16x16x32_bf16(VA1, PB, Oacc[1][nt], 0, 0, 0);
    }
  };

  int rbase = oct * 8;
  uint4 kA0, kA1, vA0, vA1, kB0, kB1, vB0, vB1;
  LOADROW(rbase + 0, kA0, kA1, vA0, vA1);
  LOADROW(rbase + 1, kB0, kB1, vB0, vB1);
#pragma unroll 1
  for (int r = 0; r < 8; r += 2) {
    compute(kA0, kA1, vA0, vA1);
    {
      int rn = (r + 2 < 8) ? (r + 2) : 6;  // clamped, branch-free
      LOADROW(rbase + rn, kA0, kA1, vA0, vA1);
    }
    compute(kB0, kB1, vB0, vB1);
    {
      int rn = (r + 3 < 8) ? (r + 3) : 7;  // clamped, branch-free
      LOADROW(rbase + rn, kB0, kB1, vB0, vB1);
    }
  }
#undef LOADROW

#pragma unroll
  for (int nt = 0; nt < 4; nt++) {
    lsum[nt] += __shfl_xor(lsum[nt], 16, 64);
    lsum[nt] += __shfl_xor(lsum[nt], 32, 64);
  }

  float* mO = (float*)lds;                 // [oct][32ch][64q]  32 KB
  float* mL = (float*)(lds + 16384);       // [oct][64q]  1 KB
  __syncthreads();  // all Pw reads done before overwrite
#pragma unroll
  for (int mt = 0; mt < 2; mt++)
#pragma unroll
    for (int nt = 0; nt < 4; nt++)
#pragma unroll
      for (int r = 0; r < 4; r++)
        mO[oct * 2048 + (16 * mt + quad * 4 + r) * 64 + 16 * nt + l15] = Oacc[mt][nt][r];
  if (quad == 0) {
#pragma unroll
    for (int nt = 0; nt < 4; nt++) mL[oct * 64 + nt * 16 + l15] = lsum[nt];
  }
  __syncthreads();
  {
    int q = threadIdx.x & 63;
    int cg = threadIdx.x >> 6;  // 0..3 -> 8 ch each
    float inv = 1.0f / (mL[q] + mL[64 + q] + mL[128 + q] + mL[192 + q]);
    float* ob = o + (((size_t)(b * 100 + n)) * 128 + h * 32 + cg * 8) * 64 + q;
#pragma unroll
    for (int e = 0; e < 8; e++) {
      int ch = cg * 8 + e;
      float s = mO[ch * 64 + q] + mO[2048 + ch * 64 + q] +
                mO[4096 + ch * 64 + q] + mO[6144 + ch * 64 + q];
      ob[(size_t)e * 64] = s * inv;
    }
  }
}

// ---------------------------------------------------------------------------
// Reverse: scatter-average overlapping 8x8 windows (step 6) into (2,128,62,62)
// ---------------------------------------------------------------------------
__global__ void reverse_kernel(const float* __restrict__ win, float* __restrict__ out) {
  int i = blockIdx.x * 256 + threadIdx.x;
  const int total = 2 * 128 * HSW;
  if (i >= total) return;
  int x = i % HS;
  int t = i / HS;
  int y = t % HS;
  t /= HS;
  int c = t % 128;
  int b = t / 128;
  int wi0 = (y >= 7) ? (y - 2) / 6 : 0;
  int wi1 = min(9, y / 6);
  int wj0 = (x >= 7) ? (x - 2) / 6 : 0;
  int wj1 = min(9, x / 6);
  float s = 0.0f;
  for (int wi = wi0; wi <= wi1; wi++)
    for (int wj = wj0; wj <= wj1; wj++) {
      int di = y - 6 * wi, dj = x - 6 * wj;
      s += win[(((size_t)(b * 100 + wi * 10 + wj)) * 128 + c) * 64 + di * 8 + dj];
    }
  float cnt = (float)((wi1 - wi0 + 1) * (wj1 - wj0 + 1));
  out[i] = s / cnt;
}

// ---------------------------------------------------------------------------
extern "C" void kernel_launch(void* const* d_in, const int* in_sizes, int n_in,
                              void* d_out, int out_size, void* d_ws, size_t ws_size,
                              hipStream_t stream) {
  const float* x      = (const float*)d_in[0];
  const float* sp     = (const float*)d_in[1];
  const float* w_pos  = (const float*)d_in[2];
  const float* b_pos  = (const float*)d_in[3];
  const float* w_q    = (const float*)d_in[4];
  const float* w_qdw  = (const float*)d_in[5];
  const float* w_kv   = (const float*)d_in[6];
  const float* w_kvdw = (const float*)d_in[7];
  const float* w_out  = (const float*)d_in[8];
  float* out = (float*)d_out;

  const size_t N_x   = (size_t)2 * 128 * HXW;   // 15,745,024 (shorts for kT/xpb)
  const size_t N_vp  = (size_t)2 * 128 * HXWP;  // 16,252,928 (padded vv, shorts)
  const size_t N_s   = (size_t)2 * 128 * HSW;
  const size_t N_att = (size_t)2 * 100 * 128 * 64;

  float* ws = (float*)d_ws;
  // shorts-based layout (all counts even -> float-aligned):
  unsigned short* xpb = (unsigned short*)ws;          // N_x shorts, dead after step 5
  unsigned short* kT  = (unsigned short*)ws;          // N_x shorts (overwrites xpb)
  unsigned short* vv  = kT + N_x;                     // N_vp shorts (padded rows)
  unsigned short* tkv = vv + N_vp;                    // 2*N_x shorts
  float* att = (float*)tkv;                           // reuse (tkv dead after step 6)
  float* rev = att + N_att;
  float* spp = (float*)(tkv + 2 * N_x);
  float* tq  = spp + N_s;
  unsigned short* qn  = (unsigned short*)(tq + N_s);  // N_s shorts
  unsigned short* wkb = qn + N_s;                     // 32768 shorts
  (void)ws_size; (void)in_sizes; (void)n_in; (void)out_size;

  // 0. wkb = bf16(w_kv)
  cvt_bf16_kernel<<<128, 256, 0, stream>>>(w_kv, wkb, 256 * 128);
  // 1. xpb = bf16(x + dwconv3(x, w_pos, b_pos))   (bf16 NCHW), 8px x 2rows/thread
  {
    int total = 2 * 128 * 124 * 31;
    dwconv8x2_bf16_kernel<<<(total + 255) / 256, 256, 0, stream>>>(x, w_pos, b_pos, xpb, total);
  }
  // 2. spp = sp + dwconv3(sp, w_pos, b_pos)
  {
    int total = (int)N_s;
    dwconv3_kernel<<<(total + 255) / 256, 256, 0, stream>>>(sp, w_pos, b_pos, spp, 128, HS, HS, total, 1);
  }
  // 3. tq = conv1(spp, w_q)
  {
    int HW = HSW;
    dim3 grid((HW + 63) / 64, 2, 2);
    conv1_kernel<128><<<grid, 256, 0, stream>>>(spp, w_q, tq, HW);
  }
  // 4. qn = bf16_nhwc(dwconv3(tq, w_qdw)) * 32^-0.5
  {
    int total = (int)N_s;
    dwconv_q_kernel<<<(total + 255) / 256, 256, 0, stream>>>(tq, w_qdw, qn, total);
  }
  // 5. tkv = bf16_nhwc(mfma_conv1(xpb, wkb))   (xpb dead after)
  {
    dim3 grid(HXW / 64, 2);
    conv1_kv_mfma_kernel<<<grid, 256, 0, stream>>>(xpb, wkb, tkv);
  }
  // 6. kT (NHWC) + vv (NCHW padded) = bf16(dwconv3(tkv, w_kvdw)) (overwrites xpb)
  {
    dim3 grid(496, 2);
    dwconv_kv_kernel<<<grid, 512, 0, stream>>>(tkv, w_kvdw, kT, vv);
  }
  // 7. attention -> att (2,100,128,64)   (800 one-head blocks, XCD-swizzled)
  {
    attn_mfma_kernel<<<800, 256, 0, stream>>>(qn, kT, vv, att);
  }
  // 8. rev = reverse(att)
  {
    int total = (int)N_s;
    reverse_kernel<<<(total + 255) / 256, 256, 0, stream>>>(att, rev);
  }
  // 9. out = conv1(rev, w_out)
  {
    int HW = HSW;
    dim3 grid((HW + 63) / 64, 2, 2);
    conv1_kernel<128><<<grid, 256, 0, stream>>>(rev, w_out, out, HW);
  }
}